// Round 2
// baseline (1077.126 us; speedup 1.0000x reference)
//
#include <hip/hip_runtime.h>

// GraphGenRnn: node-LSTM (2L, HN=128, 64 seqs, 160 steps) -> node_exit/edge_entry
// -> edge-LSTM (2L, HE=16, 10240 seqs, ragged steps) -> heads -> scatter.
//
// R2: node kernel layer-pipelined across 16 waves (L0 waves 0-7 at step t,
// L1 waves 8-15 at step t-1), double-buffered h in LDS, 1 barrier/iter.
// Edge kernel: all inner barriers removed (intra-wave LDS only), head
// weights/biases hoisted to registers.

typedef __attribute__((ext_vector_type(8))) short short8;
typedef __attribute__((ext_vector_type(4))) float floatx4;

#define NG 64
#define NMAX 161

__device__ __forceinline__ float sgm(float x) {
  return __builtin_amdgcn_rcpf(1.0f + __expf(-x));
}
__device__ __forceinline__ float tanhf_(float x) {
  return 2.0f * __builtin_amdgcn_rcpf(1.0f + __expf(-2.0f * x)) - 1.0f;
}
__device__ __forceinline__ unsigned short f2b(float x) {
  union { float f; unsigned u; } v; v.f = x;
  unsigned r = v.u + 0x7fffu + ((v.u >> 16) & 1u);   // RNE to bf16
  return (unsigned short)(r >> 16);
}
__device__ __forceinline__ float b2f(unsigned short h) {
  union { unsigned u; float f; } v; v.u = ((unsigned)h) << 16; return v.f;
}

// ---------------------------------------------------------------------------
// Node LSTM: 4 blocks x 1024 threads (16 waves). Block b owns genes [16b,16b+16).
// Waves 0-7 (grp 0): layer 0 at step t. Waves 8-15 (grp 1): layer 1 at step t-1.
// Wave w8 owns hidden units [16*w8, 16*w8+16). Weights in VGPRs as bf16 MFMA
// B-fragments. h state double-buffered in LDS; ONE barrier per iteration.
// ---------------------------------------------------------------------------
__global__ __launch_bounds__(1024) void node_kernel(
    const float* __restrict__ gene,   // [64][128]
    const float* __restrict__ entw,   // [128][128]
    const float* __restrict__ entb,   // [128]
    const float* __restrict__ nwih,   // [1][512][128]
    const float* __restrict__ nwhh,   // [2][512][128]
    const float* __restrict__ nbih,   // [2][512]
    const float* __restrict__ nbhh,   // [2][512]
    unsigned short* __restrict__ nout) // bf16 [10240][128]
{
  const int tid  = threadIdx.x;
  const int wv   = tid >> 6;
  const int grp  = wv >> 3;          // 0 = layer0, 1 = layer1
  const int w8   = wv & 7;
  const int lane = tid & 63;
  const int lo   = lane & 15;
  const int hi   = lane >> 4;
  const int u    = (w8 << 4) | lo;   // hidden unit / gate column
  const int nb   = blockIdx.x;

  // row stride 136 shorts = 272B = 17x16B -> 16B aligned, 2-way bank alias (free)
  __shared__ __align__(16) unsigned short hA0[2][16][136];
  __shared__ __align__(16) unsigned short hA1[2][16][136];

  // ---- persistent B fragments (bf16): grp0 -> whh0 (K=128); grp1 -> [wih1|whh1] (K=256)
  short8 B[4][8];
#pragma unroll
  for (int t = 0; t < 4; ++t) {
    const int n = t * 128 + u;
    if (grp == 0) {
#pragma unroll
      for (int ks = 0; ks < 4; ++ks) {
        const float* src = nwhh + n * 128 + ks * 32 + hi * 8;
        short8 bfr;
#pragma unroll
        for (int jj = 0; jj < 8; ++jj) bfr[jj] = (short)f2b(src[jj]);
        B[t][ks] = bfr;
      }
    } else {
#pragma unroll
      for (int ks = 0; ks < 8; ++ks) {
        const int k = ks * 32 + hi * 8;
        const float* src = (ks < 4) ? (nwih + n * 128 + k)
                                    : (nwhh + 512 * 128 + n * 128 + (k - 128));
        short8 bfr;
#pragma unroll
        for (int jj = 0; jj < 8; ++jj) bfr[jj] = (short)f2b(src[jj]);
        B[t][ks] = bfr;
      }
    }
  }

  const int bb = grp * 512;
  const float bi = nbih[bb + u]       + nbhh[bb + u];
  const float bf = nbih[bb + 128 + u] + nbhh[bb + 128 + u];
  const float bg = nbih[bb + 256 + u] + nbhh[bb + 256 + u];
  const float bo = nbih[bb + 384 + u] + nbhh[bb + 384 + u];
  const floatx4 bx0 = {bi, bi, bi, bi};
  const floatx4 bx1 = {bf, bf, bf, bf};
  const floatx4 bx2 = {bg, bg, bg, bg};
  const floatx4 bx3 = {bo, bo, bo, bo};

  // ---- h_init = relu(gene @ entw^T + entb): 1024 threads x 2 units each ----
  {
    const int q  = tid >> 6;        // gene row within block
    const int u2 = lane * 2;        // unit pair
    const float* gc = gene + (nb * 16 + q) * 128;
    float acc0 = entb[u2], acc1 = entb[u2 + 1];
    for (int qq = 0; qq < 32; ++qq) {
      const float4 gv = *(const float4*)&gc[qq * 4];
      const float4 w0 = *(const float4*)&entw[u2 * 128 + qq * 4];
      const float4 w1 = *(const float4*)&entw[(u2 + 1) * 128 + qq * 4];
      acc0 += gv.x * w0.x + gv.y * w0.y + gv.z * w0.z + gv.w * w0.w;
      acc1 += gv.x * w1.x + gv.y * w1.y + gv.z * w1.z + gv.w * w1.w;
    }
    const unsigned short hb0 = f2b(fmaxf(acc0, 0.0f));
    const unsigned short hb1 = f2b(fmaxf(acc1, 0.0f));
    hA0[0][q][u2] = hb0; hA0[0][q][u2 + 1] = hb1;   // L0 reads at t=0
    hA1[1][q][u2] = hb0; hA1[1][q][u2 + 1] = hb1;   // L1 h1-state at t=1
  }
  __syncthreads();

  float c[4] = {0.f, 0.f, 0.f, 0.f};

  for (int t = 0; t <= 160; ++t) {
    const int rb = t & 1, wb = rb ^ 1;
    if (grp == 0) {
      if (t < 160) {
        floatx4 a0 = bx0, a1 = bx1, a2 = bx2, a3 = bx3;
        const unsigned short* ar = &hA0[rb][lo][hi * 8];
#pragma unroll
        for (int ks = 0; ks < 4; ++ks) {
          const short8 afr = *(const short8*)(ar + ks * 32);
          a0 = __builtin_amdgcn_mfma_f32_16x16x32_bf16(afr, B[0][ks], a0, 0, 0, 0);
          a1 = __builtin_amdgcn_mfma_f32_16x16x32_bf16(afr, B[1][ks], a1, 0, 0, 0);
          a2 = __builtin_amdgcn_mfma_f32_16x16x32_bf16(afr, B[2][ks], a2, 0, 0, 0);
          a3 = __builtin_amdgcn_mfma_f32_16x16x32_bf16(afr, B[3][ks], a3, 0, 0, 0);
        }
#pragma unroll
        for (int r = 0; r < 4; ++r) {
          const float iv = sgm(a0[r]);
          const float fv = sgm(a1[r]);
          const float gv = tanhf_(a2[r]);
          const float ov = sgm(a3[r]);
          const float cn = fv * c[r] + iv * gv;
          c[r] = cn;
          hA0[wb][hi * 4 + r][u] = f2b(ov * tanhf_(cn));
        }
      }
    } else {
      if (t >= 1) {
        floatx4 a0 = bx0, a1 = bx1, a2 = bx2, a3 = bx3;
        const unsigned short* a0r = &hA0[rb][lo][hi * 8];  // h0 of step t-1
        const unsigned short* a1r = &hA1[rb][lo][hi * 8];  // h1 of step t-2
#pragma unroll
        for (int ks = 0; ks < 4; ++ks) {
          const short8 afr = *(const short8*)(a0r + ks * 32);
          a0 = __builtin_amdgcn_mfma_f32_16x16x32_bf16(afr, B[0][ks], a0, 0, 0, 0);
          a1 = __builtin_amdgcn_mfma_f32_16x16x32_bf16(afr, B[1][ks], a1, 0, 0, 0);
          a2 = __builtin_amdgcn_mfma_f32_16x16x32_bf16(afr, B[2][ks], a2, 0, 0, 0);
          a3 = __builtin_amdgcn_mfma_f32_16x16x32_bf16(afr, B[3][ks], a3, 0, 0, 0);
        }
#pragma unroll
        for (int ks = 0; ks < 4; ++ks) {
          const short8 afr = *(const short8*)(a1r + ks * 32);
          a0 = __builtin_amdgcn_mfma_f32_16x16x32_bf16(afr, B[0][ks + 4], a0, 0, 0, 0);
          a1 = __builtin_amdgcn_mfma_f32_16x16x32_bf16(afr, B[1][ks + 4], a1, 0, 0, 0);
          a2 = __builtin_amdgcn_mfma_f32_16x16x32_bf16(afr, B[2][ks + 4], a2, 0, 0, 0);
          a3 = __builtin_amdgcn_mfma_f32_16x16x32_bf16(afr, B[3][ks + 4], a3, 0, 0, 0);
        }
        const size_t obase = (size_t)((160 - t) * 64 + nb * 16) * 128;  // step s=t-1
#pragma unroll
        for (int r = 0; r < 4; ++r) {
          const float iv = sgm(a0[r]);
          const float fv = sgm(a1[r]);
          const float gv = tanhf_(a2[r]);
          const float ov = sgm(a3[r]);
          const float cn = fv * c[r] + iv * gv;
          c[r] = cn;
          const unsigned short hb = f2b(ov * tanhf_(cn));
          const int q = hi * 4 + r;
          hA1[wb][q][u] = hb;
          nout[obase + (size_t)q * 128 + u] = hb;
        }
      }
    }
    __syncthreads();
  }
}

// ---------------------------------------------------------------------------
// Edge: 640 blocks x 256 threads; block b owns sequences k in [16b,16b+16),
// uniform trip count jrow = 160 - b/4. Thread = (seq sg, unit u). Weights in
// LDS (staged once, one barrier); ALL per-step LDS traffic is intra-wave so
// the step loop has NO block barriers. Head weights/biases hoisted to regs.
// ---------------------------------------------------------------------------
__global__ __launch_bounds__(256) void edge_kernel(
    const unsigned short* __restrict__ nflat, // bf16 [10240][128]
    const float* __restrict__ exw, const float* __restrict__ exb,   // [32][128],[32]
    const float* __restrict__ enw, const float* __restrict__ enb,   // [16][32],[16]
    const float* __restrict__ ewih,  // [1][64][16]
    const float* __restrict__ ewhh,  // [2][64][16]
    const float* __restrict__ ebih, const float* __restrict__ ebhh, // [2][64]
    const float* __restrict__ ee1w, const float* __restrict__ ee1b,
    const float* __restrict__ ee2w, const float* __restrict__ ee2b,
    const float* __restrict__ ef1w, const float* __restrict__ ef1b,
    const float* __restrict__ ef2w, const float* __restrict__ ef2b,
    float* __restrict__ out)
{
  const int tid = threadIdx.x;
  const int sg  = tid >> 4;
  const int u   = tid & 15;
  const int b   = blockIdx.x;
  const int kbase = b * 16;
  const int jrow  = 160 - (b >> 2);   // = row(k) for all k in this block

  __shared__ __align__(16) float s_exw[32][132];
  __shared__ __align__(16) float s_nf[16][132];
  __shared__ __align__(16) float s_enw[16][36];
  __shared__ __align__(16) float s_w0[64][20];
  __shared__ __align__(16) float s_w1[64][36];
  __shared__ __align__(16) float s_ee1[8][20];
  __shared__ __align__(16) float s_ef1[8][20];
  __shared__ __align__(16) float s_ef2[32][8];
  __shared__ __align__(16) float s_ee2[16];
  __shared__ float s_be0[64], s_be1[64];
  __shared__ float s_exb[32], s_enb[16], s_e1b[8], s_e2b[2], s_f1b[8], s_f2b[32];
  __shared__ __align__(16) float h0b[16][20];
  __shared__ __align__(16) float h1b[16][20];
  __shared__ __align__(16) float t1b[16][12];
  __shared__ __align__(16) float t2b[16][12];
  __shared__ __align__(16) float x32[16][36];

  for (int i = tid; i < 32 * 128; i += 256) s_exw[i >> 7][i & 127] = exw[i];
  for (int i = tid; i < 16 * 128; i += 256)
    s_nf[i >> 7][i & 127] = b2f(nflat[(size_t)(kbase + (i >> 7)) * 128 + (i & 127)]);
  for (int i = tid; i < 16 * 32; i += 256) s_enw[i >> 5][i & 31] = enw[i];
  for (int i = tid; i < 64 * 16; i += 256) {
    s_w0[i >> 4][i & 15] = ewhh[i];                 // layer0 whh
    s_w1[i >> 4][i & 15] = ewih[i];                 // layer1 wih
    s_w1[i >> 4][16 + (i & 15)] = ewhh[1024 + i];   // layer1 whh
  }
  for (int i = tid; i < 8 * 16; i += 256) { s_ee1[i >> 4][i & 15] = ee1w[i]; s_ef1[i >> 4][i & 15] = ef1w[i]; }
  for (int i = tid; i < 32 * 8; i += 256) s_ef2[i >> 3][i & 7] = ef2w[i];
  if (tid < 64) { s_be0[tid] = ebih[tid] + ebhh[tid]; s_be1[tid] = ebih[64 + tid] + ebhh[64 + tid]; }
  if (tid < 32) { s_exb[tid] = exb[tid]; s_f2b[tid] = ef2b[tid]; }
  if (tid < 16) { s_enb[tid] = enb[tid]; s_ee2[tid] = ee2w[tid]; }
  if (tid < 8)  { s_e1b[tid] = ee1b[tid]; s_f1b[tid] = ef1b[tid]; }
  if (tid < 2)  s_e2b[tid] = ee2b[tid];

  // zero the (never-written) diagonal; graph g == b for first 64 blocks
  if (b < NG) {
    for (int d = tid; d < NMAX; d += 256) {
      out[(size_t)b * (NMAX * NMAX) + (size_t)d * NMAX + d] = 0.0f;
      float* fb = out + (size_t)NG * NMAX * NMAX
                + ((size_t)b * NMAX * NMAX + (size_t)d * NMAX + d) * 16;
#pragma unroll
      for (int q = 0; q < 16; ++q) fb[q] = 0.0f;
    }
  }
  __syncthreads();   // the ONLY block barrier

  // ---- hoisted per-thread constants (read-only LDS -> regs) ----
  const float be0i = s_be0[u], be0f = s_be0[16 + u], be0g = s_be0[32 + u], be0o = s_be0[48 + u];
  const float be1i = s_be1[u], be1f = s_be1[16 + u], be1g = s_be1[32 + u], be1o = s_be1[48 + u];
  const float hbias = (u < 8) ? s_e1b[u] : s_f1b[u - 8];
  const float f2bl = s_f2b[u], f2bu = s_f2b[16 + u];
  const float4 wl0 = *(const float4*)&s_ef2[u][0];
  const float4 wl1 = *(const float4*)&s_ef2[u][4];
  const float4 wu0 = *(const float4*)&s_ef2[16 + u][0];
  const float4 wu1 = *(const float4*)&s_ef2[16 + u][4];
  // e-head weights for lanes u<2 (row u of ee2)
  const int ue = (u < 2) ? u : 0;
  const float4 we0 = *(const float4*)&s_ee2[ue * 8];
  const float4 we1 = *(const float4*)&s_ee2[ue * 8 + 4];
  const float e2bias = (u < 2) ? s_e2b[u] : 0.0f;

  // ---- h0e = relu(relu(nf @ exw^T + exb) @ enw^T + enb) ----
  {
    float acc0 = s_exb[u], acc1 = s_exb[16 + u];
    for (int qq = 0; qq < 32; ++qq) {
      const float4 nv  = *(const float4*)&s_nf[sg][qq * 4];
      const float4 w0v = *(const float4*)&s_exw[u][qq * 4];
      const float4 w1v = *(const float4*)&s_exw[16 + u][qq * 4];
      acc0 += nv.x * w0v.x + nv.y * w0v.y + nv.z * w0v.z + nv.w * w0v.w;
      acc1 += nv.x * w1v.x + nv.y * w1v.y + nv.z * w1v.z + nv.w * w1v.w;
    }
    x32[sg][u] = fmaxf(acc0, 0.0f);
    x32[sg][16 + u] = fmaxf(acc1, 0.0f);
  }
  __builtin_amdgcn_wave_barrier();
  float c0 = 0.0f, c1 = 0.0f;
  {
    float acc = s_enb[u];
#pragma unroll
    for (int qq = 0; qq < 8; ++qq) {
      const float4 xv  = *(const float4*)&x32[sg][qq * 4];
      const float4 wv2 = *(const float4*)&s_enw[u][qq * 4];
      acc += xv.x * wv2.x + xv.y * wv2.y + xv.z * wv2.z + xv.w * wv2.w;
    }
    const float h0e = fmaxf(acc, 0.0f);
    h0b[sg][u] = h0e;
    h1b[sg][u] = h0e;
  }
  __builtin_amdgcn_wave_barrier();

  const int gid = (kbase & 63) + sg;
  float* exi = out + (size_t)gid * (NMAX * NMAX);
  float* fea = out + (size_t)NG * NMAX * NMAX + (size_t)gid * (NMAX * NMAX) * 16;

  for (int s = 0; s < jrow; ++s) {
    float gi, gf, gg, go;
    { // layer 0 gate dots: rows u, 16+u, 32+u, 48+u
      float ai = be0i, af = be0f, ag = be0g, ao = be0o;
#pragma unroll
      for (int qq = 0; qq < 4; ++qq) {
        const float4 hv = *(const float4*)&h0b[sg][qq * 4];
        const float4 wi = *(const float4*)&s_w0[u][qq * 4];
        const float4 wf = *(const float4*)&s_w0[16 + u][qq * 4];
        const float4 wg = *(const float4*)&s_w0[32 + u][qq * 4];
        const float4 wo = *(const float4*)&s_w0[48 + u][qq * 4];
        ai += hv.x * wi.x + hv.y * wi.y + hv.z * wi.z + hv.w * wi.w;
        af += hv.x * wf.x + hv.y * wf.y + hv.z * wf.z + hv.w * wf.w;
        ag += hv.x * wg.x + hv.y * wg.y + hv.z * wg.z + hv.w * wg.w;
        ao += hv.x * wo.x + hv.y * wo.y + hv.z * wo.z + hv.w * wo.w;
      }
      gi = ai; gf = af; gg = ag; go = ao;
    }
    __builtin_amdgcn_wave_barrier();
    {
      const float iv = sgm(gi), fv = sgm(gf), gv = tanhf_(gg), ov = sgm(go);
      c0 = fv * c0 + iv * gv;
      h0b[sg][u] = ov * tanhf_(c0);
    }
    __builtin_amdgcn_wave_barrier();
    { // layer 1 gate dots over [h0new | h1]
      float ai = be1i, af = be1f, ag = be1g, ao = be1o;
#pragma unroll
      for (int qq = 0; qq < 4; ++qq) {
        const float4 hv = *(const float4*)&h0b[sg][qq * 4];
        const float4 wi = *(const float4*)&s_w1[u][qq * 4];
        const float4 wf = *(const float4*)&s_w1[16 + u][qq * 4];
        const float4 wg = *(const float4*)&s_w1[32 + u][qq * 4];
        const float4 wo = *(const float4*)&s_w1[48 + u][qq * 4];
        ai += hv.x * wi.x + hv.y * wi.y + hv.z * wi.z + hv.w * wi.w;
        af += hv.x * wf.x + hv.y * wf.y + hv.z * wf.z + hv.w * wf.w;
        ag += hv.x * wg.x + hv.y * wg.y + hv.z * wg.z + hv.w * wg.w;
        ao += hv.x * wo.x + hv.y * wo.y + hv.z * wo.z + hv.w * wo.w;
      }
#pragma unroll
      for (int qq = 0; qq < 4; ++qq) {
        const float4 hv = *(const float4*)&h1b[sg][qq * 4];
        const float4 wi = *(const float4*)&s_w1[u][16 + qq * 4];
        const float4 wf = *(const float4*)&s_w1[16 + u][16 + qq * 4];
        const float4 wg = *(const float4*)&s_w1[32 + u][16 + qq * 4];
        const float4 wo = *(const float4*)&s_w1[48 + u][16 + qq * 4];
        ai += hv.x * wi.x + hv.y * wi.y + hv.z * wi.z + hv.w * wi.w;
        af += hv.x * wf.x + hv.y * wf.y + hv.z * wf.z + hv.w * wf.w;
        ag += hv.x * wg.x + hv.y * wg.y + hv.z * wg.z + hv.w * wg.w;
        ao += hv.x * wo.x + hv.y * wo.y + hv.z * wo.z + hv.w * wo.w;
      }
      gi = ai; gf = af; gg = ag; go = ao;
    }
    __builtin_amdgcn_wave_barrier();
    {
      const float iv = sgm(gi), fv = sgm(gf), gv = tanhf_(gg), ov = sgm(go);
      c1 = fv * c1 + iv * gv;
      h1b[sg][u] = ov * tanhf_(c1);   // = eh[s]
    }
    __builtin_amdgcn_wave_barrier();
    // ---- heads ----
    if (u < 8) {
      float a = hbias;
#pragma unroll
      for (int qq = 0; qq < 4; ++qq) {
        const float4 hv  = *(const float4*)&h1b[sg][qq * 4];
        const float4 wv2 = *(const float4*)&s_ee1[u][qq * 4];
        a += hv.x * wv2.x + hv.y * wv2.y + hv.z * wv2.z + hv.w * wv2.w;
      }
      t1b[sg][u] = fmaxf(a, 0.0f);
    } else {
      const int p = u - 8;
      float a = hbias;
#pragma unroll
      for (int qq = 0; qq < 4; ++qq) {
        const float4 hv  = *(const float4*)&h1b[sg][qq * 4];
        const float4 wv2 = *(const float4*)&s_ef1[p][qq * 4];
        a += hv.x * wv2.x + hv.y * wv2.y + hv.z * wv2.z + hv.w * wv2.w;
      }
      t2b[sg][p] = fmaxf(a, 0.0f);
    }
    __builtin_amdgcn_wave_barrier();
    {
      const float4 ta = *(const float4*)&t2b[sg][0];
      const float4 tb = *(const float4*)&t2b[sg][4];
      const float fl = f2bl
          + ta.x * wl0.x + ta.y * wl0.y + ta.z * wl0.z + ta.w * wl0.w
          + tb.x * wl1.x + tb.y * wl1.y + tb.z * wl1.z + tb.w * wl1.w;
      const float fu = f2bu
          + ta.x * wu0.x + ta.y * wu0.y + ta.z * wu0.z + ta.w * wu0.w
          + tb.x * wu1.x + tb.y * wu1.y + tb.z * wu1.z + tb.w * wu1.w;
      fea[((size_t)jrow * NMAX + s) * 16 + u] = fl;
      fea[((size_t)s * NMAX + jrow) * 16 + u] = fu;
      if (u < 2) {
        const float4 t1a = *(const float4*)&t1b[sg][0];
        const float4 t1c = *(const float4*)&t1b[sg][4];
        float e = e2bias
            + t1a.x * we0.x + t1a.y * we0.y + t1a.z * we0.z + t1a.w * we0.w
            + t1c.x * we1.x + t1c.y * we1.y + t1c.z * we1.z + t1c.w * we1.w;
        const size_t idx = (u == 0) ? ((size_t)jrow * NMAX + s)
                                    : ((size_t)s * NMAX + jrow);
        exi[idx] = sgm(e);
      }
    }
    __builtin_amdgcn_wave_barrier();
  }
}

extern "C" void kernel_launch(void* const* d_in, const int* in_sizes, int n_in,
                              void* d_out, int out_size, void* d_ws, size_t ws_size,
                              hipStream_t stream) {
  (void)in_sizes; (void)n_in; (void)out_size; (void)ws_size;
  const float* gene = (const float*)d_in[0];
  const float* entw = (const float*)d_in[1];
  const float* entb = (const float*)d_in[2];
  // d_in[3] node_wih0: multiplies the all-zero input -> unused
  const float* nwih = (const float*)d_in[4];
  const float* nwhh = (const float*)d_in[5];
  const float* nbih = (const float*)d_in[6];
  const float* nbhh = (const float*)d_in[7];
  const float* exw  = (const float*)d_in[8];
  const float* exb  = (const float*)d_in[9];
  const float* enw  = (const float*)d_in[10];
  const float* enb  = (const float*)d_in[11];
  // d_in[12] edge_wih0: unused (zero input)
  const float* ewih = (const float*)d_in[13];
  const float* ewhh = (const float*)d_in[14];
  const float* ebih = (const float*)d_in[15];
  const float* ebhh = (const float*)d_in[16];
  const float* ee1w = (const float*)d_in[17];
  const float* ee1b = (const float*)d_in[18];
  const float* ee2w = (const float*)d_in[19];
  const float* ee2b = (const float*)d_in[20];
  const float* ef1w = (const float*)d_in[21];
  const float* ef1b = (const float*)d_in[22];
  const float* ef2w = (const float*)d_in[23];
  const float* ef2b = (const float*)d_in[24];

  unsigned short* nflat = (unsigned short*)d_ws;  // bf16 [10240][128] = 2.62 MB

  node_kernel<<<4, 1024, 0, stream>>>(gene, entw, entb, nwih, nwhh, nbih, nbhh, nflat);
  edge_kernel<<<640, 256, 0, stream>>>(nflat, exw, exb, enw, enb, ewih, ewhh,
                                       ebih, ebhh, ee1w, ee1b, ee2w, ee2b,
                                       ef1w, ef1b, ef2w, ef2b, (float*)d_out);
}

// Round 3
// 817.233 us; speedup vs baseline: 1.3180x; 1.3180x over previous
//
#include <hip/hip_runtime.h>

// GraphGenRnn: node-LSTM (2L, HN=128, 64 seqs, 160 steps) -> node_exit/edge_entry
// -> edge-LSTM (2L, HE=16, 10240 seqs, ragged steps) -> heads -> scatter.
//
// R3: node kernel back to 512-thread / 8-wave / both-layers-per-wave form, but
// with __launch_bounds__(512,2) so the 192 weight VGPRs actually FIT (R1/R2
// were silently spilling: VGPR_Count 128/64 < weight footprint). Double-
// buffered h state -> 2 barriers/step (was 4). Edge: s_exw LDS staging removed
// (prologue-only data, read from L2) -> ~35KB LDS -> 4 blocks/CU.

typedef __attribute__((ext_vector_type(8))) short short8;
typedef __attribute__((ext_vector_type(4))) float floatx4;

#define NG 64
#define NMAX 161

__device__ __forceinline__ float sgm(float x) {
  return __builtin_amdgcn_rcpf(1.0f + __expf(-x));
}
__device__ __forceinline__ float tanhf_(float x) {
  return 2.0f * __builtin_amdgcn_rcpf(1.0f + __expf(-2.0f * x)) - 1.0f;
}
__device__ __forceinline__ unsigned short f2b(float x) {
  union { float f; unsigned u; } v; v.f = x;
  unsigned r = v.u + 0x7fffu + ((v.u >> 16) & 1u);   // RNE to bf16
  return (unsigned short)(r >> 16);
}
__device__ __forceinline__ float b2f(unsigned short h) {
  union { unsigned u; float f; } v; v.u = ((unsigned)h) << 16; return v.f;
}

// ---------------------------------------------------------------------------
// Node LSTM: 4 blocks x 512 threads (8 waves), 1 block/CU, 2 waves/SIMD.
// Block b owns genes [16b,16b+16). Wave w owns hidden units [16w,16w+16) for
// BOTH layers; weights persist in VGPRs as bf16 MFMA B-fragments (192 VGPRs).
// h state double-buffered in LDS; 2 barriers per step.
// ---------------------------------------------------------------------------
__global__ __launch_bounds__(512, 2) void node_kernel(
    const float* __restrict__ gene,   // [64][128]
    const float* __restrict__ entw,   // [128][128]
    const float* __restrict__ entb,   // [128]
    const float* __restrict__ nwih,   // [1][512][128]
    const float* __restrict__ nwhh,   // [2][512][128]
    const float* __restrict__ nbih,   // [2][512]
    const float* __restrict__ nbhh,   // [2][512]
    unsigned short* __restrict__ nout) // bf16 [10240][128]
{
  const int tid  = threadIdx.x;
  const int wv   = tid >> 6;
  const int lane = tid & 63;
  const int lo   = lane & 15;
  const int hi   = lane >> 4;
  const int u    = (wv << 4) | lo;   // hidden unit / gate column
  const int nb   = blockIdx.x;

  // row stride 136 shorts = 272B (17x16B): 16B-aligned rows, mild bank alias
  __shared__ __align__(16) unsigned short hA0[2][16][136];
  __shared__ __align__(16) unsigned short hA1[2][16][136];

  // ---- persistent B fragments (bf16): L0 whh (K=128); L1 [wih1|whh1] (K=256)
  short8 B0[4][4];
  short8 B1[4][8];
#pragma unroll
  for (int t = 0; t < 4; ++t) {
    const int n = t * 128 + u;
#pragma unroll
    for (int ks = 0; ks < 4; ++ks) {
      const float* src = nwhh + n * 128 + ks * 32 + hi * 8;
      short8 bfr;
#pragma unroll
      for (int jj = 0; jj < 8; ++jj) bfr[jj] = (short)f2b(src[jj]);
      B0[t][ks] = bfr;
    }
#pragma unroll
    for (int ks = 0; ks < 8; ++ks) {
      const int k = ks * 32 + hi * 8;
      const float* src = (ks < 4) ? (nwih + n * 128 + k)
                                  : (nwhh + 512 * 128 + n * 128 + (k - 128));
      short8 bfr;
#pragma unroll
      for (int jj = 0; jj < 8; ++jj) bfr[jj] = (short)f2b(src[jj]);
      B1[t][ks] = bfr;
    }
  }

  const float bi0 = nbih[u]       + nbhh[u];
  const float bf0 = nbih[128 + u] + nbhh[128 + u];
  const float bg0 = nbih[256 + u] + nbhh[256 + u];
  const float bo0 = nbih[384 + u] + nbhh[384 + u];
  const float bi1 = nbih[512 + u]       + nbhh[512 + u];
  const float bf1 = nbih[512 + 128 + u] + nbhh[512 + 128 + u];
  const float bg1 = nbih[512 + 256 + u] + nbhh[512 + 256 + u];
  const float bo1 = nbih[512 + 384 + u] + nbhh[512 + 384 + u];

  // ---- h_init = relu(gene @ entw^T + entb): 512 threads x 4 units each ----
  {
    const int q  = tid >> 5;            // gene row within block
    const int u4 = (tid & 31) * 4;      // 4 units per thread
    const float* gc = gene + (nb * 16 + q) * 128;
    float acc[4] = { entb[u4], entb[u4 + 1], entb[u4 + 2], entb[u4 + 3] };
    for (int qq = 0; qq < 32; ++qq) {
      const float4 gv = *(const float4*)&gc[qq * 4];
#pragma unroll
      for (int r = 0; r < 4; ++r) {
        const float4 wv2 = *(const float4*)&entw[(u4 + r) * 128 + qq * 4];
        acc[r] += gv.x * wv2.x + gv.y * wv2.y + gv.z * wv2.z + gv.w * wv2.w;
      }
    }
#pragma unroll
    for (int r = 0; r < 4; ++r) {
      const unsigned short hb = f2b(fmaxf(acc[r], 0.0f));
      hA0[0][q][u4 + r] = hb;   // L0 reads h0_{-1} at t=0
      hA1[0][q][u4 + r] = hb;   // L1 reads h1_{-1} at t=0
    }
  }

  float c0[4] = {0.f, 0.f, 0.f, 0.f};
  float c1[4] = {0.f, 0.f, 0.f, 0.f};
  __syncthreads();

  for (int t = 0; t < 160; ++t) {
    const int rb = t & 1, wb = rb ^ 1;
    // ---------- layer 0: gates = h0_{t-1} @ whh0^T + b ----------
    {
      floatx4 a0 = {bi0, bi0, bi0, bi0};
      floatx4 a1 = {bf0, bf0, bf0, bf0};
      floatx4 a2 = {bg0, bg0, bg0, bg0};
      floatx4 a3 = {bo0, bo0, bo0, bo0};
      const unsigned short* ar = &hA0[rb][lo][hi * 8];
#pragma unroll
      for (int ks = 0; ks < 4; ++ks) {
        const short8 afr = *(const short8*)(ar + ks * 32);
        a0 = __builtin_amdgcn_mfma_f32_16x16x32_bf16(afr, B0[0][ks], a0, 0, 0, 0);
        a1 = __builtin_amdgcn_mfma_f32_16x16x32_bf16(afr, B0[1][ks], a1, 0, 0, 0);
        a2 = __builtin_amdgcn_mfma_f32_16x16x32_bf16(afr, B0[2][ks], a2, 0, 0, 0);
        a3 = __builtin_amdgcn_mfma_f32_16x16x32_bf16(afr, B0[3][ks], a3, 0, 0, 0);
      }
#pragma unroll
      for (int r = 0; r < 4; ++r) {
        const float iv = sgm(a0[r]);
        const float fv = sgm(a1[r]);
        const float gv = tanhf_(a2[r]);
        const float ov = sgm(a3[r]);
        const float cn = fv * c0[r] + iv * gv;
        c0[r] = cn;
        hA0[wb][hi * 4 + r][u] = f2b(ov * tanhf_(cn));
      }
    }
    __syncthreads();   // h0_t visible to all waves

    // ---------- layer 1: gates = [h0_t | h1_{t-1}] @ [wih|whh1]^T + b ----------
    {
      floatx4 a0 = {bi1, bi1, bi1, bi1};
      floatx4 a1 = {bf1, bf1, bf1, bf1};
      floatx4 a2 = {bg1, bg1, bg1, bg1};
      floatx4 a3 = {bo1, bo1, bo1, bo1};
      const unsigned short* a0r = &hA0[wb][lo][hi * 8];  // h0_t
      const unsigned short* a1r = &hA1[rb][lo][hi * 8];  // h1_{t-1}
#pragma unroll
      for (int ks = 0; ks < 4; ++ks) {
        const short8 afr = *(const short8*)(a0r + ks * 32);
        a0 = __builtin_amdgcn_mfma_f32_16x16x32_bf16(afr, B1[0][ks], a0, 0, 0, 0);
        a1 = __builtin_amdgcn_mfma_f32_16x16x32_bf16(afr, B1[1][ks], a1, 0, 0, 0);
        a2 = __builtin_amdgcn_mfma_f32_16x16x32_bf16(afr, B1[2][ks], a2, 0, 0, 0);
        a3 = __builtin_amdgcn_mfma_f32_16x16x32_bf16(afr, B1[3][ks], a3, 0, 0, 0);
      }
#pragma unroll
      for (int ks = 0; ks < 4; ++ks) {
        const short8 afr = *(const short8*)(a1r + ks * 32);
        a0 = __builtin_amdgcn_mfma_f32_16x16x32_bf16(afr, B1[0][ks + 4], a0, 0, 0, 0);
        a1 = __builtin_amdgcn_mfma_f32_16x16x32_bf16(afr, B1[1][ks + 4], a1, 0, 0, 0);
        a2 = __builtin_amdgcn_mfma_f32_16x16x32_bf16(afr, B1[2][ks + 4], a2, 0, 0, 0);
        a3 = __builtin_amdgcn_mfma_f32_16x16x32_bf16(afr, B1[3][ks + 4], a3, 0, 0, 0);
      }
      const size_t obase = (size_t)((159 - t) * 64 + nb * 16) * 128;
#pragma unroll
      for (int r = 0; r < 4; ++r) {
        const float iv = sgm(a0[r]);
        const float fv = sgm(a1[r]);
        const float gv = tanhf_(a2[r]);
        const float ov = sgm(a3[r]);
        const float cn = fv * c1[r] + iv * gv;
        c1[r] = cn;
        const unsigned short hb = f2b(ov * tanhf_(cn));
        const int q = hi * 4 + r;
        hA1[wb][q][u] = hb;
        nout[obase + (size_t)q * 128 + u] = hb;
      }
    }
    __syncthreads();   // h1_t visible; old buffers free for overwrite
  }
}

// ---------------------------------------------------------------------------
// Edge: 640 blocks x 256 threads; block b owns sequences k in [16b,16b+16),
// uniform trip count jrow = 160 - b/4. Thread = (seq sg, unit u). Weights in
// LDS (staged once, one barrier); per-step LDS traffic is intra-wave so the
// step loop has NO block barriers. exw read directly from global (L2).
// ---------------------------------------------------------------------------
__global__ __launch_bounds__(256) void edge_kernel(
    const unsigned short* __restrict__ nflat, // bf16 [10240][128]
    const float* __restrict__ exw, const float* __restrict__ exb,   // [32][128],[32]
    const float* __restrict__ enw, const float* __restrict__ enb,   // [16][32],[16]
    const float* __restrict__ ewih,  // [1][64][16]
    const float* __restrict__ ewhh,  // [2][64][16]
    const float* __restrict__ ebih, const float* __restrict__ ebhh, // [2][64]
    const float* __restrict__ ee1w, const float* __restrict__ ee1b,
    const float* __restrict__ ee2w, const float* __restrict__ ee2b,
    const float* __restrict__ ef1w, const float* __restrict__ ef1b,
    const float* __restrict__ ef2w, const float* __restrict__ ef2b,
    float* __restrict__ out)
{
  const int tid = threadIdx.x;
  const int sg  = tid >> 4;
  const int u   = tid & 15;
  const int b   = blockIdx.x;
  const int kbase = b * 16;
  const int jrow  = 160 - (b >> 2);   // = row(k) for all k in this block

  __shared__ __align__(16) float s_nf[16][132];
  __shared__ __align__(16) float s_enw[16][36];
  __shared__ __align__(16) float s_w0[64][20];
  __shared__ __align__(16) float s_w1[64][36];
  __shared__ __align__(16) float s_ee1[8][20];
  __shared__ __align__(16) float s_ef1[8][20];
  __shared__ __align__(16) float s_ef2[32][8];
  __shared__ __align__(16) float s_ee2[16];
  __shared__ float s_be0[64], s_be1[64];
  __shared__ float s_exb[32], s_enb[16], s_e1b[8], s_e2b[2], s_f1b[8], s_f2b[32];
  __shared__ __align__(16) float h0b[16][20];
  __shared__ __align__(16) float h1b[16][20];
  __shared__ __align__(16) float t1b[16][12];
  __shared__ __align__(16) float t2b[16][12];
  __shared__ __align__(16) float x32[16][36];

  for (int i = tid; i < 16 * 128; i += 256)
    s_nf[i >> 7][i & 127] = b2f(nflat[(size_t)(kbase + (i >> 7)) * 128 + (i & 127)]);
  for (int i = tid; i < 16 * 32; i += 256) s_enw[i >> 5][i & 31] = enw[i];
  for (int i = tid; i < 64 * 16; i += 256) {
    s_w0[i >> 4][i & 15] = ewhh[i];                 // layer0 whh
    s_w1[i >> 4][i & 15] = ewih[i];                 // layer1 wih
    s_w1[i >> 4][16 + (i & 15)] = ewhh[1024 + i];   // layer1 whh
  }
  for (int i = tid; i < 8 * 16; i += 256) { s_ee1[i >> 4][i & 15] = ee1w[i]; s_ef1[i >> 4][i & 15] = ef1w[i]; }
  for (int i = tid; i < 32 * 8; i += 256) s_ef2[i >> 3][i & 7] = ef2w[i];
  if (tid < 64) { s_be0[tid] = ebih[tid] + ebhh[tid]; s_be1[tid] = ebih[64 + tid] + ebhh[64 + tid]; }
  if (tid < 32) { s_exb[tid] = exb[tid]; s_f2b[tid] = ef2b[tid]; }
  if (tid < 16) { s_enb[tid] = enb[tid]; s_ee2[tid] = ee2w[tid]; }
  if (tid < 8)  { s_e1b[tid] = ee1b[tid]; s_f1b[tid] = ef1b[tid]; }
  if (tid < 2)  s_e2b[tid] = ee2b[tid];

  // zero the (never-written) diagonal; graph g == b for first 64 blocks
  if (b < NG) {
    for (int d = tid; d < NMAX; d += 256) {
      out[(size_t)b * (NMAX * NMAX) + (size_t)d * NMAX + d] = 0.0f;
      float* fb = out + (size_t)NG * NMAX * NMAX
                + ((size_t)b * NMAX * NMAX + (size_t)d * NMAX + d) * 16;
#pragma unroll
      for (int q = 0; q < 16; ++q) fb[q] = 0.0f;
    }
  }
  __syncthreads();   // the ONLY block barrier

  // ---- hoisted per-thread constants (read-only LDS -> regs) ----
  const float be0i = s_be0[u], be0f = s_be0[16 + u], be0g = s_be0[32 + u], be0o = s_be0[48 + u];
  const float be1i = s_be1[u], be1f = s_be1[16 + u], be1g = s_be1[32 + u], be1o = s_be1[48 + u];
  const float hbias = (u < 8) ? s_e1b[u] : s_f1b[u - 8];
  const float f2bl = s_f2b[u], f2bu = s_f2b[16 + u];
  const float4 wl0 = *(const float4*)&s_ef2[u][0];
  const float4 wl1 = *(const float4*)&s_ef2[u][4];
  const float4 wu0 = *(const float4*)&s_ef2[16 + u][0];
  const float4 wu1 = *(const float4*)&s_ef2[16 + u][4];
  // e-head weights for lanes u<2 (row u of ee2)
  const int ue = (u < 2) ? u : 0;
  const float4 we0 = *(const float4*)&s_ee2[ue * 8];
  const float4 we1 = *(const float4*)&s_ee2[ue * 8 + 4];
  const float e2bias = (u < 2) ? s_e2b[u] : 0.0f;

  // ---- h0e = relu(relu(nf @ exw^T + exb) @ enw^T + enb) ----
  {
    float acc0 = s_exb[u], acc1 = s_exb[16 + u];
    const float* w0p = exw + u * 128;
    const float* w1p = exw + (16 + u) * 128;
    for (int qq = 0; qq < 32; ++qq) {
      const float4 nv  = *(const float4*)&s_nf[sg][qq * 4];
      const float4 w0v = *(const float4*)&w0p[qq * 4];
      const float4 w1v = *(const float4*)&w1p[qq * 4];
      acc0 += nv.x * w0v.x + nv.y * w0v.y + nv.z * w0v.z + nv.w * w0v.w;
      acc1 += nv.x * w1v.x + nv.y * w1v.y + nv.z * w1v.z + nv.w * w1v.w;
    }
    x32[sg][u] = fmaxf(acc0, 0.0f);
    x32[sg][16 + u] = fmaxf(acc1, 0.0f);
  }
  __builtin_amdgcn_wave_barrier();
  float c0 = 0.0f, c1 = 0.0f;
  {
    float acc = s_enb[u];
#pragma unroll
    for (int qq = 0; qq < 8; ++qq) {
      const float4 xv  = *(const float4*)&x32[sg][qq * 4];
      const float4 wv2 = *(const float4*)&s_enw[u][qq * 4];
      acc += xv.x * wv2.x + xv.y * wv2.y + xv.z * wv2.z + xv.w * wv2.w;
    }
    const float h0e = fmaxf(acc, 0.0f);
    h0b[sg][u] = h0e;
    h1b[sg][u] = h0e;
  }
  __builtin_amdgcn_wave_barrier();

  const int gid = (kbase & 63) + sg;
  float* exi = out + (size_t)gid * (NMAX * NMAX);
  float* fea = out + (size_t)NG * NMAX * NMAX + (size_t)gid * (NMAX * NMAX) * 16;

  for (int s = 0; s < jrow; ++s) {
    float gi, gf, gg, go;
    { // layer 0 gate dots: rows u, 16+u, 32+u, 48+u
      float ai = be0i, af = be0f, ag = be0g, ao = be0o;
#pragma unroll
      for (int qq = 0; qq < 4; ++qq) {
        const float4 hv = *(const float4*)&h0b[sg][qq * 4];
        const float4 wi = *(const float4*)&s_w0[u][qq * 4];
        const float4 wf = *(const float4*)&s_w0[16 + u][qq * 4];
        const float4 wg = *(const float4*)&s_w0[32 + u][qq * 4];
        const float4 wo = *(const float4*)&s_w0[48 + u][qq * 4];
        ai += hv.x * wi.x + hv.y * wi.y + hv.z * wi.z + hv.w * wi.w;
        af += hv.x * wf.x + hv.y * wf.y + hv.z * wf.z + hv.w * wf.w;
        ag += hv.x * wg.x + hv.y * wg.y + hv.z * wg.z + hv.w * wg.w;
        ao += hv.x * wo.x + hv.y * wo.y + hv.z * wo.z + hv.w * wo.w;
      }
      gi = ai; gf = af; gg = ag; go = ao;
    }
    __builtin_amdgcn_wave_barrier();
    {
      const float iv = sgm(gi), fv = sgm(gf), gv = tanhf_(gg), ov = sgm(go);
      c0 = fv * c0 + iv * gv;
      h0b[sg][u] = ov * tanhf_(c0);
    }
    __builtin_amdgcn_wave_barrier();
    { // layer 1 gate dots over [h0new | h1]
      float ai = be1i, af = be1f, ag = be1g, ao = be1o;
#pragma unroll
      for (int qq = 0; qq < 4; ++qq) {
        const float4 hv = *(const float4*)&h0b[sg][qq * 4];
        const float4 wi = *(const float4*)&s_w1[u][qq * 4];
        const float4 wf = *(const float4*)&s_w1[16 + u][qq * 4];
        const float4 wg = *(const float4*)&s_w1[32 + u][qq * 4];
        const float4 wo = *(const float4*)&s_w1[48 + u][qq * 4];
        ai += hv.x * wi.x + hv.y * wi.y + hv.z * wi.z + hv.w * wi.w;
        af += hv.x * wf.x + hv.y * wf.y + hv.z * wf.z + hv.w * wf.w;
        ag += hv.x * wg.x + hv.y * wg.y + hv.z * wg.z + hv.w * wg.w;
        ao += hv.x * wo.x + hv.y * wo.y + hv.z * wo.z + hv.w * wo.w;
      }
#pragma unroll
      for (int qq = 0; qq < 4; ++qq) {
        const float4 hv = *(const float4*)&h1b[sg][qq * 4];
        const float4 wi = *(const float4*)&s_w1[u][16 + qq * 4];
        const float4 wf = *(const float4*)&s_w1[16 + u][16 + qq * 4];
        const float4 wg = *(const float4*)&s_w1[32 + u][16 + qq * 4];
        const float4 wo = *(const float4*)&s_w1[48 + u][16 + qq * 4];
        ai += hv.x * wi.x + hv.y * wi.y + hv.z * wi.z + hv.w * wi.w;
        af += hv.x * wf.x + hv.y * wf.y + hv.z * wf.z + hv.w * wf.w;
        ag += hv.x * wg.x + hv.y * wg.y + hv.z * wg.z + hv.w * wg.w;
        ao += hv.x * wo.x + hv.y * wo.y + hv.z * wo.z + hv.w * wo.w;
      }
      gi = ai; gf = af; gg = ag; go = ao;
    }
    __builtin_amdgcn_wave_barrier();
    {
      const float iv = sgm(gi), fv = sgm(gf), gv = tanhf_(gg), ov = sgm(go);
      c1 = fv * c1 + iv * gv;
      h1b[sg][u] = ov * tanhf_(c1);   // = eh[s]
    }
    __builtin_amdgcn_wave_barrier();
    // ---- heads ----
    if (u < 8) {
      float a = hbias;
#pragma unroll
      for (int qq = 0; qq < 4; ++qq) {
        const float4 hv  = *(const float4*)&h1b[sg][qq * 4];
        const float4 wv2 = *(const float4*)&s_ee1[u][qq * 4];
        a += hv.x * wv2.x + hv.y * wv2.y + hv.z * wv2.z + hv.w * wv2.w;
      }
      t1b[sg][u] = fmaxf(a, 0.0f);
    } else {
      const int p = u - 8;
      float a = hbias;
#pragma unroll
      for (int qq = 0; qq < 4; ++qq) {
        const float4 hv  = *(const float4*)&h1b[sg][qq * 4];
        const float4 wv2 = *(const float4*)&s_ef1[p][qq * 4];
        a += hv.x * wv2.x + hv.y * wv2.y + hv.z * wv2.z + hv.w * wv2.w;
      }
      t2b[sg][p] = fmaxf(a, 0.0f);
    }
    __builtin_amdgcn_wave_barrier();
    {
      const float4 ta = *(const float4*)&t2b[sg][0];
      const float4 tb = *(const float4*)&t2b[sg][4];
      const float fl = f2bl
          + ta.x * wl0.x + ta.y * wl0.y + ta.z * wl0.z + ta.w * wl0.w
          + tb.x * wl1.x + tb.y * wl1.y + tb.z * wl1.z + tb.w * wl1.w;
      const float fu = f2bu
          + ta.x * wu0.x + ta.y * wu0.y + ta.z * wu0.z + ta.w * wu0.w
          + tb.x * wu1.x + tb.y * wu1.y + tb.z * wu1.z + tb.w * wu1.w;
      fea[((size_t)jrow * NMAX + s) * 16 + u] = fl;
      fea[((size_t)s * NMAX + jrow) * 16 + u] = fu;
      if (u < 2) {
        const float4 t1a = *(const float4*)&t1b[sg][0];
        const float4 t1c = *(const float4*)&t1b[sg][4];
        float e = e2bias
            + t1a.x * we0.x + t1a.y * we0.y + t1a.z * we0.z + t1a.w * we0.w
            + t1c.x * we1.x + t1c.y * we1.y + t1c.z * we1.z + t1c.w * we1.w;
        const size_t idx = (u == 0) ? ((size_t)jrow * NMAX + s)
                                    : ((size_t)s * NMAX + jrow);
        exi[idx] = sgm(e);
      }
    }
    __builtin_amdgcn_wave_barrier();
  }
}

extern "C" void kernel_launch(void* const* d_in, const int* in_sizes, int n_in,
                              void* d_out, int out_size, void* d_ws, size_t ws_size,
                              hipStream_t stream) {
  (void)in_sizes; (void)n_in; (void)out_size; (void)ws_size;
  const float* gene = (const float*)d_in[0];
  const float* entw = (const float*)d_in[1];
  const float* entb = (const float*)d_in[2];
  // d_in[3] node_wih0: multiplies the all-zero input -> unused
  const float* nwih = (const float*)d_in[4];
  const float* nwhh = (const float*)d_in[5];
  const float* nbih = (const float*)d_in[6];
  const float* nbhh = (const float*)d_in[7];
  const float* exw  = (const float*)d_in[8];
  const float* exb  = (const float*)d_in[9];
  const float* enw  = (const float*)d_in[10];
  const float* enb  = (const float*)d_in[11];
  // d_in[12] edge_wih0: unused (zero input)
  const float* ewih = (const float*)d_in[13];
  const float* ewhh = (const float*)d_in[14];
  const float* ebih = (const float*)d_in[15];
  const float* ebhh = (const float*)d_in[16];
  const float* ee1w = (const float*)d_in[17];
  const float* ee1b = (const float*)d_in[18];
  const float* ee2w = (const float*)d_in[19];
  const float* ee2b = (const float*)d_in[20];
  const float* ef1w = (const float*)d_in[21];
  const float* ef1b = (const float*)d_in[22];
  const float* ef2w = (const float*)d_in[23];
  const float* ef2b = (const float*)d_in[24];

  unsigned short* nflat = (unsigned short*)d_ws;  // bf16 [10240][128] = 2.62 MB

  node_kernel<<<4, 512, 0, stream>>>(gene, entw, entb, nwih, nwhh, nbih, nbhh, nflat);
  edge_kernel<<<640, 256, 0, stream>>>(nflat, exw, exb, enw, enb, ewih, ewhh,
                                       ebih, ebhh, ee1w, ee1b, ee2w, ee2b,
                                       ef1w, ef1b, ef2w, ef2b, (float*)d_out);
}

// Round 4
// 778.922 us; speedup vs baseline: 1.3828x; 1.0492x over previous
//
#include <hip/hip_runtime.h>

// GraphGenRnn: node-LSTM (2L, HN=128, 64 seqs, 160 steps) -> node_exit/edge_entry
// -> edge-LSTM (2L, HE=16, 10240 seqs, ragged steps) -> heads -> scatter.
//
// R4: node kernel __launch_bounds__(512, 1). R1/R3 showed VGPR_Count=128 -> the
// 192 weight VGPRs were spilled and reloaded from scratch every step (384KB/step
// per block ~= 6850 cy/step, matching the observed 7900 cy/step). The 2nd
// launch-bounds arg empirically acts as CUDA minBlocksPerCU: (512,2) -> cap 128.
// (512,1) gives budget >=256 under either semantics -> weights stay resident.
// Edge: per-thread L0 weight rows hoisted LDS->regs (64 VGPR), L1 stays in LDS.

typedef __attribute__((ext_vector_type(8))) short short8;
typedef __attribute__((ext_vector_type(4))) float floatx4;

#define NG 64
#define NMAX 161

__device__ __forceinline__ float sgm(float x) {
  return __builtin_amdgcn_rcpf(1.0f + __expf(-x));
}
__device__ __forceinline__ float tanhf_(float x) {
  return 2.0f * __builtin_amdgcn_rcpf(1.0f + __expf(-2.0f * x)) - 1.0f;
}
__device__ __forceinline__ unsigned short f2b(float x) {
  union { float f; unsigned u; } v; v.f = x;
  unsigned r = v.u + 0x7fffu + ((v.u >> 16) & 1u);   // RNE to bf16
  return (unsigned short)(r >> 16);
}
__device__ __forceinline__ float b2f(unsigned short h) {
  union { unsigned u; float f; } v; v.u = ((unsigned)h) << 16; return v.f;
}

// ---------------------------------------------------------------------------
// Node LSTM: 4 blocks x 512 threads (8 waves), 2 waves/SIMD. Block b owns genes
// [16b,16b+16). Wave w owns hidden units [16w,16w+16) for BOTH layers; weights
// persist in VGPRs as bf16 MFMA B-fragments (192 VGPRs). h state double-
// buffered in LDS; 2 barriers per step.
// ---------------------------------------------------------------------------
__global__ __launch_bounds__(512, 1) void node_kernel(
    const float* __restrict__ gene,   // [64][128]
    const float* __restrict__ entw,   // [128][128]
    const float* __restrict__ entb,   // [128]
    const float* __restrict__ nwih,   // [1][512][128]
    const float* __restrict__ nwhh,   // [2][512][128]
    const float* __restrict__ nbih,   // [2][512]
    const float* __restrict__ nbhh,   // [2][512]
    unsigned short* __restrict__ nout) // bf16 [10240][128]
{
  const int tid  = threadIdx.x;
  const int wv   = tid >> 6;
  const int lane = tid & 63;
  const int lo   = lane & 15;
  const int hi   = lane >> 4;
  const int u    = (wv << 4) | lo;   // hidden unit / gate column
  const int nb   = blockIdx.x;

  // row stride 136 shorts = 272B (17x16B): 16B-aligned rows, mild bank alias
  __shared__ __align__(16) unsigned short hA0[2][16][136];
  __shared__ __align__(16) unsigned short hA1[2][16][136];

  // ---- persistent B fragments (bf16): L0 whh (K=128); L1 [wih1|whh1] (K=256)
  short8 B0[4][4];
  short8 B1[4][8];
#pragma unroll
  for (int t = 0; t < 4; ++t) {
    const int n = t * 128 + u;
#pragma unroll
    for (int ks = 0; ks < 4; ++ks) {
      const float* src = nwhh + n * 128 + ks * 32 + hi * 8;
      short8 bfr;
#pragma unroll
      for (int jj = 0; jj < 8; ++jj) bfr[jj] = (short)f2b(src[jj]);
      B0[t][ks] = bfr;
    }
#pragma unroll
    for (int ks = 0; ks < 8; ++ks) {
      const int k = ks * 32 + hi * 8;
      const float* src = (ks < 4) ? (nwih + n * 128 + k)
                                  : (nwhh + 512 * 128 + n * 128 + (k - 128));
      short8 bfr;
#pragma unroll
      for (int jj = 0; jj < 8; ++jj) bfr[jj] = (short)f2b(src[jj]);
      B1[t][ks] = bfr;
    }
  }

  const float bi0 = nbih[u]       + nbhh[u];
  const float bf0 = nbih[128 + u] + nbhh[128 + u];
  const float bg0 = nbih[256 + u] + nbhh[256 + u];
  const float bo0 = nbih[384 + u] + nbhh[384 + u];
  const float bi1 = nbih[512 + u]       + nbhh[512 + u];
  const float bf1 = nbih[512 + 128 + u] + nbhh[512 + 128 + u];
  const float bg1 = nbih[512 + 256 + u] + nbhh[512 + 256 + u];
  const float bo1 = nbih[512 + 384 + u] + nbhh[512 + 384 + u];

  // ---- h_init = relu(gene @ entw^T + entb): 512 threads x 4 units each ----
  {
    const int q  = tid >> 5;            // gene row within block
    const int u4 = (tid & 31) * 4;      // 4 units per thread
    const float* gc = gene + (nb * 16 + q) * 128;
    float acc[4] = { entb[u4], entb[u4 + 1], entb[u4 + 2], entb[u4 + 3] };
    for (int qq = 0; qq < 32; ++qq) {
      const float4 gv = *(const float4*)&gc[qq * 4];
#pragma unroll
      for (int r = 0; r < 4; ++r) {
        const float4 wv2 = *(const float4*)&entw[(u4 + r) * 128 + qq * 4];
        acc[r] += gv.x * wv2.x + gv.y * wv2.y + gv.z * wv2.z + gv.w * wv2.w;
      }
    }
#pragma unroll
    for (int r = 0; r < 4; ++r) {
      const unsigned short hb = f2b(fmaxf(acc[r], 0.0f));
      hA0[0][q][u4 + r] = hb;   // L0 reads h0_{-1} at t=0
      hA1[0][q][u4 + r] = hb;   // L1 reads h1_{-1} at t=0
    }
  }

  float c0[4] = {0.f, 0.f, 0.f, 0.f};
  float c1[4] = {0.f, 0.f, 0.f, 0.f};
  __syncthreads();

  for (int t = 0; t < 160; ++t) {
    const int rb = t & 1, wb = rb ^ 1;
    // ---------- layer 0: gates = h0_{t-1} @ whh0^T + b ----------
    {
      floatx4 a0 = {bi0, bi0, bi0, bi0};
      floatx4 a1 = {bf0, bf0, bf0, bf0};
      floatx4 a2 = {bg0, bg0, bg0, bg0};
      floatx4 a3 = {bo0, bo0, bo0, bo0};
      const unsigned short* ar = &hA0[rb][lo][hi * 8];
#pragma unroll
      for (int ks = 0; ks < 4; ++ks) {
        const short8 afr = *(const short8*)(ar + ks * 32);
        a0 = __builtin_amdgcn_mfma_f32_16x16x32_bf16(afr, B0[0][ks], a0, 0, 0, 0);
        a1 = __builtin_amdgcn_mfma_f32_16x16x32_bf16(afr, B0[1][ks], a1, 0, 0, 0);
        a2 = __builtin_amdgcn_mfma_f32_16x16x32_bf16(afr, B0[2][ks], a2, 0, 0, 0);
        a3 = __builtin_amdgcn_mfma_f32_16x16x32_bf16(afr, B0[3][ks], a3, 0, 0, 0);
      }
#pragma unroll
      for (int r = 0; r < 4; ++r) {
        const float iv = sgm(a0[r]);
        const float fv = sgm(a1[r]);
        const float gv = tanhf_(a2[r]);
        const float ov = sgm(a3[r]);
        const float cn = fv * c0[r] + iv * gv;
        c0[r] = cn;
        hA0[wb][hi * 4 + r][u] = f2b(ov * tanhf_(cn));
      }
    }
    __syncthreads();   // h0_t visible to all waves

    // ---------- layer 1: gates = [h0_t | h1_{t-1}] @ [wih|whh1]^T + b ----------
    {
      floatx4 a0 = {bi1, bi1, bi1, bi1};
      floatx4 a1 = {bf1, bf1, bf1, bf1};
      floatx4 a2 = {bg1, bg1, bg1, bg1};
      floatx4 a3 = {bo1, bo1, bo1, bo1};
      const unsigned short* a0r = &hA0[wb][lo][hi * 8];  // h0_t
      const unsigned short* a1r = &hA1[rb][lo][hi * 8];  // h1_{t-1}
#pragma unroll
      for (int ks = 0; ks < 4; ++ks) {
        const short8 afr = *(const short8*)(a0r + ks * 32);
        a0 = __builtin_amdgcn_mfma_f32_16x16x32_bf16(afr, B1[0][ks], a0, 0, 0, 0);
        a1 = __builtin_amdgcn_mfma_f32_16x16x32_bf16(afr, B1[1][ks], a1, 0, 0, 0);
        a2 = __builtin_amdgcn_mfma_f32_16x16x32_bf16(afr, B1[2][ks], a2, 0, 0, 0);
        a3 = __builtin_amdgcn_mfma_f32_16x16x32_bf16(afr, B1[3][ks], a3, 0, 0, 0);
      }
#pragma unroll
      for (int ks = 0; ks < 4; ++ks) {
        const short8 afr = *(const short8*)(a1r + ks * 32);
        a0 = __builtin_amdgcn_mfma_f32_16x16x32_bf16(afr, B1[0][ks + 4], a0, 0, 0, 0);
        a1 = __builtin_amdgcn_mfma_f32_16x16x32_bf16(afr, B1[1][ks + 4], a1, 0, 0, 0);
        a2 = __builtin_amdgcn_mfma_f32_16x16x32_bf16(afr, B1[2][ks + 4], a2, 0, 0, 0);
        a3 = __builtin_amdgcn_mfma_f32_16x16x32_bf16(afr, B1[3][ks + 4], a3, 0, 0, 0);
      }
      const size_t obase = (size_t)((159 - t) * 64 + nb * 16) * 128;
#pragma unroll
      for (int r = 0; r < 4; ++r) {
        const float iv = sgm(a0[r]);
        const float fv = sgm(a1[r]);
        const float gv = tanhf_(a2[r]);
        const float ov = sgm(a3[r]);
        const float cn = fv * c1[r] + iv * gv;
        c1[r] = cn;
        const unsigned short hb = f2b(ov * tanhf_(cn));
        const int q = hi * 4 + r;
        hA1[wb][q][u] = hb;
        nout[obase + (size_t)q * 128 + u] = hb;
      }
    }
    __syncthreads();   // h1_t visible; old buffers free for overwrite
  }
}

// ---------------------------------------------------------------------------
// Edge: 640 blocks x 256 threads; block b owns sequences k in [16b,16b+16),
// uniform trip count jrow = 160 - b/4. Thread = (seq sg, unit u). L0 weights
// hoisted to registers (loop-invariant, 64 VGPR); L1 weights in LDS. Per-step
// LDS traffic is intra-wave so the step loop has NO block barriers.
// ---------------------------------------------------------------------------
__global__ __launch_bounds__(256, 1) void edge_kernel(
    const unsigned short* __restrict__ nflat, // bf16 [10240][128]
    const float* __restrict__ exw, const float* __restrict__ exb,   // [32][128],[32]
    const float* __restrict__ enw, const float* __restrict__ enb,   // [16][32],[16]
    const float* __restrict__ ewih,  // [1][64][16]
    const float* __restrict__ ewhh,  // [2][64][16]
    const float* __restrict__ ebih, const float* __restrict__ ebhh, // [2][64]
    const float* __restrict__ ee1w, const float* __restrict__ ee1b,
    const float* __restrict__ ee2w, const float* __restrict__ ee2b,
    const float* __restrict__ ef1w, const float* __restrict__ ef1b,
    const float* __restrict__ ef2w, const float* __restrict__ ef2b,
    float* __restrict__ out)
{
  const int tid = threadIdx.x;
  const int sg  = tid >> 4;
  const int u   = tid & 15;
  const int b   = blockIdx.x;
  const int kbase = b * 16;
  const int jrow  = 160 - (b >> 2);   // = row(k) for all k in this block

  __shared__ __align__(16) float s_nf[16][132];
  __shared__ __align__(16) float s_enw[16][36];
  __shared__ __align__(16) float s_w0[64][20];
  __shared__ __align__(16) float s_w1[64][36];
  __shared__ __align__(16) float s_ee1[8][20];
  __shared__ __align__(16) float s_ef1[8][20];
  __shared__ __align__(16) float s_ef2[32][8];
  __shared__ __align__(16) float s_ee2[16];
  __shared__ float s_be0[64], s_be1[64];
  __shared__ float s_exb[32], s_enb[16], s_e1b[8], s_e2b[2], s_f1b[8], s_f2b[32];
  __shared__ __align__(16) float h0b[16][20];
  __shared__ __align__(16) float h1b[16][20];
  __shared__ __align__(16) float t1b[16][12];
  __shared__ __align__(16) float t2b[16][12];
  __shared__ __align__(16) float x32[16][36];

  for (int i = tid; i < 16 * 128; i += 256)
    s_nf[i >> 7][i & 127] = b2f(nflat[(size_t)(kbase + (i >> 7)) * 128 + (i & 127)]);
  for (int i = tid; i < 16 * 32; i += 256) s_enw[i >> 5][i & 31] = enw[i];
  for (int i = tid; i < 64 * 16; i += 256) {
    s_w0[i >> 4][i & 15] = ewhh[i];                 // layer0 whh
    s_w1[i >> 4][i & 15] = ewih[i];                 // layer1 wih
    s_w1[i >> 4][16 + (i & 15)] = ewhh[1024 + i];   // layer1 whh
  }
  for (int i = tid; i < 8 * 16; i += 256) { s_ee1[i >> 4][i & 15] = ee1w[i]; s_ef1[i >> 4][i & 15] = ef1w[i]; }
  for (int i = tid; i < 32 * 8; i += 256) s_ef2[i >> 3][i & 7] = ef2w[i];
  if (tid < 64) { s_be0[tid] = ebih[tid] + ebhh[tid]; s_be1[tid] = ebih[64 + tid] + ebhh[64 + tid]; }
  if (tid < 32) { s_exb[tid] = exb[tid]; s_f2b[tid] = ef2b[tid]; }
  if (tid < 16) { s_enb[tid] = enb[tid]; s_ee2[tid] = ee2w[tid]; }
  if (tid < 8)  { s_e1b[tid] = ee1b[tid]; s_f1b[tid] = ef1b[tid]; }
  if (tid < 2)  s_e2b[tid] = ee2b[tid];

  // zero the (never-written) diagonal; graph g == b for first 64 blocks
  if (b < NG) {
    for (int d = tid; d < NMAX; d += 256) {
      out[(size_t)b * (NMAX * NMAX) + (size_t)d * NMAX + d] = 0.0f;
      float* fb = out + (size_t)NG * NMAX * NMAX
                + ((size_t)b * NMAX * NMAX + (size_t)d * NMAX + d) * 16;
#pragma unroll
      for (int q = 0; q < 16; ++q) fb[q] = 0.0f;
    }
  }
  __syncthreads();   // the ONLY block barrier

  // ---- hoisted per-thread constants (read-only LDS -> regs) ----
  const float be0i = s_be0[u], be0f = s_be0[16 + u], be0g = s_be0[32 + u], be0o = s_be0[48 + u];
  const float be1i = s_be1[u], be1f = s_be1[16 + u], be1g = s_be1[32 + u], be1o = s_be1[48 + u];
  const float hbias = (u < 8) ? s_e1b[u] : s_f1b[u - 8];
  const float f2bl = s_f2b[u], f2bu = s_f2b[16 + u];
  const float4 wl0 = *(const float4*)&s_ef2[u][0];
  const float4 wl1 = *(const float4*)&s_ef2[u][4];
  const float4 wu0 = *(const float4*)&s_ef2[16 + u][0];
  const float4 wu1 = *(const float4*)&s_ef2[16 + u][4];
  // e-head weights for lanes u<2 (row u of ee2)
  const int ue = (u < 2) ? u : 0;
  const float4 we0 = *(const float4*)&s_ee2[ue * 8];
  const float4 we1 = *(const float4*)&s_ee2[ue * 8 + 4];
  const float e2bias = (u < 2) ? s_e2b[u] : 0.0f;
  // L0 weight rows u,16+u,32+u,48+u -> registers (loop-invariant, 64 VGPR)
  float4 W0[4][4];
#pragma unroll
  for (int g = 0; g < 4; ++g)
#pragma unroll
    for (int qq = 0; qq < 4; ++qq)
      W0[g][qq] = *(const float4*)&s_w0[g * 16 + u][qq * 4];

  // ---- h0e = relu(relu(nf @ exw^T + exb) @ enw^T + enb) ----
  {
    float acc0 = s_exb[u], acc1 = s_exb[16 + u];
    const float* w0p = exw + u * 128;
    const float* w1p = exw + (16 + u) * 128;
    for (int qq = 0; qq < 32; ++qq) {
      const float4 nv  = *(const float4*)&s_nf[sg][qq * 4];
      const float4 w0v = *(const float4*)&w0p[qq * 4];
      const float4 w1v = *(const float4*)&w1p[qq * 4];
      acc0 += nv.x * w0v.x + nv.y * w0v.y + nv.z * w0v.z + nv.w * w0v.w;
      acc1 += nv.x * w1v.x + nv.y * w1v.y + nv.z * w1v.z + nv.w * w1v.w;
    }
    x32[sg][u] = fmaxf(acc0, 0.0f);
    x32[sg][16 + u] = fmaxf(acc1, 0.0f);
  }
  __builtin_amdgcn_wave_barrier();
  float c0 = 0.0f, c1 = 0.0f;
  {
    float acc = s_enb[u];
#pragma unroll
    for (int qq = 0; qq < 8; ++qq) {
      const float4 xv  = *(const float4*)&x32[sg][qq * 4];
      const float4 wv2 = *(const float4*)&s_enw[u][qq * 4];
      acc += xv.x * wv2.x + xv.y * wv2.y + xv.z * wv2.z + xv.w * wv2.w;
    }
    const float h0e = fmaxf(acc, 0.0f);
    h0b[sg][u] = h0e;
    h1b[sg][u] = h0e;
  }
  __builtin_amdgcn_wave_barrier();

  const int gid = (kbase & 63) + sg;
  float* exi = out + (size_t)gid * (NMAX * NMAX);
  float* fea = out + (size_t)NG * NMAX * NMAX + (size_t)gid * (NMAX * NMAX) * 16;

  for (int s = 0; s < jrow; ++s) {
    float gi, gf, gg, go;
    { // layer 0 gate dots: rows u, 16+u, 32+u, 48+u (weights in regs)
      float ai = be0i, af = be0f, ag = be0g, ao = be0o;
#pragma unroll
      for (int qq = 0; qq < 4; ++qq) {
        const float4 hv = *(const float4*)&h0b[sg][qq * 4];
        ai += hv.x * W0[0][qq].x + hv.y * W0[0][qq].y + hv.z * W0[0][qq].z + hv.w * W0[0][qq].w;
        af += hv.x * W0[1][qq].x + hv.y * W0[1][qq].y + hv.z * W0[1][qq].z + hv.w * W0[1][qq].w;
        ag += hv.x * W0[2][qq].x + hv.y * W0[2][qq].y + hv.z * W0[2][qq].z + hv.w * W0[2][qq].w;
        ao += hv.x * W0[3][qq].x + hv.y * W0[3][qq].y + hv.z * W0[3][qq].z + hv.w * W0[3][qq].w;
      }
      gi = ai; gf = af; gg = ag; go = ao;
    }
    __builtin_amdgcn_wave_barrier();
    {
      const float iv = sgm(gi), fv = sgm(gf), gv = tanhf_(gg), ov = sgm(go);
      c0 = fv * c0 + iv * gv;
      h0b[sg][u] = ov * tanhf_(c0);
    }
    __builtin_amdgcn_wave_barrier();
    { // layer 1 gate dots over [h0new | h1]
      float ai = be1i, af = be1f, ag = be1g, ao = be1o;
#pragma unroll
      for (int qq = 0; qq < 4; ++qq) {
        const float4 hv = *(const float4*)&h0b[sg][qq * 4];
        const float4 wi = *(const float4*)&s_w1[u][qq * 4];
        const float4 wf = *(const float4*)&s_w1[16 + u][qq * 4];
        const float4 wg = *(const float4*)&s_w1[32 + u][qq * 4];
        const float4 wo = *(const float4*)&s_w1[48 + u][qq * 4];
        ai += hv.x * wi.x + hv.y * wi.y + hv.z * wi.z + hv.w * wi.w;
        af += hv.x * wf.x + hv.y * wf.y + hv.z * wf.z + hv.w * wf.w;
        ag += hv.x * wg.x + hv.y * wg.y + hv.z * wg.z + hv.w * wg.w;
        ao += hv.x * wo.x + hv.y * wo.y + hv.z * wo.z + hv.w * wo.w;
      }
#pragma unroll
      for (int qq = 0; qq < 4; ++qq) {
        const float4 hv = *(const float4*)&h1b[sg][qq * 4];
        const float4 wi = *(const float4*)&s_w1[u][16 + qq * 4];
        const float4 wf = *(const float4*)&s_w1[16 + u][16 + qq * 4];
        const float4 wg = *(const float4*)&s_w1[32 + u][16 + qq * 4];
        const float4 wo = *(const float4*)&s_w1[48 + u][16 + qq * 4];
        ai += hv.x * wi.x + hv.y * wi.y + hv.z * wi.z + hv.w * wi.w;
        af += hv.x * wf.x + hv.y * wf.y + hv.z * wf.z + hv.w * wf.w;
        ag += hv.x * wg.x + hv.y * wg.y + hv.z * wg.z + hv.w * wg.w;
        ao += hv.x * wo.x + hv.y * wo.y + hv.z * wo.z + hv.w * wo.w;
      }
      gi = ai; gf = af; gg = ag; go = ao;
    }
    __builtin_amdgcn_wave_barrier();
    {
      const float iv = sgm(gi), fv = sgm(gf), gv = tanhf_(gg), ov = sgm(go);
      c1 = fv * c1 + iv * gv;
      h1b[sg][u] = ov * tanhf_(c1);   // = eh[s]
    }
    __builtin_amdgcn_wave_barrier();
    // ---- heads ----
    if (u < 8) {
      float a = hbias;
#pragma unroll
      for (int qq = 0; qq < 4; ++qq) {
        const float4 hv  = *(const float4*)&h1b[sg][qq * 4];
        const float4 wv2 = *(const float4*)&s_ee1[u][qq * 4];
        a += hv.x * wv2.x + hv.y * wv2.y + hv.z * wv2.z + hv.w * wv2.w;
      }
      t1b[sg][u] = fmaxf(a, 0.0f);
    } else {
      const int p = u - 8;
      float a = hbias;
#pragma unroll
      for (int qq = 0; qq < 4; ++qq) {
        const float4 hv  = *(const float4*)&h1b[sg][qq * 4];
        const float4 wv2 = *(const float4*)&s_ef1[p][qq * 4];
        a += hv.x * wv2.x + hv.y * wv2.y + hv.z * wv2.z + hv.w * wv2.w;
      }
      t2b[sg][p] = fmaxf(a, 0.0f);
    }
    __builtin_amdgcn_wave_barrier();
    {
      const float4 ta = *(const float4*)&t2b[sg][0];
      const float4 tb = *(const float4*)&t2b[sg][4];
      const float fl = f2bl
          + ta.x * wl0.x + ta.y * wl0.y + ta.z * wl0.z + ta.w * wl0.w
          + tb.x * wl1.x + tb.y * wl1.y + tb.z * wl1.z + tb.w * wl1.w;
      const float fu = f2bu
          + ta.x * wu0.x + ta.y * wu0.y + ta.z * wu0.z + ta.w * wu0.w
          + tb.x * wu1.x + tb.y * wu1.y + tb.z * wu1.z + tb.w * wu1.w;
      fea[((size_t)jrow * NMAX + s) * 16 + u] = fl;
      fea[((size_t)s * NMAX + jrow) * 16 + u] = fu;
      if (u < 2) {
        const float4 t1a = *(const float4*)&t1b[sg][0];
        const float4 t1c = *(const float4*)&t1b[sg][4];
        float e = e2bias
            + t1a.x * we0.x + t1a.y * we0.y + t1a.z * we0.z + t1a.w * we0.w
            + t1c.x * we1.x + t1c.y * we1.y + t1c.z * we1.z + t1c.w * we1.w;
        const size_t idx = (u == 0) ? ((size_t)jrow * NMAX + s)
                                    : ((size_t)s * NMAX + jrow);
        exi[idx] = sgm(e);
      }
    }
    __builtin_amdgcn_wave_barrier();
  }
}

extern "C" void kernel_launch(void* const* d_in, const int* in_sizes, int n_in,
                              void* d_out, int out_size, void* d_ws, size_t ws_size,
                              hipStream_t stream) {
  (void)in_sizes; (void)n_in; (void)out_size; (void)ws_size;
  const float* gene = (const float*)d_in[0];
  const float* entw = (const float*)d_in[1];
  const float* entb = (const float*)d_in[2];
  // d_in[3] node_wih0: multiplies the all-zero input -> unused
  const float* nwih = (const float*)d_in[4];
  const float* nwhh = (const float*)d_in[5];
  const float* nbih = (const float*)d_in[6];
  const float* nbhh = (const float*)d_in[7];
  const float* exw  = (const float*)d_in[8];
  const float* exb  = (const float*)d_in[9];
  const float* enw  = (const float*)d_in[10];
  const float* enb  = (const float*)d_in[11];
  // d_in[12] edge_wih0: unused (zero input)
  const float* ewih = (const float*)d_in[13];
  const float* ewhh = (const float*)d_in[14];
  const float* ebih = (const float*)d_in[15];
  const float* ebhh = (const float*)d_in[16];
  const float* ee1w = (const float*)d_in[17];
  const float* ee1b = (const float*)d_in[18];
  const float* ee2w = (const float*)d_in[19];
  const float* ee2b = (const float*)d_in[20];
  const float* ef1w = (const float*)d_in[21];
  const float* ef1b = (const float*)d_in[22];
  const float* ef2w = (const float*)d_in[23];
  const float* ef2b = (const float*)d_in[24];

  unsigned short* nflat = (unsigned short*)d_ws;  // bf16 [10240][128] = 2.62 MB

  node_kernel<<<4, 512, 0, stream>>>(gene, entw, entb, nwih, nwhh, nbih, nbhh, nflat);
  edge_kernel<<<640, 256, 0, stream>>>(nflat, exw, exb, enw, enb, ewih, ewhh,
                                       ebih, ebhh, ee1w, ee1b, ee2w, ee2b,
                                       ef1w, ef1b, ef2w, ef2b, (float*)d_out);
}

// Round 5
// 720.753 us; speedup vs baseline: 1.4944x; 1.0807x over previous
//
#include <hip/hip_runtime.h>

// GraphGenRnn — R5: node LSTM split into 3 kernels so per-wave weights fit the
// empirical 128-VGPR cap for 512-thread blocks (launch_bounds hints R3/R4
// failed to lift it; weights were spilling to scratch every step):
//   node_l0: L0 recurrence only (whh0 = 64 VGPR/lane), streams h0_t to ws
//   xgemm:   X[t] = h0_t @ wih1^T  (640-block MFMA GEMM, parallel)
//   node_l1: L1 recurrence only (whh1 = 64 VGPR/lane), adds X per step
// Edge kernel unchanged from R4.

typedef __attribute__((ext_vector_type(8))) short short8;
typedef __attribute__((ext_vector_type(4))) short short4v;
typedef __attribute__((ext_vector_type(4))) float floatx4;

#define NG 64
#define NMAX 161

__device__ __forceinline__ float sgm(float x) {
  return __builtin_amdgcn_rcpf(1.0f + __expf(-x));
}
__device__ __forceinline__ float tanhf_(float x) {
  return 2.0f * __builtin_amdgcn_rcpf(1.0f + __expf(-2.0f * x)) - 1.0f;
}
__device__ __forceinline__ unsigned short f2b(float x) {
  union { float f; unsigned u; } v; v.f = x;
  unsigned r = v.u + 0x7fffu + ((v.u >> 16) & 1u);   // RNE to bf16
  return (unsigned short)(r >> 16);
}
__device__ __forceinline__ float b2f(unsigned short h) {
  union { unsigned u; float f; } v; v.u = ((unsigned)h) << 16; return v.f;
}

// ---------------------------------------------------------------------------
// node_l0: 4 blocks x 512 threads (8 waves). Block b: genes [16b,16b+16).
// Wave w: units [16w,16w+16), 4 gate col-tiles, whh0 in 64 VGPRs. h0 state
// double-buffered in LDS, 1 barrier/step. Writes h0w[t][g][u] bf16 and
// hinit[g][u] bf16 (the replicated initial hidden for L1).
// ---------------------------------------------------------------------------
__global__ __launch_bounds__(512) void node_l0(
    const float* __restrict__ gene,   // [64][128]
    const float* __restrict__ entw,   // [128][128]
    const float* __restrict__ entb,   // [128]
    const float* __restrict__ nwhh,   // [2][512][128] (layer0 = first half)
    const float* __restrict__ nbih,   // [2][512]
    const float* __restrict__ nbhh,   // [2][512]
    unsigned short* __restrict__ h0w,   // bf16 [160][64][128]
    unsigned short* __restrict__ hinit) // bf16 [64][128]
{
  const int tid  = threadIdx.x;
  const int wv   = tid >> 6;
  const int lane = tid & 63;
  const int lo   = lane & 15;
  const int hi   = lane >> 4;
  const int u    = (wv << 4) | lo;
  const int nb   = blockIdx.x;

  __shared__ __align__(16) unsigned short hA0[2][16][136];

  // whh0 B-fragments: 4 gates x 4 K-slices = 64 VGPRs
  short8 B0[4][4];
#pragma unroll
  for (int t = 0; t < 4; ++t) {
    const int n = t * 128 + u;
#pragma unroll
    for (int ks = 0; ks < 4; ++ks) {
      const float* src = nwhh + n * 128 + ks * 32 + hi * 8;
      short8 bfr;
#pragma unroll
      for (int jj = 0; jj < 8; ++jj) bfr[jj] = (short)f2b(src[jj]);
      B0[t][ks] = bfr;
    }
  }

  const float bi0 = nbih[u]       + nbhh[u];
  const float bf0 = nbih[128 + u] + nbhh[128 + u];
  const float bg0 = nbih[256 + u] + nbhh[256 + u];
  const float bo0 = nbih[384 + u] + nbhh[384 + u];

  // h_init = relu(gene @ entw^T + entb): 512 threads x 4 units
  {
    const int q  = tid >> 5;
    const int u4 = (tid & 31) * 4;
    const float* gc = gene + (nb * 16 + q) * 128;
    float acc[4] = { entb[u4], entb[u4 + 1], entb[u4 + 2], entb[u4 + 3] };
    for (int qq = 0; qq < 32; ++qq) {
      const float4 gv = *(const float4*)&gc[qq * 4];
#pragma unroll
      for (int r = 0; r < 4; ++r) {
        const float4 wv2 = *(const float4*)&entw[(u4 + r) * 128 + qq * 4];
        acc[r] += gv.x * wv2.x + gv.y * wv2.y + gv.z * wv2.z + gv.w * wv2.w;
      }
    }
#pragma unroll
    for (int r = 0; r < 4; ++r) {
      const unsigned short hb = f2b(fmaxf(acc[r], 0.0f));
      hA0[0][q][u4 + r] = hb;
      hinit[(size_t)(nb * 16 + q) * 128 + u4 + r] = hb;
    }
  }

  float c0[4] = {0.f, 0.f, 0.f, 0.f};
  __syncthreads();

  for (int t = 0; t < 160; ++t) {
    const int rb = t & 1, wb = rb ^ 1;
    floatx4 a0 = {bi0, bi0, bi0, bi0};
    floatx4 a1 = {bf0, bf0, bf0, bf0};
    floatx4 a2 = {bg0, bg0, bg0, bg0};
    floatx4 a3 = {bo0, bo0, bo0, bo0};
    const unsigned short* ar = &hA0[rb][lo][hi * 8];
#pragma unroll
    for (int ks = 0; ks < 4; ++ks) {
      const short8 afr = *(const short8*)(ar + ks * 32);
      a0 = __builtin_amdgcn_mfma_f32_16x16x32_bf16(afr, B0[0][ks], a0, 0, 0, 0);
      a1 = __builtin_amdgcn_mfma_f32_16x16x32_bf16(afr, B0[1][ks], a1, 0, 0, 0);
      a2 = __builtin_amdgcn_mfma_f32_16x16x32_bf16(afr, B0[2][ks], a2, 0, 0, 0);
      a3 = __builtin_amdgcn_mfma_f32_16x16x32_bf16(afr, B0[3][ks], a3, 0, 0, 0);
    }
    const size_t obase = (size_t)(t * 64 + nb * 16) * 128;
#pragma unroll
    for (int r = 0; r < 4; ++r) {
      const float iv = sgm(a0[r]);
      const float fv = sgm(a1[r]);
      const float gv = tanhf_(a2[r]);
      const float ov = sgm(a3[r]);
      const float cn = fv * c0[r] + iv * gv;
      c0[r] = cn;
      const unsigned short hb = f2b(ov * tanhf_(cn));
      const int q = hi * 4 + r;
      hA0[wb][q][u] = hb;
      h0w[obase + (size_t)q * 128 + u] = hb;
    }
    __syncthreads();
  }
}

// ---------------------------------------------------------------------------
// xgemm: X2[t][col][g] = sum_u h0w[t][g][u] * wih1[col][u]   (bf16 out)
// grid (160, 4) x 256 thr. Block (bt,bn): rows = all 64 genes of step bt,
// cols [128*bn, 128*bn+128). wih1 tile staged in LDS as bf16.
// ---------------------------------------------------------------------------
__global__ __launch_bounds__(256) void xgemm(
    const unsigned short* __restrict__ h0w,  // bf16 [160][64][128]
    const float* __restrict__ nwih,          // [512][128] (layer-1 wih)
    unsigned short* __restrict__ X2)         // bf16 [160][512][64]
{
  const int tid = threadIdx.x;
  const int wv  = tid >> 6;
  const int lane = tid & 63;
  const int lo  = lane & 15;
  const int hi  = lane >> 4;
  const int bt  = blockIdx.x;
  const int bn  = blockIdx.y;

  __shared__ __align__(16) unsigned short s_b[128][136];

  for (int i = tid; i < 128 * 32; i += 256) {
    const int nc = i >> 5, k4 = (i & 31) * 4;
    const float4 w = *(const float4*)&nwih[(size_t)(bn * 128 + nc) * 128 + k4];
    s_b[nc][k4]     = f2b(w.x);
    s_b[nc][k4 + 1] = f2b(w.y);
    s_b[nc][k4 + 2] = f2b(w.z);
    s_b[nc][k4 + 3] = f2b(w.w);
  }
  __syncthreads();

  floatx4 acc[8];
#pragma unroll
  for (int nt = 0; nt < 8; ++nt) acc[nt] = (floatx4){0.f, 0.f, 0.f, 0.f};

  const unsigned short* arow = h0w + (size_t)(bt * 64 + wv * 16 + lo) * 128 + hi * 8;
#pragma unroll
  for (int ks = 0; ks < 4; ++ks) {
    const short8 afr = *(const short8*)(arow + ks * 32);
#pragma unroll
    for (int nt = 0; nt < 8; ++nt) {
      const short8 bfr = *(const short8*)&s_b[nt * 16 + lo][ks * 32 + hi * 8];
      acc[nt] = __builtin_amdgcn_mfma_f32_16x16x32_bf16(afr, bfr, acc[nt], 0, 0, 0);
    }
  }

  // write X2[(bt*512 + bn*128 + nt*16 + lo)*64 + wv*16 + hi*4 + r]
#pragma unroll
  for (int nt = 0; nt < 8; ++nt) {
    const size_t colbase = ((size_t)bt * 512 + bn * 128 + nt * 16 + lo) * 64 + wv * 16 + hi * 4;
#pragma unroll
    for (int r = 0; r < 4; ++r)
      X2[colbase + r] = f2b(acc[nt][r]);
  }
}

// ---------------------------------------------------------------------------
// node_l1: 4 blocks x 512 threads. Same wave layout as node_l0 but for layer 1:
// whh1 in 64 VGPRs; input-half read from X2 (4 x b64 loads/lane/step).
// Writes nflat[k][u] bf16 with k = (159-t)*64 + gene.
// ---------------------------------------------------------------------------
__global__ __launch_bounds__(512) void node_l1(
    const unsigned short* __restrict__ hinit, // bf16 [64][128]
    const unsigned short* __restrict__ X2,    // bf16 [160][512][64]
    const float* __restrict__ nwhh,           // [2][512][128] (layer1 = second half)
    const float* __restrict__ nbih,           // [2][512]
    const float* __restrict__ nbhh,           // [2][512]
    unsigned short* __restrict__ nout)        // bf16 [10240][128]
{
  const int tid  = threadIdx.x;
  const int wv   = tid >> 6;
  const int lane = tid & 63;
  const int lo   = lane & 15;
  const int hi   = lane >> 4;
  const int u    = (wv << 4) | lo;
  const int nb   = blockIdx.x;

  __shared__ __align__(16) unsigned short hA1[2][16][136];

  // whh1 B-fragments: 64 VGPRs
  short8 B1[4][4];
#pragma unroll
  for (int t = 0; t < 4; ++t) {
    const int n = t * 128 + u;
#pragma unroll
    for (int ks = 0; ks < 4; ++ks) {
      const float* src = nwhh + 512 * 128 + n * 128 + ks * 32 + hi * 8;
      short8 bfr;
#pragma unroll
      for (int jj = 0; jj < 8; ++jj) bfr[jj] = (short)f2b(src[jj]);
      B1[t][ks] = bfr;
    }
  }

  const float bi1 = nbih[512 + u]       + nbhh[512 + u];
  const float bf1 = nbih[512 + 128 + u] + nbhh[512 + 128 + u];
  const float bg1 = nbih[512 + 256 + u] + nbhh[512 + 256 + u];
  const float bo1 = nbih[512 + 384 + u] + nbhh[512 + 384 + u];

  // load h1_{-1} = hinit into hA1[0]
  {
    const int q  = tid >> 5;
    const int u4 = (tid & 31) * 4;
    const short4v hv = *(const short4v*)&hinit[(size_t)(nb * 16 + q) * 128 + u4];
    hA1[0][q][u4]     = (unsigned short)hv[0];
    hA1[0][q][u4 + 1] = (unsigned short)hv[1];
    hA1[0][q][u4 + 2] = (unsigned short)hv[2];
    hA1[0][q][u4 + 3] = (unsigned short)hv[3];
  }

  float c1[4] = {0.f, 0.f, 0.f, 0.f};
  __syncthreads();

  for (int t = 0; t < 160; ++t) {
    const int rb = t & 1, wb = rb ^ 1;
    // input-half loads (issued early; consumed in epilogue)
    const size_t xb = ((size_t)t * 512 + u) * 64 + nb * 16 + hi * 4;
    const short4v x0 = *(const short4v*)&X2[xb];
    const short4v x1 = *(const short4v*)&X2[xb + (size_t)128 * 64];
    const short4v x2 = *(const short4v*)&X2[xb + (size_t)256 * 64];
    const short4v x3 = *(const short4v*)&X2[xb + (size_t)384 * 64];

    floatx4 a0 = {bi1, bi1, bi1, bi1};
    floatx4 a1 = {bf1, bf1, bf1, bf1};
    floatx4 a2 = {bg1, bg1, bg1, bg1};
    floatx4 a3 = {bo1, bo1, bo1, bo1};
    const unsigned short* ar = &hA1[rb][lo][hi * 8];
#pragma unroll
    for (int ks = 0; ks < 4; ++ks) {
      const short8 afr = *(const short8*)(ar + ks * 32);
      a0 = __builtin_amdgcn_mfma_f32_16x16x32_bf16(afr, B1[0][ks], a0, 0, 0, 0);
      a1 = __builtin_amdgcn_mfma_f32_16x16x32_bf16(afr, B1[1][ks], a1, 0, 0, 0);
      a2 = __builtin_amdgcn_mfma_f32_16x16x32_bf16(afr, B1[2][ks], a2, 0, 0, 0);
      a3 = __builtin_amdgcn_mfma_f32_16x16x32_bf16(afr, B1[3][ks], a3, 0, 0, 0);
    }
    const size_t obase = (size_t)((159 - t) * 64 + nb * 16) * 128;
#pragma unroll
    for (int r = 0; r < 4; ++r) {
      const float iv = sgm(a0[r] + b2f((unsigned short)x0[r]));
      const float fv = sgm(a1[r] + b2f((unsigned short)x1[r]));
      const float gv = tanhf_(a2[r] + b2f((unsigned short)x2[r]));
      const float ov = sgm(a3[r] + b2f((unsigned short)x3[r]));
      const float cn = fv * c1[r] + iv * gv;
      c1[r] = cn;
      const unsigned short hb = f2b(ov * tanhf_(cn));
      const int q = hi * 4 + r;
      hA1[wb][q][u] = hb;
      nout[obase + (size_t)q * 128 + u] = hb;
    }
    __syncthreads();
  }
}

// ---------------------------------------------------------------------------
// Edge: unchanged from R4.
// ---------------------------------------------------------------------------
__global__ __launch_bounds__(256, 1) void edge_kernel(
    const unsigned short* __restrict__ nflat, // bf16 [10240][128]
    const float* __restrict__ exw, const float* __restrict__ exb,   // [32][128],[32]
    const float* __restrict__ enw, const float* __restrict__ enb,   // [16][32],[16]
    const float* __restrict__ ewih,  // [1][64][16]
    const float* __restrict__ ewhh,  // [2][64][16]
    const float* __restrict__ ebih, const float* __restrict__ ebhh, // [2][64]
    const float* __restrict__ ee1w, const float* __restrict__ ee1b,
    const float* __restrict__ ee2w, const float* __restrict__ ee2b,
    const float* __restrict__ ef1w, const float* __restrict__ ef1b,
    const float* __restrict__ ef2w, const float* __restrict__ ef2b,
    float* __restrict__ out)
{
  const int tid = threadIdx.x;
  const int sg  = tid >> 4;
  const int u   = tid & 15;
  const int b   = blockIdx.x;
  const int kbase = b * 16;
  const int jrow  = 160 - (b >> 2);

  __shared__ __align__(16) float s_nf[16][132];
  __shared__ __align__(16) float s_enw[16][36];
  __shared__ __align__(16) float s_w0[64][20];
  __shared__ __align__(16) float s_w1[64][36];
  __shared__ __align__(16) float s_ee1[8][20];
  __shared__ __align__(16) float s_ef1[8][20];
  __shared__ __align__(16) float s_ef2[32][8];
  __shared__ __align__(16) float s_ee2[16];
  __shared__ float s_be0[64], s_be1[64];
  __shared__ float s_exb[32], s_enb[16], s_e1b[8], s_e2b[2], s_f1b[8], s_f2b[32];
  __shared__ __align__(16) float h0b[16][20];
  __shared__ __align__(16) float h1b[16][20];
  __shared__ __align__(16) float t1b[16][12];
  __shared__ __align__(16) float t2b[16][12];
  __shared__ __align__(16) float x32[16][36];

  for (int i = tid; i < 16 * 128; i += 256)
    s_nf[i >> 7][i & 127] = b2f(nflat[(size_t)(kbase + (i >> 7)) * 128 + (i & 127)]);
  for (int i = tid; i < 16 * 32; i += 256) s_enw[i >> 5][i & 31] = enw[i];
  for (int i = tid; i < 64 * 16; i += 256) {
    s_w0[i >> 4][i & 15] = ewhh[i];
    s_w1[i >> 4][i & 15] = ewih[i];
    s_w1[i >> 4][16 + (i & 15)] = ewhh[1024 + i];
  }
  for (int i = tid; i < 8 * 16; i += 256) { s_ee1[i >> 4][i & 15] = ee1w[i]; s_ef1[i >> 4][i & 15] = ef1w[i]; }
  for (int i = tid; i < 32 * 8; i += 256) s_ef2[i >> 3][i & 7] = ef2w[i];
  if (tid < 64) { s_be0[tid] = ebih[tid] + ebhh[tid]; s_be1[tid] = ebih[64 + tid] + ebhh[64 + tid]; }
  if (tid < 32) { s_exb[tid] = exb[tid]; s_f2b[tid] = ef2b[tid]; }
  if (tid < 16) { s_enb[tid] = enb[tid]; s_ee2[tid] = ee2w[tid]; }
  if (tid < 8)  { s_e1b[tid] = ee1b[tid]; s_f1b[tid] = ef1b[tid]; }
  if (tid < 2)  s_e2b[tid] = ee2b[tid];

  if (b < NG) {
    for (int d = tid; d < NMAX; d += 256) {
      out[(size_t)b * (NMAX * NMAX) + (size_t)d * NMAX + d] = 0.0f;
      float* fb = out + (size_t)NG * NMAX * NMAX
                + ((size_t)b * NMAX * NMAX + (size_t)d * NMAX + d) * 16;
#pragma unroll
      for (int q = 0; q < 16; ++q) fb[q] = 0.0f;
    }
  }
  __syncthreads();

  const float be0i = s_be0[u], be0f = s_be0[16 + u], be0g = s_be0[32 + u], be0o = s_be0[48 + u];
  const float be1i = s_be1[u], be1f = s_be1[16 + u], be1g = s_be1[32 + u], be1o = s_be1[48 + u];
  const float hbias = (u < 8) ? s_e1b[u] : s_f1b[u - 8];
  const float f2bl = s_f2b[u], f2bu = s_f2b[16 + u];
  const float4 wl0 = *(const float4*)&s_ef2[u][0];
  const float4 wl1 = *(const float4*)&s_ef2[u][4];
  const float4 wu0 = *(const float4*)&s_ef2[16 + u][0];
  const float4 wu1 = *(const float4*)&s_ef2[16 + u][4];
  const int ue = (u < 2) ? u : 0;
  const float4 we0 = *(const float4*)&s_ee2[ue * 8];
  const float4 we1 = *(const float4*)&s_ee2[ue * 8 + 4];
  const float e2bias = (u < 2) ? s_e2b[u] : 0.0f;
  float4 W0[4][4];
#pragma unroll
  for (int g = 0; g < 4; ++g)
#pragma unroll
    for (int qq = 0; qq < 4; ++qq)
      W0[g][qq] = *(const float4*)&s_w0[g * 16 + u][qq * 4];

  {
    float acc0 = s_exb[u], acc1 = s_exb[16 + u];
    const float* w0p = exw + u * 128;
    const float* w1p = exw + (16 + u) * 128;
    for (int qq = 0; qq < 32; ++qq) {
      const float4 nv  = *(const float4*)&s_nf[sg][qq * 4];
      const float4 w0v = *(const float4*)&w0p[qq * 4];
      const float4 w1v = *(const float4*)&w1p[qq * 4];
      acc0 += nv.x * w0v.x + nv.y * w0v.y + nv.z * w0v.z + nv.w * w0v.w;
      acc1 += nv.x * w1v.x + nv.y * w1v.y + nv.z * w1v.z + nv.w * w1v.w;
    }
    x32[sg][u] = fmaxf(acc0, 0.0f);
    x32[sg][16 + u] = fmaxf(acc1, 0.0f);
  }
  __builtin_amdgcn_wave_barrier();
  float c0 = 0.0f, c1 = 0.0f;
  {
    float acc = s_enb[u];
#pragma unroll
    for (int qq = 0; qq < 8; ++qq) {
      const float4 xv  = *(const float4*)&x32[sg][qq * 4];
      const float4 wv2 = *(const float4*)&s_enw[u][qq * 4];
      acc += xv.x * wv2.x + xv.y * wv2.y + xv.z * wv2.z + xv.w * wv2.w;
    }
    const float h0e = fmaxf(acc, 0.0f);
    h0b[sg][u] = h0e;
    h1b[sg][u] = h0e;
  }
  __builtin_amdgcn_wave_barrier();

  const int gid = (kbase & 63) + sg;
  float* exi = out + (size_t)gid * (NMAX * NMAX);
  float* fea = out + (size_t)NG * NMAX * NMAX + (size_t)gid * (NMAX * NMAX) * 16;

  for (int s = 0; s < jrow; ++s) {
    float gi, gf, gg, go;
    {
      float ai = be0i, af = be0f, ag = be0g, ao = be0o;
#pragma unroll
      for (int qq = 0; qq < 4; ++qq) {
        const float4 hv = *(const float4*)&h0b[sg][qq * 4];
        ai += hv.x * W0[0][qq].x + hv.y * W0[0][qq].y + hv.z * W0[0][qq].z + hv.w * W0[0][qq].w;
        af += hv.x * W0[1][qq].x + hv.y * W0[1][qq].y + hv.z * W0[1][qq].z + hv.w * W0[1][qq].w;
        ag += hv.x * W0[2][qq].x + hv.y * W0[2][qq].y + hv.z * W0[2][qq].z + hv.w * W0[2][qq].w;
        ao += hv.x * W0[3][qq].x + hv.y * W0[3][qq].y + hv.z * W0[3][qq].z + hv.w * W0[3][qq].w;
      }
      gi = ai; gf = af; gg = ag; go = ao;
    }
    __builtin_amdgcn_wave_barrier();
    {
      const float iv = sgm(gi), fv = sgm(gf), gv = tanhf_(gg), ov = sgm(go);
      c0 = fv * c0 + iv * gv;
      h0b[sg][u] = ov * tanhf_(c0);
    }
    __builtin_amdgcn_wave_barrier();
    {
      float ai = be1i, af = be1f, ag = be1g, ao = be1o;
#pragma unroll
      for (int qq = 0; qq < 4; ++qq) {
        const float4 hv = *(const float4*)&h0b[sg][qq * 4];
        const float4 wi = *(const float4*)&s_w1[u][qq * 4];
        const float4 wf = *(const float4*)&s_w1[16 + u][qq * 4];
        const float4 wg = *(const float4*)&s_w1[32 + u][qq * 4];
        const float4 wo = *(const float4*)&s_w1[48 + u][qq * 4];
        ai += hv.x * wi.x + hv.y * wi.y + hv.z * wi.z + hv.w * wi.w;
        af += hv.x * wf.x + hv.y * wf.y + hv.z * wf.z + hv.w * wf.w;
        ag += hv.x * wg.x + hv.y * wg.y + hv.z * wg.z + hv.w * wg.w;
        ao += hv.x * wo.x + hv.y * wo.y + hv.z * wo.z + hv.w * wo.w;
      }
#pragma unroll
      for (int qq = 0; qq < 4; ++qq) {
        const float4 hv = *(const float4*)&h1b[sg][qq * 4];
        const float4 wi = *(const float4*)&s_w1[u][16 + qq * 4];
        const float4 wf = *(const float4*)&s_w1[16 + u][16 + qq * 4];
        const float4 wg = *(const float4*)&s_w1[32 + u][16 + qq * 4];
        const float4 wo = *(const float4*)&s_w1[48 + u][16 + qq * 4];
        ai += hv.x * wi.x + hv.y * wi.y + hv.z * wi.z + hv.w * wi.w;
        af += hv.x * wf.x + hv.y * wf.y + hv.z * wf.z + hv.w * wf.w;
        ag += hv.x * wg.x + hv.y * wg.y + hv.z * wg.z + hv.w * wg.w;
        ao += hv.x * wo.x + hv.y * wo.y + hv.z * wo.z + hv.w * wo.w;
      }
      gi = ai; gf = af; gg = ag; go = ao;
    }
    __builtin_amdgcn_wave_barrier();
    {
      const float iv = sgm(gi), fv = sgm(gf), gv = tanhf_(gg), ov = sgm(go);
      c1 = fv * c1 + iv * gv;
      h1b[sg][u] = ov * tanhf_(c1);
    }
    __builtin_amdgcn_wave_barrier();
    if (u < 8) {
      float a = hbias;
#pragma unroll
      for (int qq = 0; qq < 4; ++qq) {
        const float4 hv  = *(const float4*)&h1b[sg][qq * 4];
        const float4 wv2 = *(const float4*)&s_ee1[u][qq * 4];
        a += hv.x * wv2.x + hv.y * wv2.y + hv.z * wv2.z + hv.w * wv2.w;
      }
      t1b[sg][u] = fmaxf(a, 0.0f);
    } else {
      const int p = u - 8;
      float a = hbias;
#pragma unroll
      for (int qq = 0; qq < 4; ++qq) {
        const float4 hv  = *(const float4*)&h1b[sg][qq * 4];
        const float4 wv2 = *(const float4*)&s_ef1[p][qq * 4];
        a += hv.x * wv2.x + hv.y * wv2.y + hv.z * wv2.z + hv.w * wv2.w;
      }
      t2b[sg][p] = fmaxf(a, 0.0f);
    }
    __builtin_amdgcn_wave_barrier();
    {
      const float4 ta = *(const float4*)&t2b[sg][0];
      const float4 tb = *(const float4*)&t2b[sg][4];
      const float fl = f2bl
          + ta.x * wl0.x + ta.y * wl0.y + ta.z * wl0.z + ta.w * wl0.w
          + tb.x * wl1.x + tb.y * wl1.y + tb.z * wl1.z + tb.w * wl1.w;
      const float fu = f2bu
          + ta.x * wu0.x + ta.y * wu0.y + ta.z * wu0.z + ta.w * wu0.w
          + tb.x * wu1.x + tb.y * wu1.y + tb.z * wu1.z + tb.w * wu1.w;
      fea[((size_t)jrow * NMAX + s) * 16 + u] = fl;
      fea[((size_t)s * NMAX + jrow) * 16 + u] = fu;
      if (u < 2) {
        const float4 t1a = *(const float4*)&t1b[sg][0];
        const float4 t1c = *(const float4*)&t1b[sg][4];
        float e = e2bias
            + t1a.x * we0.x + t1a.y * we0.y + t1a.z * we0.z + t1a.w * we0.w
            + t1c.x * we1.x + t1c.y * we1.y + t1c.z * we1.z + t1c.w * we1.w;
        const size_t idx = (u == 0) ? ((size_t)jrow * NMAX + s)
                                    : ((size_t)s * NMAX + jrow);
        exi[idx] = sgm(e);
      }
    }
    __builtin_amdgcn_wave_barrier();
  }
}

extern "C" void kernel_launch(void* const* d_in, const int* in_sizes, int n_in,
                              void* d_out, int out_size, void* d_ws, size_t ws_size,
                              hipStream_t stream) {
  (void)in_sizes; (void)n_in; (void)out_size; (void)ws_size;
  const float* gene = (const float*)d_in[0];
  const float* entw = (const float*)d_in[1];
  const float* entb = (const float*)d_in[2];
  const float* nwih = (const float*)d_in[4];
  const float* nwhh = (const float*)d_in[5];
  const float* nbih = (const float*)d_in[6];
  const float* nbhh = (const float*)d_in[7];
  const float* exw  = (const float*)d_in[8];
  const float* exb  = (const float*)d_in[9];
  const float* enw  = (const float*)d_in[10];
  const float* enb  = (const float*)d_in[11];
  const float* ewih = (const float*)d_in[13];
  const float* ewhh = (const float*)d_in[14];
  const float* ebih = (const float*)d_in[15];
  const float* ebhh = (const float*)d_in[16];
  const float* ee1w = (const float*)d_in[17];
  const float* ee1b = (const float*)d_in[18];
  const float* ee2w = (const float*)d_in[19];
  const float* ee2b = (const float*)d_in[20];
  const float* ef1w = (const float*)d_in[21];
  const float* ef1b = (const float*)d_in[22];
  const float* ef2w = (const float*)d_in[23];
  const float* ef2b = (const float*)d_in[24];

  // ws layout (bytes):
  //   nflat @ 0         : 10240*128*2 = 2,621,440
  //   h0w   @ 2621440   : 160*64*128*2 = 2,621,440
  //   hinit @ 5242880   : 64*128*2 = 16,384
  //   X2    @ 5259264   : 160*512*64*2 = 10,485,760   (total ~15.0 MB)
  char* ws = (char*)d_ws;
  unsigned short* nflat = (unsigned short*)(ws);
  unsigned short* h0w   = (unsigned short*)(ws + 2621440);
  unsigned short* hinit = (unsigned short*)(ws + 5242880);
  unsigned short* X2    = (unsigned short*)(ws + 5259264);

  node_l0<<<4, 512, 0, stream>>>(gene, entw, entb, nwhh, nbih, nbhh, h0w, hinit);
  xgemm<<<dim3(160, 4), 256, 0, stream>>>(h0w, nwih, X2);
  node_l1<<<4, 512, 0, stream>>>(hinit, X2, nwhh, nbih, nbhh, nflat);
  edge_kernel<<<640, 256, 0, stream>>>(nflat, exw, exb, enw, enb, ewih, ewhh,
                                       ebih, ebhh, ee1w, ee1b, ee2w, ee2b,
                                       ef1w, ef1b, ef2w, ef2b, (float*)d_out);
}

// Round 6
// 688.296 us; speedup vs baseline: 1.5649x; 1.0472x over previous
//
#include <hip/hip_runtime.h>

// GraphGenRnn — R6:
//  * X2 -> X3[gene_block][t][col][g&15]: node_l1 now streams a contiguous
//    2.6MB slice (R5 layout caused 4-8x fetch amplification + latency-bound
//    30ms cold dispatch). One-step register prefetch added.
//  * edge: ragged work scattered across blocks (wave w of block b takes quad
//    b+640w) so per-CU work is balanced (was 3:1); head weights/biases moved
//    to regs/global, shrinking LDS ~10KB for higher occupancy.

typedef __attribute__((ext_vector_type(8))) short short8;
typedef __attribute__((ext_vector_type(4))) short short4v;
typedef __attribute__((ext_vector_type(4))) float floatx4;

#define NG 64
#define NMAX 161

__device__ __forceinline__ float sgm(float x) {
  return __builtin_amdgcn_rcpf(1.0f + __expf(-x));
}
__device__ __forceinline__ float tanhf_(float x) {
  return 2.0f * __builtin_amdgcn_rcpf(1.0f + __expf(-2.0f * x)) - 1.0f;
}
__device__ __forceinline__ unsigned short f2b(float x) {
  union { float f; unsigned u; } v; v.f = x;
  unsigned r = v.u + 0x7fffu + ((v.u >> 16) & 1u);   // RNE to bf16
  return (unsigned short)(r >> 16);
}
__device__ __forceinline__ float b2f(unsigned short h) {
  union { unsigned u; float f; } v; v.u = ((unsigned)h) << 16; return v.f;
}

// ---------------------------------------------------------------------------
// node_l0: 4 blocks x 512 threads. Wave w: units [16w,16w+16), whh0 in 64
// VGPRs. h0 double-buffered in LDS, 1 barrier/step. Streams h0_t to h0w.
// ---------------------------------------------------------------------------
__global__ __launch_bounds__(512) void node_l0(
    const float* __restrict__ gene,   // [64][128]
    const float* __restrict__ entw,   // [128][128]
    const float* __restrict__ entb,   // [128]
    const float* __restrict__ nwhh,   // [2][512][128] (layer0 = first half)
    const float* __restrict__ nbih,   // [2][512]
    const float* __restrict__ nbhh,   // [2][512]
    unsigned short* __restrict__ h0w,   // bf16 [160][64][128]
    unsigned short* __restrict__ hinit) // bf16 [64][128]
{
  const int tid  = threadIdx.x;
  const int wv   = tid >> 6;
  const int lane = tid & 63;
  const int lo   = lane & 15;
  const int hi   = lane >> 4;
  const int u    = (wv << 4) | lo;
  const int nb   = blockIdx.x;

  __shared__ __align__(16) unsigned short hA0[2][16][136];

  short8 B0[4][4];
#pragma unroll
  for (int t = 0; t < 4; ++t) {
    const int n = t * 128 + u;
#pragma unroll
    for (int ks = 0; ks < 4; ++ks) {
      const float* src = nwhh + n * 128 + ks * 32 + hi * 8;
      short8 bfr;
#pragma unroll
      for (int jj = 0; jj < 8; ++jj) bfr[jj] = (short)f2b(src[jj]);
      B0[t][ks] = bfr;
    }
  }

  const float bi0 = nbih[u]       + nbhh[u];
  const float bf0 = nbih[128 + u] + nbhh[128 + u];
  const float bg0 = nbih[256 + u] + nbhh[256 + u];
  const float bo0 = nbih[384 + u] + nbhh[384 + u];

  {
    const int q  = tid >> 5;
    const int u4 = (tid & 31) * 4;
    const float* gc = gene + (nb * 16 + q) * 128;
    float acc[4] = { entb[u4], entb[u4 + 1], entb[u4 + 2], entb[u4 + 3] };
    for (int qq = 0; qq < 32; ++qq) {
      const float4 gv = *(const float4*)&gc[qq * 4];
#pragma unroll
      for (int r = 0; r < 4; ++r) {
        const float4 wv2 = *(const float4*)&entw[(u4 + r) * 128 + qq * 4];
        acc[r] += gv.x * wv2.x + gv.y * wv2.y + gv.z * wv2.z + gv.w * wv2.w;
      }
    }
#pragma unroll
    for (int r = 0; r < 4; ++r) {
      const unsigned short hb = f2b(fmaxf(acc[r], 0.0f));
      hA0[0][q][u4 + r] = hb;
      hinit[(size_t)(nb * 16 + q) * 128 + u4 + r] = hb;
    }
  }

  float c0[4] = {0.f, 0.f, 0.f, 0.f};
  __syncthreads();

  for (int t = 0; t < 160; ++t) {
    const int rb = t & 1, wb = rb ^ 1;
    floatx4 a0 = {bi0, bi0, bi0, bi0};
    floatx4 a1 = {bf0, bf0, bf0, bf0};
    floatx4 a2 = {bg0, bg0, bg0, bg0};
    floatx4 a3 = {bo0, bo0, bo0, bo0};
    const unsigned short* ar = &hA0[rb][lo][hi * 8];
#pragma unroll
    for (int ks = 0; ks < 4; ++ks) {
      const short8 afr = *(const short8*)(ar + ks * 32);
      a0 = __builtin_amdgcn_mfma_f32_16x16x32_bf16(afr, B0[0][ks], a0, 0, 0, 0);
      a1 = __builtin_amdgcn_mfma_f32_16x16x32_bf16(afr, B0[1][ks], a1, 0, 0, 0);
      a2 = __builtin_amdgcn_mfma_f32_16x16x32_bf16(afr, B0[2][ks], a2, 0, 0, 0);
      a3 = __builtin_amdgcn_mfma_f32_16x16x32_bf16(afr, B0[3][ks], a3, 0, 0, 0);
    }
    const size_t obase = (size_t)(t * 64 + nb * 16) * 128;
#pragma unroll
    for (int r = 0; r < 4; ++r) {
      const float iv = sgm(a0[r]);
      const float fv = sgm(a1[r]);
      const float gv = tanhf_(a2[r]);
      const float ov = sgm(a3[r]);
      const float cn = fv * c0[r] + iv * gv;
      c0[r] = cn;
      const unsigned short hb = f2b(ov * tanhf_(cn));
      const int q = hi * 4 + r;
      hA0[wb][q][u] = hb;
      h0w[obase + (size_t)q * 128 + u] = hb;
    }
    __syncthreads();
  }
}

// ---------------------------------------------------------------------------
// xgemm: X3[g>>4][t][col][g&15] = sum_u h0w[t][g][u] * wih1[col][u]  (bf16)
// grid (160,4) x 256 thr.
// ---------------------------------------------------------------------------
__global__ __launch_bounds__(256) void xgemm(
    const unsigned short* __restrict__ h0w,  // bf16 [160][64][128]
    const float* __restrict__ nwih,          // [512][128] (layer-1 wih)
    unsigned short* __restrict__ X3)         // bf16 [4][160][512][16]
{
  const int tid = threadIdx.x;
  const int wv  = tid >> 6;
  const int lane = tid & 63;
  const int lo  = lane & 15;
  const int hi  = lane >> 4;
  const int bt  = blockIdx.x;
  const int bn  = blockIdx.y;

  __shared__ __align__(16) unsigned short s_b[128][136];

  for (int i = tid; i < 128 * 32; i += 256) {
    const int nc = i >> 5, k4 = (i & 31) * 4;
    const float4 w = *(const float4*)&nwih[(size_t)(bn * 128 + nc) * 128 + k4];
    s_b[nc][k4]     = f2b(w.x);
    s_b[nc][k4 + 1] = f2b(w.y);
    s_b[nc][k4 + 2] = f2b(w.z);
    s_b[nc][k4 + 3] = f2b(w.w);
  }
  __syncthreads();

  floatx4 acc[8];
#pragma unroll
  for (int nt = 0; nt < 8; ++nt) acc[nt] = (floatx4){0.f, 0.f, 0.f, 0.f};

  const unsigned short* arow = h0w + (size_t)(bt * 64 + wv * 16 + lo) * 128 + hi * 8;
#pragma unroll
  for (int ks = 0; ks < 4; ++ks) {
    const short8 afr = *(const short8*)(arow + ks * 32);
#pragma unroll
    for (int nt = 0; nt < 8; ++nt) {
      const short8 bfr = *(const short8*)&s_b[nt * 16 + lo][ks * 32 + hi * 8];
      acc[nt] = __builtin_amdgcn_mfma_f32_16x16x32_bf16(afr, bfr, acc[nt], 0, 0, 0);
    }
  }

  // C layout: gene row = hi*4+r, col = nt*16+lo. Write 8B per nt.
#pragma unroll
  for (int nt = 0; nt < 8; ++nt) {
    const size_t base3 = ((((size_t)wv * 160 + bt) * 512) + bn * 128 + nt * 16 + lo) * 16 + hi * 4;
    short4v xv;
#pragma unroll
    for (int r = 0; r < 4; ++r) xv[r] = (short)f2b(acc[nt][r]);
    *(short4v*)&X3[base3] = xv;
  }
}

// ---------------------------------------------------------------------------
// node_l1: 4 blocks x 512 threads. whh1 in 64 VGPRs; input-half streamed from
// X3 (contiguous 16KB/block/step, prefetched one step ahead).
// ---------------------------------------------------------------------------
__global__ __launch_bounds__(512) void node_l1(
    const unsigned short* __restrict__ hinit, // bf16 [64][128]
    const unsigned short* __restrict__ X3,    // bf16 [4][160][512][16]
    const float* __restrict__ nwhh,           // [2][512][128] (layer1 = 2nd half)
    const float* __restrict__ nbih,           // [2][512]
    const float* __restrict__ nbhh,           // [2][512]
    unsigned short* __restrict__ nout)        // bf16 [10240][128]
{
  const int tid  = threadIdx.x;
  const int wv   = tid >> 6;
  const int lane = tid & 63;
  const int lo   = lane & 15;
  const int hi   = lane >> 4;
  const int u    = (wv << 4) | lo;
  const int nb   = blockIdx.x;

  __shared__ __align__(16) unsigned short hA1[2][16][136];

  short8 B1[4][4];
#pragma unroll
  for (int t = 0; t < 4; ++t) {
    const int n = t * 128 + u;
#pragma unroll
    for (int ks = 0; ks < 4; ++ks) {
      const float* src = nwhh + 512 * 128 + n * 128 + ks * 32 + hi * 8;
      short8 bfr;
#pragma unroll
      for (int jj = 0; jj < 8; ++jj) bfr[jj] = (short)f2b(src[jj]);
      B1[t][ks] = bfr;
    }
  }

  const float bi1 = nbih[512 + u]       + nbhh[512 + u];
  const float bf1 = nbih[512 + 128 + u] + nbhh[512 + 128 + u];
  const float bg1 = nbih[512 + 256 + u] + nbhh[512 + 256 + u];
  const float bo1 = nbih[512 + 384 + u] + nbhh[512 + 384 + u];

  {
    const int q  = tid >> 5;
    const int u4 = (tid & 31) * 4;
    const short4v hv = *(const short4v*)&hinit[(size_t)(nb * 16 + q) * 128 + u4];
    *(short4v*)&hA1[0][q][u4] = hv;
  }

  float c1[4] = {0.f, 0.f, 0.f, 0.f};

  // prefetch step 0 input
  const size_t xstep = 512 * 16;
  const unsigned short* xb = X3 + ((size_t)nb * 160) * xstep + (size_t)u * 16 + hi * 4;
  short4v x0 = *(const short4v*)(xb);
  short4v x1 = *(const short4v*)(xb + 128 * 16);
  short4v x2 = *(const short4v*)(xb + 256 * 16);
  short4v x3 = *(const short4v*)(xb + 384 * 16);
  __syncthreads();

  for (int t = 0; t < 160; ++t) {
    const int rb = t & 1, wb = rb ^ 1;

    floatx4 a0 = {bi1, bi1, bi1, bi1};
    floatx4 a1 = {bf1, bf1, bf1, bf1};
    floatx4 a2 = {bg1, bg1, bg1, bg1};
    floatx4 a3 = {bo1, bo1, bo1, bo1};
    const unsigned short* ar = &hA1[rb][lo][hi * 8];
#pragma unroll
    for (int ks = 0; ks < 4; ++ks) {
      const short8 afr = *(const short8*)(ar + ks * 32);
      a0 = __builtin_amdgcn_mfma_f32_16x16x32_bf16(afr, B1[0][ks], a0, 0, 0, 0);
      a1 = __builtin_amdgcn_mfma_f32_16x16x32_bf16(afr, B1[1][ks], a1, 0, 0, 0);
      a2 = __builtin_amdgcn_mfma_f32_16x16x32_bf16(afr, B1[2][ks], a2, 0, 0, 0);
      a3 = __builtin_amdgcn_mfma_f32_16x16x32_bf16(afr, B1[3][ks], a3, 0, 0, 0);
    }

    const short4v cx0 = x0, cx1 = x1, cx2 = x2, cx3 = x3;
    if (t + 1 < 160) {  // prefetch next step
      const unsigned short* xn = xb + (size_t)(t + 1) * xstep;
      x0 = *(const short4v*)(xn);
      x1 = *(const short4v*)(xn + 128 * 16);
      x2 = *(const short4v*)(xn + 256 * 16);
      x3 = *(const short4v*)(xn + 384 * 16);
    }

    const size_t obase = (size_t)((159 - t) * 64 + nb * 16) * 128;
#pragma unroll
    for (int r = 0; r < 4; ++r) {
      const float iv = sgm(a0[r] + b2f((unsigned short)cx0[r]));
      const float fv = sgm(a1[r] + b2f((unsigned short)cx1[r]));
      const float gv = tanhf_(a2[r] + b2f((unsigned short)cx2[r]));
      const float ov = sgm(a3[r] + b2f((unsigned short)cx3[r]));
      const float cn = fv * c1[r] + iv * gv;
      c1[r] = cn;
      const unsigned short hb = f2b(ov * tanhf_(cn));
      const int q = hi * 4 + r;
      hA1[wb][q][u] = hb;
      nout[obase + (size_t)q * 128 + u] = hb;
    }
    __syncthreads();
  }
}

// ---------------------------------------------------------------------------
// Edge: 640 blocks x 256 threads. Wave w of block b owns quad q=b+640w, i.e.
// sequences k=4q..4q+3 (uniform jrow per wave) -> per-CU work balanced.
// No block barriers in the loop; per-wave trip counts. Head weights/biases in
// registers; LDS holds nf staging, L0/L1 weights, and small h/t buffers.
// ---------------------------------------------------------------------------
__global__ __launch_bounds__(256, 1) void edge_kernel(
    const unsigned short* __restrict__ nflat, // bf16 [10240][128]
    const float* __restrict__ exw, const float* __restrict__ exb,   // [32][128],[32]
    const float* __restrict__ enw, const float* __restrict__ enb,   // [16][32],[16]
    const float* __restrict__ ewih,  // [1][64][16]
    const float* __restrict__ ewhh,  // [2][64][16]
    const float* __restrict__ ebih, const float* __restrict__ ebhh, // [2][64]
    const float* __restrict__ ee1w, const float* __restrict__ ee1b,
    const float* __restrict__ ee2w, const float* __restrict__ ee2b,
    const float* __restrict__ ef1w, const float* __restrict__ ef1b,
    const float* __restrict__ ef2w, const float* __restrict__ ef2b,
    float* __restrict__ out)
{
  const int tid = threadIdx.x;
  const int sg  = tid >> 4;          // 0..15 (wave = sg>>2)
  const int u   = tid & 15;
  const int b   = blockIdx.x;

  const int kq  = b + 640 * (sg >> 2);     // quad id for this wave
  const int k   = 4 * kq + (sg & 3);       // sequence id
  const int gid = k & 63;
  const int jw  = 160 - (kq >> 4);         // trip count (uniform per wave)

  __shared__ __align__(16) float s_nf[16][132];
  __shared__ __align__(16) float s_w0[64][20];
  __shared__ __align__(16) float s_w1[64][36];
  __shared__ __align__(16) float h0b[16][20];
  __shared__ __align__(16) float h1b[16][20];
  __shared__ __align__(16) float t1b[16][12];
  __shared__ __align__(16) float t2b[16][12];
  __shared__ __align__(16) float x32[16][36];

  for (int i = tid; i < 16 * 128; i += 256) {
    const int rr = i >> 7;
    const int kk = 4 * (b + 640 * (rr >> 2)) + (rr & 3);
    s_nf[rr][i & 127] = b2f(nflat[(size_t)kk * 128 + (i & 127)]);
  }
  for (int i = tid; i < 64 * 16; i += 256) {
    s_w0[i >> 4][i & 15] = ewhh[i];                 // layer0 whh
    s_w1[i >> 4][i & 15] = ewih[i];                 // layer1 wih
    s_w1[i >> 4][16 + (i & 15)] = ewhh[1024 + i];   // layer1 whh
  }

  // zero the (never-written) diagonal; graph g == b for first 64 blocks
  if (b < NG) {
    for (int d = tid; d < NMAX; d += 256) {
      out[(size_t)b * (NMAX * NMAX) + (size_t)d * NMAX + d] = 0.0f;
      float* fb = out + (size_t)NG * NMAX * NMAX
                + ((size_t)b * NMAX * NMAX + (size_t)d * NMAX + d) * 16;
#pragma unroll
      for (int q = 0; q < 16; ++q) fb[q] = 0.0f;
    }
  }

  // ---- per-thread constants from global (L2-resident, read once) ----
  const float be0i = ebih[u]      + ebhh[u];
  const float be0f = ebih[16 + u] + ebhh[16 + u];
  const float be0g = ebih[32 + u] + ebhh[32 + u];
  const float be0o = ebih[48 + u] + ebhh[48 + u];
  const float be1i = ebih[64 + u]      + ebhh[64 + u];
  const float be1f = ebih[64 + 16 + u] + ebhh[64 + 16 + u];
  const float be1g = ebih[64 + 32 + u] + ebhh[64 + 32 + u];
  const float be1o = ebih[64 + 48 + u] + ebhh[64 + 48 + u];
  const float hbias = (u < 8) ? ee1b[u] : ef1b[u - 8];
  const float f2bl = ef2b[u], f2bu = ef2b[16 + u];
  const float4 wl0 = *(const float4*)&ef2w[u * 8];
  const float4 wl1 = *(const float4*)&ef2w[u * 8 + 4];
  const float4 wu0 = *(const float4*)&ef2w[(16 + u) * 8];
  const float4 wu1 = *(const float4*)&ef2w[(16 + u) * 8 + 4];
  const int ue = (u < 2) ? u : 0;
  const float4 we0 = *(const float4*)&ee2w[ue * 8];
  const float4 we1 = *(const float4*)&ee2w[ue * 8 + 4];
  const float e2bias = (u < 2) ? ee2b[u] : 0.0f;
  // t-head weight row (ee1 for u<8, ef1 for u>=8) -> 16 VGPR
  const float* whp = (u < 8) ? (ee1w + u * 16) : (ef1w + (u - 8) * 16);
  float4 WH[4];
#pragma unroll
  for (int qq = 0; qq < 4; ++qq) WH[qq] = *(const float4*)&whp[qq * 4];

  __syncthreads();   // the ONLY block barrier

  // ---- h0e = relu(relu(nf @ exw^T + exb) @ enw^T + enb) ----
  {
    float acc0 = exb[u], acc1 = exb[16 + u];
    const float* w0p = exw + u * 128;
    const float* w1p = exw + (16 + u) * 128;
    for (int qq = 0; qq < 32; ++qq) {
      const float4 nv  = *(const float4*)&s_nf[sg][qq * 4];
      const float4 w0v = *(const float4*)&w0p[qq * 4];
      const float4 w1v = *(const float4*)&w1p[qq * 4];
      acc0 += nv.x * w0v.x + nv.y * w0v.y + nv.z * w0v.z + nv.w * w0v.w;
      acc1 += nv.x * w1v.x + nv.y * w1v.y + nv.z * w1v.z + nv.w * w1v.w;
    }
    x32[sg][u] = fmaxf(acc0, 0.0f);
    x32[sg][16 + u] = fmaxf(acc1, 0.0f);
  }
  __builtin_amdgcn_wave_barrier();
  float c0 = 0.0f, c1 = 0.0f;
  {
    float acc = enb[u];
    const float* ewp = enw + u * 32;
#pragma unroll
    for (int qq = 0; qq < 8; ++qq) {
      const float4 xv  = *(const float4*)&x32[sg][qq * 4];
      const float4 wv2 = *(const float4*)&ewp[qq * 4];
      acc += xv.x * wv2.x + xv.y * wv2.y + xv.z * wv2.z + xv.w * wv2.w;
    }
    const float h0e = fmaxf(acc, 0.0f);
    h0b[sg][u] = h0e;
    h1b[sg][u] = h0e;
  }
  __builtin_amdgcn_wave_barrier();

  float* exi = out + (size_t)gid * (NMAX * NMAX);
  float* fea = out + (size_t)NG * NMAX * NMAX + (size_t)gid * (NMAX * NMAX) * 16;

  for (int s = 0; s < jw; ++s) {
    float gi, gf, gg, go;
    { // layer 0 gate dots
      float ai = be0i, af = be0f, ag = be0g, ao = be0o;
#pragma unroll
      for (int qq = 0; qq < 4; ++qq) {
        const float4 hv = *(const float4*)&h0b[sg][qq * 4];
        const float4 wi = *(const float4*)&s_w0[u][qq * 4];
        const float4 wf = *(const float4*)&s_w0[16 + u][qq * 4];
        const float4 wg = *(const float4*)&s_w0[32 + u][qq * 4];
        const float4 wo = *(const float4*)&s_w0[48 + u][qq * 4];
        ai += hv.x * wi.x + hv.y * wi.y + hv.z * wi.z + hv.w * wi.w;
        af += hv.x * wf.x + hv.y * wf.y + hv.z * wf.z + hv.w * wf.w;
        ag += hv.x * wg.x + hv.y * wg.y + hv.z * wg.z + hv.w * wg.w;
        ao += hv.x * wo.x + hv.y * wo.y + hv.z * wo.z + hv.w * wo.w;
      }
      gi = ai; gf = af; gg = ag; go = ao;
    }
    __builtin_amdgcn_wave_barrier();
    {
      const float iv = sgm(gi), fv = sgm(gf), gv = tanhf_(gg), ov = sgm(go);
      c0 = fv * c0 + iv * gv;
      h0b[sg][u] = ov * tanhf_(c0);
    }
    __builtin_amdgcn_wave_barrier();
    { // layer 1 gate dots over [h0new | h1]
      float ai = be1i, af = be1f, ag = be1g, ao = be1o;
#pragma unroll
      for (int qq = 0; qq < 4; ++qq) {
        const float4 hv = *(const float4*)&h0b[sg][qq * 4];
        const float4 wi = *(const float4*)&s_w1[u][qq * 4];
        const float4 wf = *(const float4*)&s_w1[16 + u][qq * 4];
        const float4 wg = *(const float4*)&s_w1[32 + u][qq * 4];
        const float4 wo = *(const float4*)&s_w1[48 + u][qq * 4];
        ai += hv.x * wi.x + hv.y * wi.y + hv.z * wi.z + hv.w * wi.w;
        af += hv.x * wf.x + hv.y * wf.y + hv.z * wf.z + hv.w * wf.w;
        ag += hv.x * wg.x + hv.y * wg.y + hv.z * wg.z + hv.w * wg.w;
        ao += hv.x * wo.x + hv.y * wo.y + hv.z * wo.z + hv.w * wo.w;
      }
#pragma unroll
      for (int qq = 0; qq < 4; ++qq) {
        const float4 hv = *(const float4*)&h1b[sg][qq * 4];
        const float4 wi = *(const float4*)&s_w1[u][16 + qq * 4];
        const float4 wf = *(const float4*)&s_w1[16 + u][16 + qq * 4];
        const float4 wg = *(const float4*)&s_w1[32 + u][16 + qq * 4];
        const float4 wo = *(const float4*)&s_w1[48 + u][16 + qq * 4];
        ai += hv.x * wi.x + hv.y * wi.y + hv.z * wi.z + hv.w * wi.w;
        af += hv.x * wf.x + hv.y * wf.y + hv.z * wf.z + hv.w * wf.w;
        ag += hv.x * wg.x + hv.y * wg.y + hv.z * wg.z + hv.w * wg.w;
        ao += hv.x * wo.x + hv.y * wo.y + hv.z * wo.z + hv.w * wo.w;
      }
      gi = ai; gf = af; gg = ag; go = ao;
    }
    __builtin_amdgcn_wave_barrier();
    {
      const float iv = sgm(gi), fv = sgm(gf), gv = tanhf_(gg), ov = sgm(go);
      c1 = fv * c1 + iv * gv;
      h1b[sg][u] = ov * tanhf_(c1);   // = eh[s]
    }
    __builtin_amdgcn_wave_barrier();
    // ---- heads (weights in regs) ----
    {
      float a = hbias;
#pragma unroll
      for (int qq = 0; qq < 4; ++qq) {
        const float4 hv = *(const float4*)&h1b[sg][qq * 4];
        a += hv.x * WH[qq].x + hv.y * WH[qq].y + hv.z * WH[qq].z + hv.w * WH[qq].w;
      }
      a = fmaxf(a, 0.0f);
      if (u < 8) t1b[sg][u] = a; else t2b[sg][u - 8] = a;
    }
    __builtin_amdgcn_wave_barrier();
    {
      const float4 ta = *(const float4*)&t2b[sg][0];
      const float4 tb = *(const float4*)&t2b[sg][4];
      const float fl = f2bl
          + ta.x * wl0.x + ta.y * wl0.y + ta.z * wl0.z + ta.w * wl0.w
          + tb.x * wl1.x + tb.y * wl1.y + tb.z * wl1.z + tb.w * wl1.w;
      const float fu = f2bu
          + ta.x * wu0.x + ta.y * wu0.y + ta.z * wu0.z + ta.w * wu0.w
          + tb.x * wu1.x + tb.y * wu1.y + tb.z * wu1.z + tb.w * wu1.w;
      fea[((size_t)jw * NMAX + s) * 16 + u] = fl;
      fea[((size_t)s * NMAX + jw) * 16 + u] = fu;
      if (u < 2) {
        const float4 t1a = *(const float4*)&t1b[sg][0];
        const float4 t1c = *(const float4*)&t1b[sg][4];
        float e = e2bias
            + t1a.x * we0.x + t1a.y * we0.y + t1a.z * we0.z + t1a.w * we0.w
            + t1c.x * we1.x + t1c.y * we1.y + t1c.z * we1.z + t1c.w * we1.w;
        const size_t idx = (u == 0) ? ((size_t)jw * NMAX + s)
                                    : ((size_t)s * NMAX + jw);
        exi[idx] = sgm(e);
      }
    }
    __builtin_amdgcn_wave_barrier();
  }
}

extern "C" void kernel_launch(void* const* d_in, const int* in_sizes, int n_in,
                              void* d_out, int out_size, void* d_ws, size_t ws_size,
                              hipStream_t stream) {
  (void)in_sizes; (void)n_in; (void)out_size; (void)ws_size;
  const float* gene = (const float*)d_in[0];
  const float* entw = (const float*)d_in[1];
  const float* entb = (const float*)d_in[2];
  const float* nwih = (const float*)d_in[4];
  const float* nwhh = (const float*)d_in[5];
  const float* nbih = (const float*)d_in[6];
  const float* nbhh = (const float*)d_in[7];
  const float* exw  = (const float*)d_in[8];
  const float* exb  = (const float*)d_in[9];
  const float* enw  = (const float*)d_in[10];
  const float* enb  = (const float*)d_in[11];
  const float* ewih = (const float*)d_in[13];
  const float* ewhh = (const float*)d_in[14];
  const float* ebih = (const float*)d_in[15];
  const float* ebhh = (const float*)d_in[16];
  const float* ee1w = (const float*)d_in[17];
  const float* ee1b = (const float*)d_in[18];
  const float* ee2w = (const float*)d_in[19];
  const float* ee2b = (const float*)d_in[20];
  const float* ef1w = (const float*)d_in[21];
  const float* ef1b = (const float*)d_in[22];
  const float* ef2w = (const float*)d_in[23];
  const float* ef2b = (const float*)d_in[24];

  // ws layout (bytes):
  //   nflat @ 0         : 10240*128*2 = 2,621,440
  //   h0w   @ 2621440   : 160*64*128*2 = 2,621,440
  //   hinit @ 5242880   : 64*128*2 = 16,384
  //   X3    @ 5259264   : 4*160*512*16*2 = 10,485,760
  char* ws = (char*)d_ws;
  unsigned short* nflat = (unsigned short*)(ws);
  unsigned short* h0w   = (unsigned short*)(ws + 2621440);
  unsigned short* hinit = (unsigned short*)(ws + 5242880);
  unsigned short* X3    = (unsigned short*)(ws + 5259264);

  node_l0<<<4, 512, 0, stream>>>(gene, entw, entb, nwhh, nbih, nbhh, h0w, hinit);
  xgemm<<<dim3(160, 4), 256, 0, stream>>>(h0w, nwih, X3);
  node_l1<<<4, 512, 0, stream>>>(hinit, X3, nwhh, nbih, nbhh, nflat);
  edge_kernel<<<640, 256, 0, stream>>>(nflat, exw, exb, enw, enb, ewih, ewhh,
                                       ebih, ebhh, ee1w, ee1b, ee2w, ee2b,
                                       ef1w, ef1b, ef2w, ef2b, (float*)d_out);
}

// Round 7
// 629.968 us; speedup vs baseline: 1.7098x; 1.0926x over previous
//
#include <hip/hip_runtime.h>

// GraphGenRnn — R7: edge work mapping reverted to uniform-waves-per-block
// (R5 style) + snake block permutation (row0: r, row1: 511-r, row2: 512+r) so
// each CU's resident blocks {d, d+256, d+512} have constant jrow sums
// (224 / 192 vs R5's 288..128, R6's 1008..540). L1 h1-half dots hoisted before
// the h0 LDS round-trip. Node kernels unchanged from R6.

typedef __attribute__((ext_vector_type(8))) short short8;
typedef __attribute__((ext_vector_type(4))) short short4v;
typedef __attribute__((ext_vector_type(4))) float floatx4;

#define NG 64
#define NMAX 161

__device__ __forceinline__ float sgm(float x) {
  return __builtin_amdgcn_rcpf(1.0f + __expf(-x));
}
__device__ __forceinline__ float tanhf_(float x) {
  return 2.0f * __builtin_amdgcn_rcpf(1.0f + __expf(-2.0f * x)) - 1.0f;
}
__device__ __forceinline__ unsigned short f2b(float x) {
  union { float f; unsigned u; } v; v.f = x;
  unsigned r = v.u + 0x7fffu + ((v.u >> 16) & 1u);   // RNE to bf16
  return (unsigned short)(r >> 16);
}
__device__ __forceinline__ float b2f(unsigned short h) {
  union { unsigned u; float f; } v; v.u = ((unsigned)h) << 16; return v.f;
}

// ---------------------------------------------------------------------------
// node_l0: 4 blocks x 512 threads. Wave w: units [16w,16w+16), whh0 in 64
// VGPRs. h0 double-buffered in LDS, 1 barrier/step. Streams h0_t to h0w.
// ---------------------------------------------------------------------------
__global__ __launch_bounds__(512) void node_l0(
    const float* __restrict__ gene,   // [64][128]
    const float* __restrict__ entw,   // [128][128]
    const float* __restrict__ entb,   // [128]
    const float* __restrict__ nwhh,   // [2][512][128] (layer0 = first half)
    const float* __restrict__ nbih,   // [2][512]
    const float* __restrict__ nbhh,   // [2][512]
    unsigned short* __restrict__ h0w,   // bf16 [160][64][128]
    unsigned short* __restrict__ hinit) // bf16 [64][128]
{
  const int tid  = threadIdx.x;
  const int wv   = tid >> 6;
  const int lane = tid & 63;
  const int lo   = lane & 15;
  const int hi   = lane >> 4;
  const int u    = (wv << 4) | lo;
  const int nb   = blockIdx.x;

  __shared__ __align__(16) unsigned short hA0[2][16][136];

  short8 B0[4][4];
#pragma unroll
  for (int t = 0; t < 4; ++t) {
    const int n = t * 128 + u;
#pragma unroll
    for (int ks = 0; ks < 4; ++ks) {
      const float* src = nwhh + n * 128 + ks * 32 + hi * 8;
      short8 bfr;
#pragma unroll
      for (int jj = 0; jj < 8; ++jj) bfr[jj] = (short)f2b(src[jj]);
      B0[t][ks] = bfr;
    }
  }

  const float bi0 = nbih[u]       + nbhh[u];
  const float bf0 = nbih[128 + u] + nbhh[128 + u];
  const float bg0 = nbih[256 + u] + nbhh[256 + u];
  const float bo0 = nbih[384 + u] + nbhh[384 + u];

  {
    const int q  = tid >> 5;
    const int u4 = (tid & 31) * 4;
    const float* gc = gene + (nb * 16 + q) * 128;
    float acc[4] = { entb[u4], entb[u4 + 1], entb[u4 + 2], entb[u4 + 3] };
    for (int qq = 0; qq < 32; ++qq) {
      const float4 gv = *(const float4*)&gc[qq * 4];
#pragma unroll
      for (int r = 0; r < 4; ++r) {
        const float4 wv2 = *(const float4*)&entw[(u4 + r) * 128 + qq * 4];
        acc[r] += gv.x * wv2.x + gv.y * wv2.y + gv.z * wv2.z + gv.w * wv2.w;
      }
    }
#pragma unroll
    for (int r = 0; r < 4; ++r) {
      const unsigned short hb = f2b(fmaxf(acc[r], 0.0f));
      hA0[0][q][u4 + r] = hb;
      hinit[(size_t)(nb * 16 + q) * 128 + u4 + r] = hb;
    }
  }

  float c0[4] = {0.f, 0.f, 0.f, 0.f};
  __syncthreads();

  for (int t = 0; t < 160; ++t) {
    const int rb = t & 1, wb = rb ^ 1;
    floatx4 a0 = {bi0, bi0, bi0, bi0};
    floatx4 a1 = {bf0, bf0, bf0, bf0};
    floatx4 a2 = {bg0, bg0, bg0, bg0};
    floatx4 a3 = {bo0, bo0, bo0, bo0};
    const unsigned short* ar = &hA0[rb][lo][hi * 8];
#pragma unroll
    for (int ks = 0; ks < 4; ++ks) {
      const short8 afr = *(const short8*)(ar + ks * 32);
      a0 = __builtin_amdgcn_mfma_f32_16x16x32_bf16(afr, B0[0][ks], a0, 0, 0, 0);
      a1 = __builtin_amdgcn_mfma_f32_16x16x32_bf16(afr, B0[1][ks], a1, 0, 0, 0);
      a2 = __builtin_amdgcn_mfma_f32_16x16x32_bf16(afr, B0[2][ks], a2, 0, 0, 0);
      a3 = __builtin_amdgcn_mfma_f32_16x16x32_bf16(afr, B0[3][ks], a3, 0, 0, 0);
    }
    const size_t obase = (size_t)(t * 64 + nb * 16) * 128;
#pragma unroll
    for (int r = 0; r < 4; ++r) {
      const float iv = sgm(a0[r]);
      const float fv = sgm(a1[r]);
      const float gv = tanhf_(a2[r]);
      const float ov = sgm(a3[r]);
      const float cn = fv * c0[r] + iv * gv;
      c0[r] = cn;
      const unsigned short hb = f2b(ov * tanhf_(cn));
      const int q = hi * 4 + r;
      hA0[wb][q][u] = hb;
      h0w[obase + (size_t)q * 128 + u] = hb;
    }
    __syncthreads();
  }
}

// ---------------------------------------------------------------------------
// xgemm: X3[g>>4][t][col][g&15] = sum_u h0w[t][g][u] * wih1[col][u]  (bf16)
// grid (160,4) x 256 thr.
// ---------------------------------------------------------------------------
__global__ __launch_bounds__(256) void xgemm(
    const unsigned short* __restrict__ h0w,  // bf16 [160][64][128]
    const float* __restrict__ nwih,          // [512][128] (layer-1 wih)
    unsigned short* __restrict__ X3)         // bf16 [4][160][512][16]
{
  const int tid = threadIdx.x;
  const int wv  = tid >> 6;
  const int lane = tid & 63;
  const int lo  = lane & 15;
  const int hi  = lane >> 4;
  const int bt  = blockIdx.x;
  const int bn  = blockIdx.y;

  __shared__ __align__(16) unsigned short s_b[128][136];

  for (int i = tid; i < 128 * 32; i += 256) {
    const int nc = i >> 5, k4 = (i & 31) * 4;
    const float4 w = *(const float4*)&nwih[(size_t)(bn * 128 + nc) * 128 + k4];
    s_b[nc][k4]     = f2b(w.x);
    s_b[nc][k4 + 1] = f2b(w.y);
    s_b[nc][k4 + 2] = f2b(w.z);
    s_b[nc][k4 + 3] = f2b(w.w);
  }
  __syncthreads();

  floatx4 acc[8];
#pragma unroll
  for (int nt = 0; nt < 8; ++nt) acc[nt] = (floatx4){0.f, 0.f, 0.f, 0.f};

  const unsigned short* arow = h0w + (size_t)(bt * 64 + wv * 16 + lo) * 128 + hi * 8;
#pragma unroll
  for (int ks = 0; ks < 4; ++ks) {
    const short8 afr = *(const short8*)(arow + ks * 32);
#pragma unroll
    for (int nt = 0; nt < 8; ++nt) {
      const short8 bfr = *(const short8*)&s_b[nt * 16 + lo][ks * 32 + hi * 8];
      acc[nt] = __builtin_amdgcn_mfma_f32_16x16x32_bf16(afr, bfr, acc[nt], 0, 0, 0);
    }
  }

#pragma unroll
  for (int nt = 0; nt < 8; ++nt) {
    const size_t base3 = ((((size_t)wv * 160 + bt) * 512) + bn * 128 + nt * 16 + lo) * 16 + hi * 4;
    short4v xv;
#pragma unroll
    for (int r = 0; r < 4; ++r) xv[r] = (short)f2b(acc[nt][r]);
    *(short4v*)&X3[base3] = xv;
  }
}

// ---------------------------------------------------------------------------
// node_l1: 4 blocks x 512 threads. whh1 in 64 VGPRs; input-half streamed from
// X3 (contiguous 16KB/block/step, prefetched one step ahead).
// ---------------------------------------------------------------------------
__global__ __launch_bounds__(512) void node_l1(
    const unsigned short* __restrict__ hinit, // bf16 [64][128]
    const unsigned short* __restrict__ X3,    // bf16 [4][160][512][16]
    const float* __restrict__ nwhh,           // [2][512][128] (layer1 = 2nd half)
    const float* __restrict__ nbih,           // [2][512]
    const float* __restrict__ nbhh,           // [2][512]
    unsigned short* __restrict__ nout)        // bf16 [10240][128]
{
  const int tid  = threadIdx.x;
  const int wv   = tid >> 6;
  const int lane = tid & 63;
  const int lo   = lane & 15;
  const int hi   = lane >> 4;
  const int u    = (wv << 4) | lo;
  const int nb   = blockIdx.x;

  __shared__ __align__(16) unsigned short hA1[2][16][136];

  short8 B1[4][4];
#pragma unroll
  for (int t = 0; t < 4; ++t) {
    const int n = t * 128 + u;
#pragma unroll
    for (int ks = 0; ks < 4; ++ks) {
      const float* src = nwhh + 512 * 128 + n * 128 + ks * 32 + hi * 8;
      short8 bfr;
#pragma unroll
      for (int jj = 0; jj < 8; ++jj) bfr[jj] = (short)f2b(src[jj]);
      B1[t][ks] = bfr;
    }
  }

  const float bi1 = nbih[512 + u]       + nbhh[512 + u];
  const float bf1 = nbih[512 + 128 + u] + nbhh[512 + 128 + u];
  const float bg1 = nbih[512 + 256 + u] + nbhh[512 + 256 + u];
  const float bo1 = nbih[512 + 384 + u] + nbhh[512 + 384 + u];

  {
    const int q  = tid >> 5;
    const int u4 = (tid & 31) * 4;
    const short4v hv = *(const short4v*)&hinit[(size_t)(nb * 16 + q) * 128 + u4];
    *(short4v*)&hA1[0][q][u4] = hv;
  }

  float c1[4] = {0.f, 0.f, 0.f, 0.f};

  const size_t xstep = 512 * 16;
  const unsigned short* xb = X3 + ((size_t)nb * 160) * xstep + (size_t)u * 16 + hi * 4;
  short4v x0 = *(const short4v*)(xb);
  short4v x1 = *(const short4v*)(xb + 128 * 16);
  short4v x2 = *(const short4v*)(xb + 256 * 16);
  short4v x3 = *(const short4v*)(xb + 384 * 16);
  __syncthreads();

  for (int t = 0; t < 160; ++t) {
    const int rb = t & 1, wb = rb ^ 1;

    floatx4 a0 = {bi1, bi1, bi1, bi1};
    floatx4 a1 = {bf1, bf1, bf1, bf1};
    floatx4 a2 = {bg1, bg1, bg1, bg1};
    floatx4 a3 = {bo1, bo1, bo1, bo1};
    const unsigned short* ar = &hA1[rb][lo][hi * 8];
#pragma unroll
    for (int ks = 0; ks < 4; ++ks) {
      const short8 afr = *(const short8*)(ar + ks * 32);
      a0 = __builtin_amdgcn_mfma_f32_16x16x32_bf16(afr, B1[0][ks], a0, 0, 0, 0);
      a1 = __builtin_amdgcn_mfma_f32_16x16x32_bf16(afr, B1[1][ks], a1, 0, 0, 0);
      a2 = __builtin_amdgcn_mfma_f32_16x16x32_bf16(afr, B1[2][ks], a2, 0, 0, 0);
      a3 = __builtin_amdgcn_mfma_f32_16x16x32_bf16(afr, B1[3][ks], a3, 0, 0, 0);
    }

    const short4v cx0 = x0, cx1 = x1, cx2 = x2, cx3 = x3;
    if (t + 1 < 160) {
      const unsigned short* xn = xb + (size_t)(t + 1) * xstep;
      x0 = *(const short4v*)(xn);
      x1 = *(const short4v*)(xn + 128 * 16);
      x2 = *(const short4v*)(xn + 256 * 16);
      x3 = *(const short4v*)(xn + 384 * 16);
    }

    const size_t obase = (size_t)((159 - t) * 64 + nb * 16) * 128;
#pragma unroll
    for (int r = 0; r < 4; ++r) {
      const float iv = sgm(a0[r] + b2f((unsigned short)cx0[r]));
      const float fv = sgm(a1[r] + b2f((unsigned short)cx1[r]));
      const float gv = tanhf_(a2[r] + b2f((unsigned short)cx2[r]));
      const float ov = sgm(a3[r] + b2f((unsigned short)cx3[r]));
      const float cn = fv * c1[r] + iv * gv;
      c1[r] = cn;
      const unsigned short hb = f2b(ov * tanhf_(cn));
      const int q = hi * 4 + r;
      hA1[wb][q][u] = hb;
      nout[obase + (size_t)q * 128 + u] = hb;
    }
    __syncthreads();
  }
}

// ---------------------------------------------------------------------------
// Edge: 640 blocks x 256 threads. Snake-permuted block id bb; block bb owns
// seqs [16bb,16bb+16) -> all 4 waves share jrow (no intra-block stragglers),
// and same-CU blocks {d,d+256,d+512} have constant jrow sums. L1's h1-half
// dots computed before the h0 LDS round trip. No block barriers in the loop.
// ---------------------------------------------------------------------------
__global__ __launch_bounds__(256, 1) void edge_kernel(
    const unsigned short* __restrict__ nflat, // bf16 [10240][128]
    const float* __restrict__ exw, const float* __restrict__ exb,   // [32][128],[32]
    const float* __restrict__ enw, const float* __restrict__ enb,   // [16][32],[16]
    const float* __restrict__ ewih,  // [1][64][16]
    const float* __restrict__ ewhh,  // [2][64][16]
    const float* __restrict__ ebih, const float* __restrict__ ebhh, // [2][64]
    const float* __restrict__ ee1w, const float* __restrict__ ee1b,
    const float* __restrict__ ee2w, const float* __restrict__ ee2b,
    const float* __restrict__ ef1w, const float* __restrict__ ef1b,
    const float* __restrict__ ef2w, const float* __restrict__ ef2b,
    float* __restrict__ out)
{
  const int tid = threadIdx.x;
  const int sg  = tid >> 4;
  const int u   = tid & 15;
  const int b   = blockIdx.x;

  // snake permutation: dispatch rows {0,1,2} -> bb = r, 511-r, 512+r
  const int row = b >> 8, r = b & 255;
  const int bb  = (row == 1) ? (511 - r) : ((row << 8) + r);
  const int kbase = bb * 16;
  const int jrow  = 160 - (bb >> 2);   // uniform for all seqs of this block
  const int gid   = (kbase & 63) + sg;

  __shared__ __align__(16) float s_nf[16][132];
  __shared__ __align__(16) float s_w0[64][20];
  __shared__ __align__(16) float s_w1[64][36];
  __shared__ __align__(16) float h0b[16][20];
  __shared__ __align__(16) float h1b[16][20];
  __shared__ __align__(16) float t1b[16][12];
  __shared__ __align__(16) float t2b[16][12];
  __shared__ __align__(16) float x32[16][36];

  for (int i = tid; i < 16 * 128; i += 256)
    s_nf[i >> 7][i & 127] = b2f(nflat[(size_t)(kbase + (i >> 7)) * 128 + (i & 127)]);
  for (int i = tid; i < 64 * 16; i += 256) {
    s_w0[i >> 4][i & 15] = ewhh[i];                 // layer0 whh
    s_w1[i >> 4][i & 15] = ewih[i];                 // layer1 wih
    s_w1[i >> 4][16 + (i & 15)] = ewhh[1024 + i];   // layer1 whh
  }

  // zero the (never-written) diagonal; graph g == b for first 64 blocks
  if (b < NG) {
    for (int d = tid; d < NMAX; d += 256) {
      out[(size_t)b * (NMAX * NMAX) + (size_t)d * NMAX + d] = 0.0f;
      float* fb = out + (size_t)NG * NMAX * NMAX
                + ((size_t)b * NMAX * NMAX + (size_t)d * NMAX + d) * 16;
#pragma unroll
      for (int q = 0; q < 16; ++q) fb[q] = 0.0f;
    }
  }

  // ---- per-thread constants from global (read once) ----
  const float be0i = ebih[u]      + ebhh[u];
  const float be0f = ebih[16 + u] + ebhh[16 + u];
  const float be0g = ebih[32 + u] + ebhh[32 + u];
  const float be0o = ebih[48 + u] + ebhh[48 + u];
  const float be1i = ebih[64 + u]      + ebhh[64 + u];
  const float be1f = ebih[64 + 16 + u] + ebhh[64 + 16 + u];
  const float be1g = ebih[64 + 32 + u] + ebhh[64 + 32 + u];
  const float be1o = ebih[64 + 48 + u] + ebhh[64 + 48 + u];
  const float hbias = (u < 8) ? ee1b[u] : ef1b[u - 8];
  const float f2bl = ef2b[u], f2bu = ef2b[16 + u];
  const float4 wl0 = *(const float4*)&ef2w[u * 8];
  const float4 wl1 = *(const float4*)&ef2w[u * 8 + 4];
  const float4 wu0 = *(const float4*)&ef2w[(16 + u) * 8];
  const float4 wu1 = *(const float4*)&ef2w[(16 + u) * 8 + 4];
  const int ue = (u < 2) ? u : 0;
  const float4 we0 = *(const float4*)&ee2w[ue * 8];
  const float4 we1 = *(const float4*)&ee2w[ue * 8 + 4];
  const float e2bias = (u < 2) ? ee2b[u] : 0.0f;
  const float* whp = (u < 8) ? (ee1w + u * 16) : (ef1w + (u - 8) * 16);
  float4 WH[4];
#pragma unroll
  for (int qq = 0; qq < 4; ++qq) WH[qq] = *(const float4*)&whp[qq * 4];

  __syncthreads();   // the ONLY block barrier

  // ---- h0e = relu(relu(nf @ exw^T + exb) @ enw^T + enb) ----
  {
    float acc0 = exb[u], acc1 = exb[16 + u];
    const float* w0p = exw + u * 128;
    const float* w1p = exw + (16 + u) * 128;
    for (int qq = 0; qq < 32; ++qq) {
      const float4 nv  = *(const float4*)&s_nf[sg][qq * 4];
      const float4 w0v = *(const float4*)&w0p[qq * 4];
      const float4 w1v = *(const float4*)&w1p[qq * 4];
      acc0 += nv.x * w0v.x + nv.y * w0v.y + nv.z * w0v.z + nv.w * w0v.w;
      acc1 += nv.x * w1v.x + nv.y * w1v.y + nv.z * w1v.z + nv.w * w1v.w;
    }
    x32[sg][u] = fmaxf(acc0, 0.0f);
    x32[sg][16 + u] = fmaxf(acc1, 0.0f);
  }
  __builtin_amdgcn_wave_barrier();
  float c0 = 0.0f, c1 = 0.0f;
  {
    float acc = enb[u];
    const float* ewp = enw + u * 32;
#pragma unroll
    for (int qq = 0; qq < 8; ++qq) {
      const float4 xv  = *(const float4*)&x32[sg][qq * 4];
      const float4 wv2 = *(const float4*)&ewp[qq * 4];
      acc += xv.x * wv2.x + xv.y * wv2.y + xv.z * wv2.z + xv.w * wv2.w;
    }
    const float h0e = fmaxf(acc, 0.0f);
    h0b[sg][u] = h0e;
    h1b[sg][u] = h0e;
  }
  __builtin_amdgcn_wave_barrier();

  float* exi = out + (size_t)gid * (NMAX * NMAX);
  float* fea = out + (size_t)NG * NMAX * NMAX + (size_t)gid * (NMAX * NMAX) * 16;

  for (int s = 0; s < jrow; ++s) {
    float gi, gf, gg, go;       // L0 gates
    float pi, pf, pg, po;       // L1 partials (h1-half, independent of h0 new)
    { // L0 gate dots (h0b = h0_{s-1})
      float ai = be0i, af = be0f, ag = be0g, ao = be0o;
#pragma unroll
      for (int qq = 0; qq < 4; ++qq) {
        const float4 hv = *(const float4*)&h0b[sg][qq * 4];
        const float4 wi = *(const float4*)&s_w0[u][qq * 4];
        const float4 wf = *(const float4*)&s_w0[16 + u][qq * 4];
        const float4 wg = *(const float4*)&s_w0[32 + u][qq * 4];
        const float4 wo = *(const float4*)&s_w0[48 + u][qq * 4];
        ai += hv.x * wi.x + hv.y * wi.y + hv.z * wi.z + hv.w * wi.w;
        af += hv.x * wf.x + hv.y * wf.y + hv.z * wf.z + hv.w * wf.w;
        ag += hv.x * wg.x + hv.y * wg.y + hv.z * wg.z + hv.w * wg.w;
        ao += hv.x * wo.x + hv.y * wo.y + hv.z * wo.z + hv.w * wo.w;
      }
      gi = ai; gf = af; gg = ag; go = ao;
    }
    { // L1 h1-half dots (h1b = h1_{s-1}) — fills the h0 round-trip stall
      float ai = be1i, af = be1f, ag = be1g, ao = be1o;
#pragma unroll
      for (int qq = 0; qq < 4; ++qq) {
        const float4 hv = *(const float4*)&h1b[sg][qq * 4];
        const float4 wi = *(const float4*)&s_w1[u][16 + qq * 4];
        const float4 wf = *(const float4*)&s_w1[16 + u][16 + qq * 4];
        const float4 wg = *(const float4*)&s_w1[32 + u][16 + qq * 4];
        const float4 wo = *(const float4*)&s_w1[48 + u][16 + qq * 4];
        ai += hv.x * wi.x + hv.y * wi.y + hv.z * wi.z + hv.w * wi.w;
        af += hv.x * wf.x + hv.y * wf.y + hv.z * wf.z + hv.w * wf.w;
        ag += hv.x * wg.x + hv.y * wg.y + hv.z * wg.z + hv.w * wg.w;
        ao += hv.x * wo.x + hv.y * wo.y + hv.z * wo.z + hv.w * wo.w;
      }
      pi = ai; pf = af; pg = ag; po = ao;
    }
    __builtin_amdgcn_wave_barrier();
    { // h0 activation
      const float iv = sgm(gi), fv = sgm(gf), gv = tanhf_(gg), ov = sgm(go);
      c0 = fv * c0 + iv * gv;
      h0b[sg][u] = ov * tanhf_(c0);
    }
    __builtin_amdgcn_wave_barrier();
    { // L1 h0-half dots (fresh h0b), add to partials
#pragma unroll
      for (int qq = 0; qq < 4; ++qq) {
        const float4 hv = *(const float4*)&h0b[sg][qq * 4];
        const float4 wi = *(const float4*)&s_w1[u][qq * 4];
        const float4 wf = *(const float4*)&s_w1[16 + u][qq * 4];
        const float4 wg = *(const float4*)&s_w1[32 + u][qq * 4];
        const float4 wo = *(const float4*)&s_w1[48 + u][qq * 4];
        pi += hv.x * wi.x + hv.y * wi.y + hv.z * wi.z + hv.w * wi.w;
        pf += hv.x * wf.x + hv.y * wf.y + hv.z * wf.z + hv.w * wf.w;
        pg += hv.x * wg.x + hv.y * wg.y + hv.z * wg.z + hv.w * wg.w;
        po += hv.x * wo.x + hv.y * wo.y + hv.z * wo.z + hv.w * wo.w;
      }
    }
    __builtin_amdgcn_wave_barrier();
    { // h1 activation
      const float iv = sgm(pi), fv = sgm(pf), gv = tanhf_(pg), ov = sgm(po);
      c1 = fv * c1 + iv * gv;
      h1b[sg][u] = ov * tanhf_(c1);   // = eh[s]
    }
    __builtin_amdgcn_wave_barrier();
    // ---- heads (weights in regs) ----
    {
      float a = hbias;
#pragma unroll
      for (int qq = 0; qq < 4; ++qq) {
        const float4 hv = *(const float4*)&h1b[sg][qq * 4];
        a += hv.x * WH[qq].x + hv.y * WH[qq].y + hv.z * WH[qq].z + hv.w * WH[qq].w;
      }
      a = fmaxf(a, 0.0f);
      if (u < 8) t1b[sg][u] = a; else t2b[sg][u - 8] = a;
    }
    __builtin_amdgcn_wave_barrier();
    {
      const float4 ta = *(const float4*)&t2b[sg][0];
      const float4 tb = *(const float4*)&t2b[sg][4];
      const float fl = f2bl
          + ta.x * wl0.x + ta.y * wl0.y + ta.z * wl0.z + ta.w * wl0.w
          + tb.x * wl1.x + tb.y * wl1.y + tb.z * wl1.z + tb.w * wl1.w;
      const float fu = f2bu
          + ta.x * wu0.x + ta.y * wu0.y + ta.z * wu0.z + ta.w * wu0.w
          + tb.x * wu1.x + tb.y * wu1.y + tb.z * wu1.z + tb.w * wu1.w;
      fea[((size_t)jrow * NMAX + s) * 16 + u] = fl;
      fea[((size_t)s * NMAX + jrow) * 16 + u] = fu;
      if (u < 2) {
        const float4 t1a = *(const float4*)&t1b[sg][0];
        const float4 t1c = *(const float4*)&t1b[sg][4];
        float e = e2bias
            + t1a.x * we0.x + t1a.y * we0.y + t1a.z * we0.z + t1a.w * we0.w
            + t1c.x * we1.x + t1c.y * we1.y + t1c.z * we1.z + t1c.w * we1.w;
        const size_t idx = (u == 0) ? ((size_t)jrow * NMAX + s)
                                    : ((size_t)s * NMAX + jrow);
        exi[idx] = sgm(e);
      }
    }
    __builtin_amdgcn_wave_barrier();
  }
}

extern "C" void kernel_launch(void* const* d_in, const int* in_sizes, int n_in,
                              void* d_out, int out_size, void* d_ws, size_t ws_size,
                              hipStream_t stream) {
  (void)in_sizes; (void)n_in; (void)out_size; (void)ws_size;
  const float* gene = (const float*)d_in[0];
  const float* entw = (const float*)d_in[1];
  const float* entb = (const float*)d_in[2];
  const float* nwih = (const float*)d_in[4];
  const float* nwhh = (const float*)d_in[5];
  const float* nbih = (const float*)d_in[6];
  const float* nbhh = (const float*)d_in[7];
  const float* exw  = (const float*)d_in[8];
  const float* exb  = (const float*)d_in[9];
  const float* enw  = (const float*)d_in[10];
  const float* enb  = (const float*)d_in[11];
  const float* ewih = (const float*)d_in[13];
  const float* ewhh = (const float*)d_in[14];
  const float* ebih = (const float*)d_in[15];
  const float* ebhh = (const float*)d_in[16];
  const float* ee1w = (const float*)d_in[17];
  const float* ee1b = (const float*)d_in[18];
  const float* ee2w = (const float*)d_in[19];
  const float* ee2b = (const float*)d_in[20];
  const float* ef1w = (const float*)d_in[21];
  const float* ef1b = (const float*)d_in[22];
  const float* ef2w = (const float*)d_in[23];
  const float* ef2b = (const float*)d_in[24];

  // ws layout (bytes):
  //   nflat @ 0         : 10240*128*2 = 2,621,440
  //   h0w   @ 2621440   : 160*64*128*2 = 2,621,440
  //   hinit @ 5242880   : 64*128*2 = 16,384
  //   X3    @ 5259264   : 4*160*512*16*2 = 10,485,760
  char* ws = (char*)d_ws;
  unsigned short* nflat = (unsigned short*)(ws);
  unsigned short* h0w   = (unsigned short*)(ws + 2621440);
  unsigned short* hinit = (unsigned short*)(ws + 5242880);
  unsigned short* X3    = (unsigned short*)(ws + 5259264);

  node_l0<<<4, 512, 0, stream>>>(gene, entw, entb, nwhh, nbih, nbhh, h0w, hinit);
  xgemm<<<dim3(160, 4), 256, 0, stream>>>(h0w, nwih, X3);
  node_l1<<<4, 512, 0, stream>>>(hinit, X3, nwhh, nbih, nbhh, nflat);
  edge_kernel<<<640, 256, 0, stream>>>(nflat, exw, exb, enw, enb, ewih, ewhh,
                                       ebih, ebhh, ee1w, ee1b, ee2w, ee2b,
                                       ef1w, ef1b, ef2w, ef2b, (float*)d_out);
}

// Round 8
// 610.393 us; speedup vs baseline: 1.7646x; 1.0321x over previous
//
#include <hip/hip_runtime.h>

// GraphGenRnn — R8: edge LSTM recurrence moved fully into registers.
// h0/h1 live one-element-per-lane in each 16-lane group; gate dots use DPP
// row_ror:j broadcasts (out[i]=in[(i+j)&15]) against per-lane pre-rotated
// weight registers (192 VGPRs). No LDS/barriers on the recurrent path; heads
// (cross-lane t exchange) pipelined one step late through LDS so their RAW
// latency hides under the next step's register-only dot phases.
// Node kernels unchanged from R7.

typedef __attribute__((ext_vector_type(8))) short short8;
typedef __attribute__((ext_vector_type(4))) short short4v;
typedef __attribute__((ext_vector_type(4))) float floatx4;

#define NG 64
#define NMAX 161

__device__ __forceinline__ float sgm(float x) {
  return __builtin_amdgcn_rcpf(1.0f + __expf(-x));
}
__device__ __forceinline__ float tanhf_(float x) {
  return 2.0f * __builtin_amdgcn_rcpf(1.0f + __expf(-2.0f * x)) - 1.0f;
}
__device__ __forceinline__ unsigned short f2b(float x) {
  union { float f; unsigned u; } v; v.f = x;
  unsigned r = v.u + 0x7fffu + ((v.u >> 16) & 1u);   // RNE to bf16
  return (unsigned short)(r >> 16);
}
__device__ __forceinline__ float b2f(unsigned short h) {
  union { unsigned u; float f; } v; v.u = ((unsigned)h) << 16; return v.f;
}

// DPP row_ror:N within 16-lane rows: out[i] = in[(i+N)&15]
#define RORF(x, N) __builtin_bit_cast(float, __builtin_amdgcn_update_dpp(      \
    __builtin_bit_cast(int, (x)), __builtin_bit_cast(int, (x)),                \
    0x120 | (N), 0xF, 0xF, false))

#define DOTJ(W, h, J, q0, q1, q2, q3) {                                        \
    const float hj_ = RORF((h), J);                                            \
    q0 += hj_ * W[0][J]; q1 += hj_ * W[1][J];                                  \
    q2 += hj_ * W[2][J]; q3 += hj_ * W[3][J]; }

#define DOT16(W, h, a0, a1, a2, a3, b0, b1, b2, b3)                            \
  { const float hz_ = (h);                                                     \
    a0 += hz_ * W[0][0]; a1 += hz_ * W[1][0];                                  \
    a2 += hz_ * W[2][0]; a3 += hz_ * W[3][0]; }                                \
  DOTJ(W, h, 1,  b0, b1, b2, b3)  DOTJ(W, h, 2,  a0, a1, a2, a3)               \
  DOTJ(W, h, 3,  b0, b1, b2, b3)  DOTJ(W, h, 4,  a0, a1, a2, a3)               \
  DOTJ(W, h, 5,  b0, b1, b2, b3)  DOTJ(W, h, 6,  a0, a1, a2, a3)               \
  DOTJ(W, h, 7,  b0, b1, b2, b3)  DOTJ(W, h, 8,  a0, a1, a2, a3)               \
  DOTJ(W, h, 9,  b0, b1, b2, b3)  DOTJ(W, h, 10, a0, a1, a2, a3)               \
  DOTJ(W, h, 11, b0, b1, b2, b3)  DOTJ(W, h, 12, a0, a1, a2, a3)               \
  DOTJ(W, h, 13, b0, b1, b2, b3)  DOTJ(W, h, 14, a0, a1, a2, a3)               \
  DOTJ(W, h, 15, b0, b1, b2, b3)

// ---------------------------------------------------------------------------
// node_l0: 4 blocks x 512 threads. Wave w: units [16w,16w+16), whh0 in 64
// VGPRs. h0 double-buffered in LDS, 1 barrier/step. Streams h0_t to h0w.
// ---------------------------------------------------------------------------
__global__ __launch_bounds__(512) void node_l0(
    const float* __restrict__ gene,   // [64][128]
    const float* __restrict__ entw,   // [128][128]
    const float* __restrict__ entb,   // [128]
    const float* __restrict__ nwhh,   // [2][512][128] (layer0 = first half)
    const float* __restrict__ nbih,   // [2][512]
    const float* __restrict__ nbhh,   // [2][512]
    unsigned short* __restrict__ h0w,   // bf16 [160][64][128]
    unsigned short* __restrict__ hinit) // bf16 [64][128]
{
  const int tid  = threadIdx.x;
  const int wv   = tid >> 6;
  const int lane = tid & 63;
  const int lo   = lane & 15;
  const int hi   = lane >> 4;
  const int u    = (wv << 4) | lo;
  const int nb   = blockIdx.x;

  __shared__ __align__(16) unsigned short hA0[2][16][136];

  short8 B0[4][4];
#pragma unroll
  for (int t = 0; t < 4; ++t) {
    const int n = t * 128 + u;
#pragma unroll
    for (int ks = 0; ks < 4; ++ks) {
      const float* src = nwhh + n * 128 + ks * 32 + hi * 8;
      short8 bfr;
#pragma unroll
      for (int jj = 0; jj < 8; ++jj) bfr[jj] = (short)f2b(src[jj]);
      B0[t][ks] = bfr;
    }
  }

  const float bi0 = nbih[u]       + nbhh[u];
  const float bf0 = nbih[128 + u] + nbhh[128 + u];
  const float bg0 = nbih[256 + u] + nbhh[256 + u];
  const float bo0 = nbih[384 + u] + nbhh[384 + u];

  {
    const int q  = tid >> 5;
    const int u4 = (tid & 31) * 4;
    const float* gc = gene + (nb * 16 + q) * 128;
    float acc[4] = { entb[u4], entb[u4 + 1], entb[u4 + 2], entb[u4 + 3] };
    for (int qq = 0; qq < 32; ++qq) {
      const float4 gv = *(const float4*)&gc[qq * 4];
#pragma unroll
      for (int r = 0; r < 4; ++r) {
        const float4 wv2 = *(const float4*)&entw[(u4 + r) * 128 + qq * 4];
        acc[r] += gv.x * wv2.x + gv.y * wv2.y + gv.z * wv2.z + gv.w * wv2.w;
      }
    }
#pragma unroll
    for (int r = 0; r < 4; ++r) {
      const unsigned short hb = f2b(fmaxf(acc[r], 0.0f));
      hA0[0][q][u4 + r] = hb;
      hinit[(size_t)(nb * 16 + q) * 128 + u4 + r] = hb;
    }
  }

  float c0[4] = {0.f, 0.f, 0.f, 0.f};
  __syncthreads();

  for (int t = 0; t < 160; ++t) {
    const int rb = t & 1, wb = rb ^ 1;
    floatx4 a0 = {bi0, bi0, bi0, bi0};
    floatx4 a1 = {bf0, bf0, bf0, bf0};
    floatx4 a2 = {bg0, bg0, bg0, bg0};
    floatx4 a3 = {bo0, bo0, bo0, bo0};
    const unsigned short* ar = &hA0[rb][lo][hi * 8];
#pragma unroll
    for (int ks = 0; ks < 4; ++ks) {
      const short8 afr = *(const short8*)(ar + ks * 32);
      a0 = __builtin_amdgcn_mfma_f32_16x16x32_bf16(afr, B0[0][ks], a0, 0, 0, 0);
      a1 = __builtin_amdgcn_mfma_f32_16x16x32_bf16(afr, B0[1][ks], a1, 0, 0, 0);
      a2 = __builtin_amdgcn_mfma_f32_16x16x32_bf16(afr, B0[2][ks], a2, 0, 0, 0);
      a3 = __builtin_amdgcn_mfma_f32_16x16x32_bf16(afr, B0[3][ks], a3, 0, 0, 0);
    }
    const size_t obase = (size_t)(t * 64 + nb * 16) * 128;
#pragma unroll
    for (int r = 0; r < 4; ++r) {
      const float iv = sgm(a0[r]);
      const float fv = sgm(a1[r]);
      const float gv = tanhf_(a2[r]);
      const float ov = sgm(a3[r]);
      const float cn = fv * c0[r] + iv * gv;
      c0[r] = cn;
      const unsigned short hb = f2b(ov * tanhf_(cn));
      const int q = hi * 4 + r;
      hA0[wb][q][u] = hb;
      h0w[obase + (size_t)q * 128 + u] = hb;
    }
    __syncthreads();
  }
}

// ---------------------------------------------------------------------------
// xgemm: X3[g>>4][t][col][g&15] = sum_u h0w[t][g][u] * wih1[col][u]  (bf16)
// ---------------------------------------------------------------------------
__global__ __launch_bounds__(256) void xgemm(
    const unsigned short* __restrict__ h0w,  // bf16 [160][64][128]
    const float* __restrict__ nwih,          // [512][128] (layer-1 wih)
    unsigned short* __restrict__ X3)         // bf16 [4][160][512][16]
{
  const int tid = threadIdx.x;
  const int wv  = tid >> 6;
  const int lane = tid & 63;
  const int lo  = lane & 15;
  const int hi  = lane >> 4;
  const int bt  = blockIdx.x;
  const int bn  = blockIdx.y;

  __shared__ __align__(16) unsigned short s_b[128][136];

  for (int i = tid; i < 128 * 32; i += 256) {
    const int nc = i >> 5, k4 = (i & 31) * 4;
    const float4 w = *(const float4*)&nwih[(size_t)(bn * 128 + nc) * 128 + k4];
    s_b[nc][k4]     = f2b(w.x);
    s_b[nc][k4 + 1] = f2b(w.y);
    s_b[nc][k4 + 2] = f2b(w.z);
    s_b[nc][k4 + 3] = f2b(w.w);
  }
  __syncthreads();

  floatx4 acc[8];
#pragma unroll
  for (int nt = 0; nt < 8; ++nt) acc[nt] = (floatx4){0.f, 0.f, 0.f, 0.f};

  const unsigned short* arow = h0w + (size_t)(bt * 64 + wv * 16 + lo) * 128 + hi * 8;
#pragma unroll
  for (int ks = 0; ks < 4; ++ks) {
    const short8 afr = *(const short8*)(arow + ks * 32);
#pragma unroll
    for (int nt = 0; nt < 8; ++nt) {
      const short8 bfr = *(const short8*)&s_b[nt * 16 + lo][ks * 32 + hi * 8];
      acc[nt] = __builtin_amdgcn_mfma_f32_16x16x32_bf16(afr, bfr, acc[nt], 0, 0, 0);
    }
  }

#pragma unroll
  for (int nt = 0; nt < 8; ++nt) {
    const size_t base3 = ((((size_t)wv * 160 + bt) * 512) + bn * 128 + nt * 16 + lo) * 16 + hi * 4;
    short4v xv;
#pragma unroll
    for (int r = 0; r < 4; ++r) xv[r] = (short)f2b(acc[nt][r]);
    *(short4v*)&X3[base3] = xv;
  }
}

// ---------------------------------------------------------------------------
// node_l1: 4 blocks x 512 threads. whh1 in 64 VGPRs; input-half streamed from
// X3 (contiguous 16KB/block/step, prefetched one step ahead).
// ---------------------------------------------------------------------------
__global__ __launch_bounds__(512) void node_l1(
    const unsigned short* __restrict__ hinit, // bf16 [64][128]
    const unsigned short* __restrict__ X3,    // bf16 [4][160][512][16]
    const float* __restrict__ nwhh,           // [2][512][128] (layer1 = 2nd half)
    const float* __restrict__ nbih,           // [2][512]
    const float* __restrict__ nbhh,           // [2][512]
    unsigned short* __restrict__ nout)        // bf16 [10240][128]
{
  const int tid  = threadIdx.x;
  const int wv   = tid >> 6;
  const int lane = tid & 63;
  const int lo   = lane & 15;
  const int hi   = lane >> 4;
  const int u    = (wv << 4) | lo;
  const int nb   = blockIdx.x;

  __shared__ __align__(16) unsigned short hA1[2][16][136];

  short8 B1[4][4];
#pragma unroll
  for (int t = 0; t < 4; ++t) {
    const int n = t * 128 + u;
#pragma unroll
    for (int ks = 0; ks < 4; ++ks) {
      const float* src = nwhh + 512 * 128 + n * 128 + ks * 32 + hi * 8;
      short8 bfr;
#pragma unroll
      for (int jj = 0; jj < 8; ++jj) bfr[jj] = (short)f2b(src[jj]);
      B1[t][ks] = bfr;
    }
  }

  const float bi1 = nbih[512 + u]       + nbhh[512 + u];
  const float bf1 = nbih[512 + 128 + u] + nbhh[512 + 128 + u];
  const float bg1 = nbih[512 + 256 + u] + nbhh[512 + 256 + u];
  const float bo1 = nbih[512 + 384 + u] + nbhh[512 + 384 + u];

  {
    const int q  = tid >> 5;
    const int u4 = (tid & 31) * 4;
    const short4v hv = *(const short4v*)&hinit[(size_t)(nb * 16 + q) * 128 + u4];
    *(short4v*)&hA1[0][q][u4] = hv;
  }

  float c1[4] = {0.f, 0.f, 0.f, 0.f};

  const size_t xstep = 512 * 16;
  const unsigned short* xb = X3 + ((size_t)nb * 160) * xstep + (size_t)u * 16 + hi * 4;
  short4v x0 = *(const short4v*)(xb);
  short4v x1 = *(const short4v*)(xb + 128 * 16);
  short4v x2 = *(const short4v*)(xb + 256 * 16);
  short4v x3 = *(const short4v*)(xb + 384 * 16);
  __syncthreads();

  for (int t = 0; t < 160; ++t) {
    const int rb = t & 1, wb = rb ^ 1;

    floatx4 a0 = {bi1, bi1, bi1, bi1};
    floatx4 a1 = {bf1, bf1, bf1, bf1};
    floatx4 a2 = {bg1, bg1, bg1, bg1};
    floatx4 a3 = {bo1, bo1, bo1, bo1};
    const unsigned short* ar = &hA1[rb][lo][hi * 8];
#pragma unroll
    for (int ks = 0; ks < 4; ++ks) {
      const short8 afr = *(const short8*)(ar + ks * 32);
      a0 = __builtin_amdgcn_mfma_f32_16x16x32_bf16(afr, B1[0][ks], a0, 0, 0, 0);
      a1 = __builtin_amdgcn_mfma_f32_16x16x32_bf16(afr, B1[1][ks], a1, 0, 0, 0);
      a2 = __builtin_amdgcn_mfma_f32_16x16x32_bf16(afr, B1[2][ks], a2, 0, 0, 0);
      a3 = __builtin_amdgcn_mfma_f32_16x16x32_bf16(afr, B1[3][ks], a3, 0, 0, 0);
    }

    const short4v cx0 = x0, cx1 = x1, cx2 = x2, cx3 = x3;
    if (t + 1 < 160) {
      const unsigned short* xn = xb + (size_t)(t + 1) * xstep;
      x0 = *(const short4v*)(xn);
      x1 = *(const short4v*)(xn + 128 * 16);
      x2 = *(const short4v*)(xn + 256 * 16);
      x3 = *(const short4v*)(xn + 384 * 16);
    }

    const size_t obase = (size_t)((159 - t) * 64 + nb * 16) * 128;
#pragma unroll
    for (int r = 0; r < 4; ++r) {
      const float iv = sgm(a0[r] + b2f((unsigned short)cx0[r]));
      const float fv = sgm(a1[r] + b2f((unsigned short)cx1[r]));
      const float gv = tanhf_(a2[r] + b2f((unsigned short)cx2[r]));
      const float ov = sgm(a3[r] + b2f((unsigned short)cx3[r]));
      const float cn = fv * c1[r] + iv * gv;
      c1[r] = cn;
      const unsigned short hb = f2b(ov * tanhf_(cn));
      const int q = hi * 4 + r;
      hA1[wb][q][u] = hb;
      nout[obase + (size_t)q * 128 + u] = hb;
    }
    __syncthreads();
  }
}

// ---------------------------------------------------------------------------
// Edge: 640 blocks x 256 threads, snake-permuted. Recurrence fully in regs:
// per-lane rotated weights W0r/War/Wbr (192 VGPR), DPP row_ror gate dots.
// Heads pipelined one step late through small LDS.
// ---------------------------------------------------------------------------
__global__ __launch_bounds__(256, 1) void edge_kernel(
    const unsigned short* __restrict__ nflat, // bf16 [10240][128]
    const float* __restrict__ exw, const float* __restrict__ exb,   // [32][128],[32]
    const float* __restrict__ enw, const float* __restrict__ enb,   // [16][32],[16]
    const float* __restrict__ ewih,  // [1][64][16]
    const float* __restrict__ ewhh,  // [2][64][16]
    const float* __restrict__ ebih, const float* __restrict__ ebhh, // [2][64]
    const float* __restrict__ ee1w, const float* __restrict__ ee1b,
    const float* __restrict__ ee2w, const float* __restrict__ ee2b,
    const float* __restrict__ ef1w, const float* __restrict__ ef1b,
    const float* __restrict__ ef2w, const float* __restrict__ ef2b,
    float* __restrict__ out)
{
  const int tid = threadIdx.x;
  const int sg  = tid >> 4;
  const int u   = tid & 15;
  const int b   = blockIdx.x;

  // snake permutation: dispatch rows {0,1,2} -> bb = r, 511-r, 512+r
  const int row = b >> 8, r = b & 255;
  const int bb  = (row == 1) ? (511 - r) : ((row << 8) + r);
  const int kbase = bb * 16;
  const int jrow  = 160 - (bb >> 2);
  const int gid   = (kbase & 63) + sg;

  __shared__ __align__(16) float s_nf[16][132];
  __shared__ float s_w0s[64][17];
  __shared__ float s_was[64][17];
  __shared__ float s_wbs[64][17];
  __shared__ __align__(16) float s_wh[16][20];
  __shared__ __align__(16) float s_ef2[32][8];
  __shared__ __align__(16) float s_ee2[16];
  __shared__ __align__(16) float h1b[16][20];
  __shared__ __align__(16) float t1b[16][12];
  __shared__ __align__(16) float t2b[16][12];
  __shared__ __align__(16) float x32[16][36];

  for (int i = tid; i < 16 * 128; i += 256)
    s_nf[i >> 7][i & 127] = b2f(nflat[(size_t)(kbase + (i >> 7)) * 128 + (i & 127)]);
  for (int i = tid; i < 64 * 16; i += 256) {
    s_w0s[i >> 4][i & 15] = ewhh[i];                 // layer0 whh
    s_was[i >> 4][i & 15] = ewih[i];                 // layer1 wih
    s_wbs[i >> 4][i & 15] = ewhh[1024 + i];          // layer1 whh
  }
  for (int i = tid; i < 8 * 16; i += 256) {
    s_wh[i >> 4][i & 15]       = ee1w[i];            // rows 0-7: e t-head
    s_wh[8 + (i >> 4)][i & 15] = ef1w[i];            // rows 8-15: f t-head
  }
  for (int i = tid; i < 32 * 8; i += 256) s_ef2[i >> 3][i & 7] = ef2w[i];
  if (tid < 16) s_ee2[tid] = ee2w[tid];

  // zero the (never-written) diagonal; graph g == b for first 64 blocks
  if (b < NG) {
    for (int d = tid; d < NMAX; d += 256) {
      out[(size_t)b * (NMAX * NMAX) + (size_t)d * NMAX + d] = 0.0f;
      float* fb = out + (size_t)NG * NMAX * NMAX
                + ((size_t)b * NMAX * NMAX + (size_t)d * NMAX + d) * 16;
#pragma unroll
      for (int q = 0; q < 16; ++q) fb[q] = 0.0f;
    }
  }

  // ---- per-thread bias constants from global ----
  const float be0i = ebih[u]      + ebhh[u];
  const float be0f = ebih[16 + u] + ebhh[16 + u];
  const float be0g = ebih[32 + u] + ebhh[32 + u];
  const float be0o = ebih[48 + u] + ebhh[48 + u];
  const float be1i = ebih[64 + u]      + ebhh[64 + u];
  const float be1f = ebih[64 + 16 + u] + ebhh[64 + 16 + u];
  const float be1g = ebih[64 + 32 + u] + ebhh[64 + 32 + u];
  const float be1o = ebih[64 + 48 + u] + ebhh[64 + 48 + u];
  const float hbias = (u < 8) ? ee1b[u] : ef1b[u - 8];
  const float f2bl = ef2b[u], f2bu = ef2b[16 + u];
  const float e2bias = (u < 2) ? ee2b[u] : 0.0f;

  __syncthreads();   // staging + diag done

  // ---- per-lane rotated weight registers ----
  float W0r[4][16], War[4][16], Wbr[4][16];
#pragma unroll
  for (int g = 0; g < 4; ++g) {
    const int rw = g * 16 + u;
#pragma unroll
    for (int j = 0; j < 16; ++j) {
      const int v = (u + j) & 15;
      W0r[g][j] = s_w0s[rw][v];
      War[g][j] = s_was[rw][v];
      Wbr[g][j] = s_wbs[rw][v];
    }
  }

  // ---- h0e = relu(relu(nf @ exw^T + exb) @ enw^T + enb) ----
  {
    float acc0 = exb[u], acc1 = exb[16 + u];
    const float* w0p = exw + u * 128;
    const float* w1p = exw + (16 + u) * 128;
    for (int qq = 0; qq < 32; ++qq) {
      const float4 nv  = *(const float4*)&s_nf[sg][qq * 4];
      const float4 w0v = *(const float4*)&w0p[qq * 4];
      const float4 w1v = *(const float4*)&w1p[qq * 4];
      acc0 += nv.x * w0v.x + nv.y * w0v.y + nv.z * w0v.z + nv.w * w0v.w;
      acc1 += nv.x * w1v.x + nv.y * w1v.y + nv.z * w1v.z + nv.w * w1v.w;
    }
    x32[sg][u] = fmaxf(acc0, 0.0f);
    x32[sg][16 + u] = fmaxf(acc1, 0.0f);
  }
  __builtin_amdgcn_wave_barrier();
  float h0, h1, c0 = 0.0f, c1 = 0.0f;
  {
    float acc = enb[u];
    const float* ewp = enw + u * 32;
#pragma unroll
    for (int qq = 0; qq < 8; ++qq) {
      const float4 xv  = *(const float4*)&x32[sg][qq * 4];
      const float4 wv2 = *(const float4*)&ewp[qq * 4];
      acc += xv.x * wv2.x + xv.y * wv2.y + xv.z * wv2.z + xv.w * wv2.w;
    }
    const float h0e = fmaxf(acc, 0.0f);
    h0 = h0e;
    h1 = h0e;
  }

  float* exi = out + (size_t)gid * (NMAX * NMAX);
  float* fea = out + (size_t)NG * NMAX * NMAX + (size_t)gid * (NMAX * NMAX) * 16;
  const int jN = jrow * NMAX;

  // pipelined loop: iteration s computes LSTM step s (if s<jrow) and
  // finalizes heads/stores for step s-1 (if s>0).
  for (int s = 0; s <= jrow; ++s) {
    const bool doStep = (s < jrow);
    const bool doHead = (s > 0);

    // ---- L0 gate dots on h0_{s-1} (pure regs + DPP) ----
    float a0, a1, a2, a3, p0, p1, p2, p3;
    if (doStep) {
      a0 = be0i; a1 = be0f; a2 = be0g; a3 = be0o;
      p0 = 0.f; p1 = 0.f; p2 = 0.f; p3 = 0.f;
      DOT16(W0r, h0, a0, a1, a2, a3, p0, p1, p2, p3)
    }

    // ---- t-head for step s-1: gather h1_{s-1} from LDS ----
    if (doHead) {
      __builtin_amdgcn_wave_barrier();
      float th = hbias;
#pragma unroll
      for (int qq = 0; qq < 4; ++qq) {
        const float4 hv = *(const float4*)&h1b[sg][qq * 4];
        const float4 wv = *(const float4*)&s_wh[u][qq * 4];
        th += hv.x * wv.x + hv.y * wv.y + hv.z * wv.z + hv.w * wv.w;
      }
      th = fmaxf(th, 0.0f);
      if (u < 8) t1b[sg][u] = th; else t2b[sg][u - 8] = th;
      __builtin_amdgcn_wave_barrier();
    }

    // ---- h0 activation ----
    float h0n = 0.0f;
    if (doStep) {
      a0 += p0; a1 += p1; a2 += p2; a3 += p3;
      const float iv = sgm(a0), fv = sgm(a1), gv = tanhf_(a2), ov = sgm(a3);
      c0 = fv * c0 + iv * gv;
      h0n = ov * tanhf_(c0);
    }

    // ---- f/e heads for step s-1 ----
    if (doHead) {
      const int sm = s - 1;
      const float4 ta = *(const float4*)&t2b[sg][0];
      const float4 tb = *(const float4*)&t2b[sg][4];
      const float4 wl0 = *(const float4*)&s_ef2[u][0];
      const float4 wl1 = *(const float4*)&s_ef2[u][4];
      const float4 wu0 = *(const float4*)&s_ef2[16 + u][0];
      const float4 wu1 = *(const float4*)&s_ef2[16 + u][4];
      const float fl = f2bl
          + ta.x * wl0.x + ta.y * wl0.y + ta.z * wl0.z + ta.w * wl0.w
          + tb.x * wl1.x + tb.y * wl1.y + tb.z * wl1.z + tb.w * wl1.w;
      const float fu = f2bu
          + ta.x * wu0.x + ta.y * wu0.y + ta.z * wu0.z + ta.w * wu0.w
          + tb.x * wu1.x + tb.y * wu1.y + tb.z * wu1.z + tb.w * wu1.w;
      fea[((size_t)jN + sm) * 16 + u] = fl;
      fea[((size_t)sm * NMAX + jrow) * 16 + u] = fu;
      if (u < 2) {
        const float4 t1a = *(const float4*)&t1b[sg][0];
        const float4 t1c = *(const float4*)&t1b[sg][4];
        const float4 we0 = *(const float4*)&s_ee2[u * 8];
        const float4 we1 = *(const float4*)&s_ee2[u * 8 + 4];
        float e = e2bias
            + t1a.x * we0.x + t1a.y * we0.y + t1a.z * we0.z + t1a.w * we0.w
            + t1c.x * we1.x + t1c.y * we1.y + t1c.z * we1.z + t1c.w * we1.w;
        const size_t idx = (u == 0) ? ((size_t)jN + sm)
                                    : ((size_t)sm * NMAX + jrow);
        exi[idx] = sgm(e);
      }
    }

    // ---- L1 dots on [h0_s | h1_{s-1}] + h1 activation ----
    if (doStep) {
      float b0 = be1i, b1 = be1f, b2 = be1g, b3 = be1o;
      float q0 = 0.f, q1 = 0.f, q2 = 0.f, q3 = 0.f;
      DOT16(War, h0n, b0, b1, b2, b3, q0, q1, q2, q3)
      DOT16(Wbr, h1,  b0, b1, b2, b3, q0, q1, q2, q3)
      b0 += q0; b1 += q1; b2 += q2; b3 += q3;
      const float iv = sgm(b0), fv = sgm(b1), gv = tanhf_(b2), ov = sgm(b3);
      c1 = fv * c1 + iv * gv;
      const float h1n = ov * tanhf_(c1);
      __builtin_amdgcn_wave_barrier();
      h1b[sg][u] = h1n;     // for next iteration's t-head
      h0 = h0n;
      h1 = h1n;
    }
  }
}

extern "C" void kernel_launch(void* const* d_in, const int* in_sizes, int n_in,
                              void* d_out, int out_size, void* d_ws, size_t ws_size,
                              hipStream_t stream) {
  (void)in_sizes; (void)n_in; (void)out_size; (void)ws_size;
  const float* gene = (const float*)d_in[0];
  const float* entw = (const float*)d_in[1];
  const float* entb = (const float*)d_in[2];
  const float* nwih = (const float*)d_in[4];
  const float* nwhh = (const float*)d_in[5];
  const float* nbih = (const float*)d_in[6];
  const float* nbhh = (const float*)d_in[7];
  const float* exw  = (const float*)d_in[8];
  const float* exb  = (const float*)d_in[9];
  const float* enw  = (const float*)d_in[10];
  const float* enb  = (const float*)d_in[11];
  const float* ewih = (const float*)d_in[13];
  const float* ewhh = (const float*)d_in[14];
  const float* ebih = (const float*)d_in[15];
  const float* ebhh = (const float*)d_in[16];
  const float* ee1w = (const float*)d_in[17];
  const float* ee1b = (const float*)d_in[18];
  const float* ee2w = (const float*)d_in[19];
  const float* ee2b = (const float*)d_in[20];
  const float* ef1w = (const float*)d_in[21];
  const float* ef1b = (const float*)d_in[22];
  const float* ef2w = (const float*)d_in[23];
  const float* ef2b = (const float*)d_in[24];

  // ws layout (bytes):
  //   nflat @ 0         : 10240*128*2 = 2,621,440
  //   h0w   @ 2621440   : 160*64*128*2 = 2,621,440
  //   hinit @ 5242880   : 64*128*2 = 16,384
  //   X3    @ 5259264   : 4*160*512*16*2 = 10,485,760
  char* ws = (char*)d_ws;
  unsigned short* nflat = (unsigned short*)(ws);
  unsigned short* h0w   = (unsigned short*)(ws + 2621440);
  unsigned short* hinit = (unsigned short*)(ws + 5242880);
  unsigned short* X3    = (unsigned short*)(ws + 5259264);

  node_l0<<<4, 512, 0, stream>>>(gene, entw, entb, nwhh, nbih, nbhh, h0w, hinit);
  xgemm<<<dim3(160, 4), 256, 0, stream>>>(h0w, nwih, X3);
  node_l1<<<4, 512, 0, stream>>>(hinit, X3, nwhh, nbih, nbhh, nflat);
  edge_kernel<<<640, 256, 0, stream>>>(nflat, exw, exb, enw, enb, ewih, ewhh,
                                       ebih, ebhh, ee1w, ee1b, ee2w, ee2b,
                                       ef1w, ef1b, ef2w, ef2b, (float*)d_out);
}

// Round 10
// 501.581 us; speedup vs baseline: 2.1475x; 1.2169x over previous
//
#include <hip/hip_runtime.h>

// GraphGenRnn — R10: R9 (f16-packed register weights + v_dot2_f32_f16 edge
// recurrence) with the cvt_pkrtz type mismatch fixed via bit_cast
// (__builtin_amdgcn_cvt_pkrtz returns __fp16x2; fdot2 wants _Float16x2).
// Node kernels unchanged.

typedef __attribute__((ext_vector_type(8))) short short8;
typedef __attribute__((ext_vector_type(4))) short short4v;
typedef __attribute__((ext_vector_type(4))) float floatx4;
typedef _Float16 half2v __attribute__((ext_vector_type(2)));

#define NG 64
#define NMAX 161

__device__ __forceinline__ float sgm(float x) {
  return __builtin_amdgcn_rcpf(1.0f + __expf(-x));
}
__device__ __forceinline__ float tanhf_(float x) {
  return 2.0f * __builtin_amdgcn_rcpf(1.0f + __expf(-2.0f * x)) - 1.0f;
}
__device__ __forceinline__ unsigned short f2b(float x) {
  union { float f; unsigned u; } v; v.f = x;
  unsigned r = v.u + 0x7fffu + ((v.u >> 16) & 1u);   // RNE to bf16
  return (unsigned short)(r >> 16);
}
__device__ __forceinline__ float b2f(unsigned short h) {
  union { unsigned u; float f; } v; v.u = ((unsigned)h) << 16; return v.f;
}
__device__ __forceinline__ half2v pkh(float a, float b) {
  return __builtin_bit_cast(half2v, __builtin_amdgcn_cvt_pkrtz(a, b));
}

// DPP row_ror:N within 16-lane rows: out[i] = in[(i+N)&15]
#define RORF(x, N) __builtin_bit_cast(float, __builtin_amdgcn_update_dpp(      \
    __builtin_bit_cast(int, (x)), __builtin_bit_cast(int, (x)),                \
    0x120 | (N), 0xF, 0xF, false))

// rotate h across the 16-lane group and pack to 8 half2 (lane u slot j holds
// {h[(u+2j)&15], h[(u+2j+1)&15]})
__device__ __forceinline__ void rotpack(float h, half2v* out) {
  const float r1  = RORF(h, 1),  r2  = RORF(h, 2),  r3  = RORF(h, 3);
  const float r4  = RORF(h, 4),  r5  = RORF(h, 5),  r6  = RORF(h, 6);
  const float r7  = RORF(h, 7),  r8  = RORF(h, 8),  r9  = RORF(h, 9);
  const float r10 = RORF(h, 10), r11 = RORF(h, 11), r12 = RORF(h, 12);
  const float r13 = RORF(h, 13), r14 = RORF(h, 14), r15 = RORF(h, 15);
  out[0] = pkh(h,   r1);
  out[1] = pkh(r2,  r3);
  out[2] = pkh(r4,  r5);
  out[3] = pkh(r6,  r7);
  out[4] = pkh(r8,  r9);
  out[5] = pkh(r10, r11);
  out[6] = pkh(r12, r13);
  out[7] = pkh(r14, r15);
}

// ---------------------------------------------------------------------------
// node_l0: 4 blocks x 512 threads. Wave w: units [16w,16w+16), whh0 in 64
// VGPRs. h0 double-buffered in LDS, 1 barrier/step. Streams h0_t to h0w.
// ---------------------------------------------------------------------------
__global__ __launch_bounds__(512) void node_l0(
    const float* __restrict__ gene,   // [64][128]
    const float* __restrict__ entw,   // [128][128]
    const float* __restrict__ entb,   // [128]
    const float* __restrict__ nwhh,   // [2][512][128] (layer0 = first half)
    const float* __restrict__ nbih,   // [2][512]
    const float* __restrict__ nbhh,   // [2][512]
    unsigned short* __restrict__ h0w,   // bf16 [160][64][128]
    unsigned short* __restrict__ hinit) // bf16 [64][128]
{
  const int tid  = threadIdx.x;
  const int wv   = tid >> 6;
  const int lane = tid & 63;
  const int lo   = lane & 15;
  const int hi   = lane >> 4;
  const int u    = (wv << 4) | lo;
  const int nb   = blockIdx.x;

  __shared__ __align__(16) unsigned short hA0[2][16][136];

  short8 B0[4][4];
#pragma unroll
  for (int t = 0; t < 4; ++t) {
    const int n = t * 128 + u;
#pragma unroll
    for (int ks = 0; ks < 4; ++ks) {
      const float* src = nwhh + n * 128 + ks * 32 + hi * 8;
      short8 bfr;
#pragma unroll
      for (int jj = 0; jj < 8; ++jj) bfr[jj] = (short)f2b(src[jj]);
      B0[t][ks] = bfr;
    }
  }

  const float bi0 = nbih[u]       + nbhh[u];
  const float bf0 = nbih[128 + u] + nbhh[128 + u];
  const float bg0 = nbih[256 + u] + nbhh[256 + u];
  const float bo0 = nbih[384 + u] + nbhh[384 + u];

  {
    const int q  = tid >> 5;
    const int u4 = (tid & 31) * 4;
    const float* gc = gene + (nb * 16 + q) * 128;
    float acc[4] = { entb[u4], entb[u4 + 1], entb[u4 + 2], entb[u4 + 3] };
    for (int qq = 0; qq < 32; ++qq) {
      const float4 gv = *(const float4*)&gc[qq * 4];
#pragma unroll
      for (int r = 0; r < 4; ++r) {
        const float4 wv2 = *(const float4*)&entw[(u4 + r) * 128 + qq * 4];
        acc[r] += gv.x * wv2.x + gv.y * wv2.y + gv.z * wv2.z + gv.w * wv2.w;
      }
    }
#pragma unroll
    for (int r = 0; r < 4; ++r) {
      const unsigned short hb = f2b(fmaxf(acc[r], 0.0f));
      hA0[0][q][u4 + r] = hb;
      hinit[(size_t)(nb * 16 + q) * 128 + u4 + r] = hb;
    }
  }

  float c0[4] = {0.f, 0.f, 0.f, 0.f};
  __syncthreads();

  for (int t = 0; t < 160; ++t) {
    const int rb = t & 1, wb = rb ^ 1;
    floatx4 a0 = {bi0, bi0, bi0, bi0};
    floatx4 a1 = {bf0, bf0, bf0, bf0};
    floatx4 a2 = {bg0, bg0, bg0, bg0};
    floatx4 a3 = {bo0, bo0, bo0, bo0};
    const unsigned short* ar = &hA0[rb][lo][hi * 8];
#pragma unroll
    for (int ks = 0; ks < 4; ++ks) {
      const short8 afr = *(const short8*)(ar + ks * 32);
      a0 = __builtin_amdgcn_mfma_f32_16x16x32_bf16(afr, B0[0][ks], a0, 0, 0, 0);
      a1 = __builtin_amdgcn_mfma_f32_16x16x32_bf16(afr, B0[1][ks], a1, 0, 0, 0);
      a2 = __builtin_amdgcn_mfma_f32_16x16x32_bf16(afr, B0[2][ks], a2, 0, 0, 0);
      a3 = __builtin_amdgcn_mfma_f32_16x16x32_bf16(afr, B0[3][ks], a3, 0, 0, 0);
    }
    const size_t obase = (size_t)(t * 64 + nb * 16) * 128;
#pragma unroll
    for (int r = 0; r < 4; ++r) {
      const float iv = sgm(a0[r]);
      const float fv = sgm(a1[r]);
      const float gv = tanhf_(a2[r]);
      const float ov = sgm(a3[r]);
      const float cn = fv * c0[r] + iv * gv;
      c0[r] = cn;
      const unsigned short hb = f2b(ov * tanhf_(cn));
      const int q = hi * 4 + r;
      hA0[wb][q][u] = hb;
      h0w[obase + (size_t)q * 128 + u] = hb;
    }
    __syncthreads();
  }
}

// ---------------------------------------------------------------------------
// xgemm: X3[g>>4][t][col][g&15] = sum_u h0w[t][g][u] * wih1[col][u]  (bf16)
// ---------------------------------------------------------------------------
__global__ __launch_bounds__(256) void xgemm(
    const unsigned short* __restrict__ h0w,  // bf16 [160][64][128]
    const float* __restrict__ nwih,          // [512][128] (layer-1 wih)
    unsigned short* __restrict__ X3)         // bf16 [4][160][512][16]
{
  const int tid = threadIdx.x;
  const int wv  = tid >> 6;
  const int lane = tid & 63;
  const int lo  = lane & 15;
  const int hi  = lane >> 4;
  const int bt  = blockIdx.x;
  const int bn  = blockIdx.y;

  __shared__ __align__(16) unsigned short s_b[128][136];

  for (int i = tid; i < 128 * 32; i += 256) {
    const int nc = i >> 5, k4 = (i & 31) * 4;
    const float4 w = *(const float4*)&nwih[(size_t)(bn * 128 + nc) * 128 + k4];
    s_b[nc][k4]     = f2b(w.x);
    s_b[nc][k4 + 1] = f2b(w.y);
    s_b[nc][k4 + 2] = f2b(w.z);
    s_b[nc][k4 + 3] = f2b(w.w);
  }
  __syncthreads();

  floatx4 acc[8];
#pragma unroll
  for (int nt = 0; nt < 8; ++nt) acc[nt] = (floatx4){0.f, 0.f, 0.f, 0.f};

  const unsigned short* arow = h0w + (size_t)(bt * 64 + wv * 16 + lo) * 128 + hi * 8;
#pragma unroll
  for (int ks = 0; ks < 4; ++ks) {
    const short8 afr = *(const short8*)(arow + ks * 32);
#pragma unroll
    for (int nt = 0; nt < 8; ++nt) {
      const short8 bfr = *(const short8*)&s_b[nt * 16 + lo][ks * 32 + hi * 8];
      acc[nt] = __builtin_amdgcn_mfma_f32_16x16x32_bf16(afr, bfr, acc[nt], 0, 0, 0);
    }
  }

#pragma unroll
  for (int nt = 0; nt < 8; ++nt) {
    const size_t base3 = ((((size_t)wv * 160 + bt) * 512) + bn * 128 + nt * 16 + lo) * 16 + hi * 4;
    short4v xv;
#pragma unroll
    for (int r = 0; r < 4; ++r) xv[r] = (short)f2b(acc[nt][r]);
    *(short4v*)&X3[base3] = xv;
  }
}

// ---------------------------------------------------------------------------
// node_l1: 4 blocks x 512 threads. whh1 in 64 VGPRs; input-half streamed from
// X3 (contiguous 16KB/block/step, prefetched one step ahead).
// ---------------------------------------------------------------------------
__global__ __launch_bounds__(512) void node_l1(
    const unsigned short* __restrict__ hinit, // bf16 [64][128]
    const unsigned short* __restrict__ X3,    // bf16 [4][160][512][16]
    const float* __restrict__ nwhh,           // [2][512][128] (layer1 = 2nd half)
    const float* __restrict__ nbih,           // [2][512]
    const float* __restrict__ nbhh,           // [2][512]
    unsigned short* __restrict__ nout)        // bf16 [10240][128]
{
  const int tid  = threadIdx.x;
  const int wv   = tid >> 6;
  const int lane = tid & 63;
  const int lo   = lane & 15;
  const int hi   = lane >> 4;
  const int u    = (wv << 4) | lo;
  const int nb   = blockIdx.x;

  __shared__ __align__(16) unsigned short hA1[2][16][136];

  short8 B1[4][4];
#pragma unroll
  for (int t = 0; t < 4; ++t) {
    const int n = t * 128 + u;
#pragma unroll
    for (int ks = 0; ks < 4; ++ks) {
      const float* src = nwhh + 512 * 128 + n * 128 + ks * 32 + hi * 8;
      short8 bfr;
#pragma unroll
      for (int jj = 0; jj < 8; ++jj) bfr[jj] = (short)f2b(src[jj]);
      B1[t][ks] = bfr;
    }
  }

  const float bi1 = nbih[512 + u]       + nbhh[512 + u];
  const float bf1 = nbih[512 + 128 + u] + nbhh[512 + 128 + u];
  const float bg1 = nbih[512 + 256 + u] + nbhh[512 + 256 + u];
  const float bo1 = nbih[512 + 384 + u] + nbhh[512 + 384 + u];

  {
    const int q  = tid >> 5;
    const int u4 = (tid & 31) * 4;
    const short4v hv = *(const short4v*)&hinit[(size_t)(nb * 16 + q) * 128 + u4];
    *(short4v*)&hA1[0][q][u4] = hv;
  }

  float c1[4] = {0.f, 0.f, 0.f, 0.f};

  const size_t xstep = 512 * 16;
  const unsigned short* xb = X3 + ((size_t)nb * 160) * xstep + (size_t)u * 16 + hi * 4;
  short4v x0 = *(const short4v*)(xb);
  short4v x1 = *(const short4v*)(xb + 128 * 16);
  short4v x2 = *(const short4v*)(xb + 256 * 16);
  short4v x3 = *(const short4v*)(xb + 384 * 16);
  __syncthreads();

  for (int t = 0; t < 160; ++t) {
    const int rb = t & 1, wb = rb ^ 1;

    floatx4 a0 = {bi1, bi1, bi1, bi1};
    floatx4 a1 = {bf1, bf1, bf1, bf1};
    floatx4 a2 = {bg1, bg1, bg1, bg1};
    floatx4 a3 = {bo1, bo1, bo1, bo1};
    const unsigned short* ar = &hA1[rb][lo][hi * 8];
#pragma unroll
    for (int ks = 0; ks < 4; ++ks) {
      const short8 afr = *(const short8*)(ar + ks * 32);
      a0 = __builtin_amdgcn_mfma_f32_16x16x32_bf16(afr, B1[0][ks], a0, 0, 0, 0);
      a1 = __builtin_amdgcn_mfma_f32_16x16x32_bf16(afr, B1[1][ks], a1, 0, 0, 0);
      a2 = __builtin_amdgcn_mfma_f32_16x16x32_bf16(afr, B1[2][ks], a2, 0, 0, 0);
      a3 = __builtin_amdgcn_mfma_f32_16x16x32_bf16(afr, B1[3][ks], a3, 0, 0, 0);
    }

    const short4v cx0 = x0, cx1 = x1, cx2 = x2, cx3 = x3;
    if (t + 1 < 160) {
      const unsigned short* xn = xb + (size_t)(t + 1) * xstep;
      x0 = *(const short4v*)(xn);
      x1 = *(const short4v*)(xn + 128 * 16);
      x2 = *(const short4v*)(xn + 256 * 16);
      x3 = *(const short4v*)(xn + 384 * 16);
    }

    const size_t obase = (size_t)((159 - t) * 64 + nb * 16) * 128;
#pragma unroll
    for (int r = 0; r < 4; ++r) {
      const float iv = sgm(a0[r] + b2f((unsigned short)cx0[r]));
      const float fv = sgm(a1[r] + b2f((unsigned short)cx1[r]));
      const float gv = tanhf_(a2[r] + b2f((unsigned short)cx2[r]));
      const float ov = sgm(a3[r] + b2f((unsigned short)cx3[r]));
      const float cn = fv * c1[r] + iv * gv;
      c1[r] = cn;
      const unsigned short hb = f2b(ov * tanhf_(cn));
      const int q = hi * 4 + r;
      hA1[wb][q][u] = hb;
      nout[obase + (size_t)q * 128 + u] = hb;
    }
    __syncthreads();
  }
}

// ---------------------------------------------------------------------------
// Edge: 640 blocks x 256 threads, snake-permuted. Recurrence in registers:
// f16-packed rotated weights (104 VGPR) + DPP rotate/pack + v_dot2_f32_f16.
// Heads pipelined one step late; only t1/t2 exchange touches LDS per step.
// ---------------------------------------------------------------------------
__global__ __launch_bounds__(256, 1) void edge_kernel(
    const unsigned short* __restrict__ nflat, // bf16 [10240][128]
    const float* __restrict__ exw, const float* __restrict__ exb,   // [32][128],[32]
    const float* __restrict__ enw, const float* __restrict__ enb,   // [16][32],[16]
    const float* __restrict__ ewih,  // [1][64][16]
    const float* __restrict__ ewhh,  // [2][64][16]
    const float* __restrict__ ebih, const float* __restrict__ ebhh, // [2][64]
    const float* __restrict__ ee1w, const float* __restrict__ ee1b,
    const float* __restrict__ ee2w, const float* __restrict__ ee2b,
    const float* __restrict__ ef1w, const float* __restrict__ ef1b,
    const float* __restrict__ ef2w, const float* __restrict__ ef2b,
    float* __restrict__ out)
{
  const int tid = threadIdx.x;
  const int sg  = tid >> 4;
  const int u   = tid & 15;
  const int b   = blockIdx.x;

  // snake permutation: dispatch rows {0,1,2} -> bb = r, 511-r, 512+r
  const int row = b >> 8, r = b & 255;
  const int bb  = (row == 1) ? (511 - r) : ((row << 8) + r);
  const int kbase = bb * 16;
  const int jrow  = 160 - (bb >> 2);
  const int gid   = (kbase & 63) + sg;

  __shared__ __align__(16) float s_nf[16][132];
  __shared__ float s_w0s[64][17];
  __shared__ float s_was[64][17];
  __shared__ float s_wbs[64][17];
  __shared__ float s_wh[16][17];
  __shared__ float s_ef2[32][10];
  __shared__ __align__(16) float s_ee2[16];
  __shared__ __align__(16) float t1b[16][12];
  __shared__ __align__(16) float t2b[16][12];
  __shared__ __align__(16) float x32[16][36];

  for (int i = tid; i < 16 * 128; i += 256)
    s_nf[i >> 7][i & 127] = b2f(nflat[(size_t)(kbase + (i >> 7)) * 128 + (i & 127)]);
  for (int i = tid; i < 64 * 16; i += 256) {
    s_w0s[i >> 4][i & 15] = ewhh[i];                 // layer0 whh
    s_was[i >> 4][i & 15] = ewih[i];                 // layer1 wih
    s_wbs[i >> 4][i & 15] = ewhh[1024 + i];          // layer1 whh
  }
  for (int i = tid; i < 8 * 16; i += 256) {
    s_wh[i >> 4][i & 15]       = ee1w[i];            // rows 0-7: e t-head
    s_wh[8 + (i >> 4)][i & 15] = ef1w[i];            // rows 8-15: f t-head
  }
  for (int i = tid; i < 32 * 8; i += 256) s_ef2[i >> 3][i & 7] = ef2w[i];
  if (tid < 16) s_ee2[tid] = ee2w[tid];

  // zero the (never-written) diagonal; graph g == b for first 64 blocks
  if (b < NG) {
    for (int d = tid; d < NMAX; d += 256) {
      out[(size_t)b * (NMAX * NMAX) + (size_t)d * NMAX + d] = 0.0f;
      float* fb = out + (size_t)NG * NMAX * NMAX
                + ((size_t)b * NMAX * NMAX + (size_t)d * NMAX + d) * 16;
#pragma unroll
      for (int q = 0; q < 16; ++q) fb[q] = 0.0f;
    }
  }

  // ---- per-thread bias constants from global ----
  const float be0i = ebih[u]      + ebhh[u];
  const float be0f = ebih[16 + u] + ebhh[16 + u];
  const float be0g = ebih[32 + u] + ebhh[32 + u];
  const float be0o = ebih[48 + u] + ebhh[48 + u];
  const float be1i = ebih[64 + u]      + ebhh[64 + u];
  const float be1f = ebih[64 + 16 + u] + ebhh[64 + 16 + u];
  const float be1g = ebih[64 + 32 + u] + ebhh[64 + 32 + u];
  const float be1o = ebih[64 + 48 + u] + ebhh[64 + 48 + u];
  const float hbias = (u < 8) ? ee1b[u] : ef1b[u - 8];
  const float f2bl = ef2b[u], f2bu = ef2b[16 + u];
  const float e2bias = (u < 2) ? ee2b[u] : 0.0f;

  __syncthreads();   // staging + diag done

  // ---- rotated f16-packed weight registers (104 VGPR total) ----
  half2v W0h[4][8], WAh[4][8], WBh[4][8], WHh[8];
#pragma unroll
  for (int g = 0; g < 4; ++g) {
    const int rw = g * 16 + u;
#pragma unroll
    for (int j = 0; j < 8; ++j) {
      const int v0 = (u + 2 * j) & 15, v1 = (u + 2 * j + 1) & 15;
      W0h[g][j] = pkh(s_w0s[rw][v0], s_w0s[rw][v1]);
      WAh[g][j] = pkh(s_was[rw][v0], s_was[rw][v1]);
      WBh[g][j] = pkh(s_wbs[rw][v0], s_wbs[rw][v1]);
    }
  }
#pragma unroll
  for (int j = 0; j < 8; ++j) {
    const int v0 = (u + 2 * j) & 15, v1 = (u + 2 * j + 1) & 15;
    WHh[j] = pkh(s_wh[u][v0], s_wh[u][v1]);
  }

  // ---- h0e = relu(relu(nf @ exw^T + exb) @ enw^T + enb) ----
  {
    float acc0 = exb[u], acc1 = exb[16 + u];
    const float* w0p = exw + u * 128;
    const float* w1p = exw + (16 + u) * 128;
    for (int qq = 0; qq < 32; ++qq) {
      const float4 nv  = *(const float4*)&s_nf[sg][qq * 4];
      const float4 w0v = *(const float4*)&w0p[qq * 4];
      const float4 w1v = *(const float4*)&w1p[qq * 4];
      acc0 += nv.x * w0v.x + nv.y * w0v.y + nv.z * w0v.z + nv.w * w0v.w;
      acc1 += nv.x * w1v.x + nv.y * w1v.y + nv.z * w1v.z + nv.w * w1v.w;
    }
    x32[sg][u] = fmaxf(acc0, 0.0f);
    x32[sg][16 + u] = fmaxf(acc1, 0.0f);
  }
  __builtin_amdgcn_wave_barrier();
  float c0 = 0.0f, c1 = 0.0f;
  half2v h20[8], h21[8];
  {
    float acc = enb[u];
    const float* ewp = enw + u * 32;
#pragma unroll
    for (int qq = 0; qq < 8; ++qq) {
      const float4 xv  = *(const float4*)&x32[sg][qq * 4];
      const float4 wv2 = *(const float4*)&ewp[qq * 4];
      acc += xv.x * wv2.x + xv.y * wv2.y + xv.z * wv2.z + xv.w * wv2.w;
    }
    const float h0e = fmaxf(acc, 0.0f);
    rotpack(h0e, h20);
#pragma unroll
    for (int j = 0; j < 8; ++j) h21[j] = h20[j];
  }

  float* exi = out + (size_t)gid * (NMAX * NMAX);
  float* fea = out + (size_t)NG * NMAX * NMAX + (size_t)gid * (NMAX * NMAX) * 16;
  const int jN = jrow * NMAX;

  // pipelined loop: iteration s computes LSTM step s (if s<jrow) and
  // finalizes f/e heads/stores for step s-1 (if s>0).
  for (int s = 0; s <= jrow; ++s) {
    const bool doStep = (s < jrow);
    const bool doHead = (s > 0);

    // ---- L0 gate dots on h0_{s-1} (regs, dot2) ----
    float a0, a1, a2, a3;
    if (doStep) {
      a0 = be0i; a1 = be0f; a2 = be0g; a3 = be0o;
#pragma unroll
      for (int j = 0; j < 8; ++j) {
        a0 = __builtin_amdgcn_fdot2(h20[j], W0h[0][j], a0, false);
        a1 = __builtin_amdgcn_fdot2(h20[j], W0h[1][j], a1, false);
        a2 = __builtin_amdgcn_fdot2(h20[j], W0h[2][j], a2, false);
        a3 = __builtin_amdgcn_fdot2(h20[j], W0h[3][j], a3, false);
      }
    }

    // ---- f/e heads for step s-1 (t1b/t2b written at end of prev iter) ----
    if (doHead) {
      __builtin_amdgcn_wave_barrier();
      const int sm = s - 1;
      const float2 ta0 = *(const float2*)&t2b[sg][0];
      const float2 ta1 = *(const float2*)&t2b[sg][2];
      const float2 ta2 = *(const float2*)&t2b[sg][4];
      const float2 ta3 = *(const float2*)&t2b[sg][6];
      const float2 wl0 = *(const float2*)&s_ef2[u][0];
      const float2 wl1 = *(const float2*)&s_ef2[u][2];
      const float2 wl2 = *(const float2*)&s_ef2[u][4];
      const float2 wl3 = *(const float2*)&s_ef2[u][6];
      const float2 wu0 = *(const float2*)&s_ef2[16 + u][0];
      const float2 wu1 = *(const float2*)&s_ef2[16 + u][2];
      const float2 wu2 = *(const float2*)&s_ef2[16 + u][4];
      const float2 wu3 = *(const float2*)&s_ef2[16 + u][6];
      const float fl = f2bl
          + ta0.x * wl0.x + ta0.y * wl0.y + ta1.x * wl1.x + ta1.y * wl1.y
          + ta2.x * wl2.x + ta2.y * wl2.y + ta3.x * wl3.x + ta3.y * wl3.y;
      const float fu = f2bu
          + ta0.x * wu0.x + ta0.y * wu0.y + ta1.x * wu1.x + ta1.y * wu1.y
          + ta2.x * wu2.x + ta2.y * wu2.y + ta3.x * wu3.x + ta3.y * wu3.y;
      fea[((size_t)jN + sm) * 16 + u] = fl;
      fea[((size_t)sm * NMAX + jrow) * 16 + u] = fu;
      if (u < 2) {
        const float4 t1a = *(const float4*)&t1b[sg][0];
        const float4 t1c = *(const float4*)&t1b[sg][4];
        const float4 we0 = *(const float4*)&s_ee2[u * 8];
        const float4 we1 = *(const float4*)&s_ee2[u * 8 + 4];
        float e = e2bias
            + t1a.x * we0.x + t1a.y * we0.y + t1a.z * we0.z + t1a.w * we0.w
            + t1c.x * we1.x + t1c.y * we1.y + t1c.z * we1.z + t1c.w * we1.w;
        const size_t idx = (u == 0) ? ((size_t)jN + sm)
                                    : ((size_t)sm * NMAX + jrow);
        exi[idx] = sgm(e);
      }
    }

    if (doStep) {
      // ---- h0 activation + rotate/pack ----
      {
        const float iv = sgm(a0), fv = sgm(a1), gv = tanhf_(a2), ov = sgm(a3);
        c0 = fv * c0 + iv * gv;
        rotpack(ov * tanhf_(c0), h20);
      }
      // ---- L1 dots on [h0_s | h1_{s-1}] ----
      float b0 = be1i, b1 = be1f, b2 = be1g, b3 = be1o;
#pragma unroll
      for (int j = 0; j < 8; ++j) {
        b0 = __builtin_amdgcn_fdot2(h20[j], WAh[0][j], b0, false);
        b1 = __builtin_amdgcn_fdot2(h20[j], WAh[1][j], b1, false);
        b2 = __builtin_amdgcn_fdot2(h20[j], WAh[2][j], b2, false);
        b3 = __builtin_amdgcn_fdot2(h20[j], WAh[3][j], b3, false);
      }
#pragma unroll
      for (int j = 0; j < 8; ++j) {
        b0 = __builtin_amdgcn_fdot2(h21[j], WBh[0][j], b0, false);
        b1 = __builtin_amdgcn_fdot2(h21[j], WBh[1][j], b1, false);
        b2 = __builtin_amdgcn_fdot2(h21[j], WBh[2][j], b2, false);
        b3 = __builtin_amdgcn_fdot2(h21[j], WBh[3][j], b3, false);
      }
      // ---- h1 activation + rotate/pack ----
      {
        const float iv = sgm(b0), fv = sgm(b1), gv = tanhf_(b2), ov = sgm(b3);
        c1 = fv * c1 + iv * gv;
        rotpack(ov * tanhf_(c1), h21);
      }
      // ---- t-head for step s (from rotated h1 broadcast) ----
      {
        float th = hbias;
#pragma unroll
        for (int j = 0; j < 8; ++j)
          th = __builtin_amdgcn_fdot2(h21[j], WHh[j], th, false);
        th = fmaxf(th, 0.0f);
        if (u < 8) t1b[sg][u] = th; else t2b[sg][u - 8] = th;
      }
      __builtin_amdgcn_wave_barrier();
    }
  }
}

extern "C" void kernel_launch(void* const* d_in, const int* in_sizes, int n_in,
                              void* d_out, int out_size, void* d_ws, size_t ws_size,
                              hipStream_t stream) {
  (void)in_sizes; (void)n_in; (void)out_size; (void)ws_size;
  const float* gene = (const float*)d_in[0];
  const float* entw = (const float*)d_in[1];
  const float* entb = (const float*)d_in[2];
  const float* nwih = (const float*)d_in[4];
  const float* nwhh = (const float*)d_in[5];
  const float* nbih = (const float*)d_in[6];
  const float* nbhh = (const float*)d_in[7];
  const float* exw  = (const float*)d_in[8];
  const float* exb  = (const float*)d_in[9];
  const float* enw  = (const float*)d_in[10];
  const float* enb  = (const float*)d_in[11];
  const float* ewih = (const float*)d_in[13];
  const float* ewhh = (const float*)d_in[14];
  const float* ebih = (const float*)d_in[15];
  const float* ebhh = (const float*)d_in[16];
  const float* ee1w = (const float*)d_in[17];
  const float* ee1b = (const float*)d_in[18];
  const float* ee2w = (const float*)d_in[19];
  const float* ee2b = (const float*)d_in[20];
  const float* ef1w = (const float*)d_in[21];
  const float* ef1b = (const float*)d_in[22];
  const float* ef2w = (const float*)d_in[23];
  const float* ef2b = (const float*)d_in[24];

  // ws layout (bytes):
  //   nflat @ 0         : 10240*128*2 = 2,621,440
  //   h0w   @ 2621440   : 160*64*128*2 = 2,621,440
  //   hinit @ 5242880   : 64*128*2 = 16,384
  //   X3    @ 5259264   : 4*160*512*16*2 = 10,485,760
  char* ws = (char*)d_ws;
  unsigned short* nflat = (unsigned short*)(ws);
  unsigned short* h0w   = (unsigned short*)(ws + 2621440);
  unsigned short* hinit = (unsigned short*)(ws + 5242880);
  unsigned short* X3    = (unsigned short*)(ws + 5259264);

  node_l0<<<4, 512, 0, stream>>>(gene, entw, entb, nwhh, nbih, nbhh, h0w, hinit);
  xgemm<<<dim3(160, 4), 256, 0, stream>>>(h0w, nwih, X3);
  node_l1<<<4, 512, 0, stream>>>(hinit, X3, nwhh, nbih, nbhh, nflat);
  edge_kernel<<<640, 256, 0, stream>>>(nflat, exw, exb, enw, enb, ewih, ewhh,
                                       ebih, ebhh, ee1w, ee1b, ee2w, ee2b,
                                       ef1w, ef1b, ef2w, ef2b, (float*)d_out);
}